// Round 2
// baseline (9810.930 us; speedup 1.0000x reference)
//
#include <hip/hip_runtime.h>
#include <cstddef>

#define LN_EPS 1e-5f

__device__ __forceinline__ float wave_reduce_sum(float v) {
    #pragma unroll
    for (int off = 32; off > 0; off >>= 1) v += __shfl_down(v, off, 64);
    return v;
}

// ---------------- GEMM: C = A[MxK] @ B[KxN] (+bias) (+relu) (+epilogue) ----------
// CMODE: 0 = overwrite, 1 = accumulate (C += gemm), 2 = C = elu(Cold + cbias) + gemm(+bias)
template<bool BIAS, bool RELU, int CMODE>
__global__ __launch_bounds__(256) void gemm_kernel(const float* __restrict__ A,
                                                   const float* __restrict__ B,
                                                   const float* __restrict__ bias,
                                                   const float* __restrict__ cbias,
                                                   float* __restrict__ C,
                                                   int M, int N, int K,
                                                   int lda, int ldb, int ldc) {
    const int BM = 128, BN = 128, BK = 16;
    __shared__ float As[BK][BM + 4];
    __shared__ float Bs[BK][BN];
    int tid = threadIdx.x;
    int tx = tid & 15, ty = tid >> 4;
    int m0 = blockIdx.y * BM, n0 = blockIdx.x * BN;
    float acc[8][8] = {};

    for (int k0 = 0; k0 < K; k0 += BK) {
        // Stage A tile (BM x BK), scalar loads with bounds checks (K=405 odd edge)
        #pragma unroll
        for (int i = 0; i < 2; i++) {
            int f = tid + i * 256;           // slot id in [0,512)
            int row = f >> 2;
            int kc = (f & 3) * 4;
            int gr = m0 + row;
            #pragma unroll
            for (int j = 0; j < 4; j++) {
                int gk = k0 + kc + j;
                float v = (gr < M && gk < K) ? A[(size_t)gr * lda + gk] : 0.f;
                As[kc + j][row] = v;
            }
        }
        // Stage B tile (BK x BN), vector loads (N always %4==0 here)
        #pragma unroll
        for (int i = 0; i < 2; i++) {
            int f = tid + i * 256;
            int kk = f >> 5;
            int nc = (f & 31) * 4;
            int gk = k0 + kk, gn = n0 + nc;
            float4 v = make_float4(0.f, 0.f, 0.f, 0.f);
            if (gk < K && gn < N) v = *reinterpret_cast<const float4*>(&B[(size_t)gk * ldb + gn]);
            *reinterpret_cast<float4*>(&Bs[kk][nc]) = v;
        }
        __syncthreads();
        #pragma unroll
        for (int k = 0; k < BK; k++) {
            float a[8], b[8];
            #pragma unroll
            for (int i = 0; i < 8; i++) a[i] = As[k][ty * 8 + i];
            #pragma unroll
            for (int j = 0; j < 8; j++) b[j] = Bs[k][tx * 8 + j];
            #pragma unroll
            for (int i = 0; i < 8; i++)
                #pragma unroll
                for (int j = 0; j < 8; j++) acc[i][j] += a[i] * b[j];
        }
        __syncthreads();
    }

    #pragma unroll
    for (int i = 0; i < 8; i++) {
        int row = m0 + ty * 8 + i;
        if (row >= M) continue;
        #pragma unroll
        for (int j = 0; j < 8; j++) {
            int col = n0 + tx * 8 + j;
            if (col >= N) continue;
            float v = acc[i][j];
            if (BIAS) v += bias[col];
            if (RELU) v = fmaxf(v, 0.f);
            size_t idx = (size_t)row * ldc + col;
            if (CMODE == 1) v += C[idx];
            if (CMODE == 2) {
                float o = C[idx] + cbias[col];
                o = o > 0.f ? o : (__expf(o) - 1.f);   // elu
                v += o;
            }
            C[idx] = v;
        }
    }
}

// ---------------- LayerNorm(+ReLU) in-place, C == blockDim == 256 ----------------
__global__ __launch_bounds__(256) void ln_relu_kernel(float* __restrict__ x,
                                                      const float* __restrict__ g,
                                                      const float* __restrict__ b) {
    const int C = 256;
    int row = blockIdx.x;
    int tid = threadIdx.x;
    int lane = tid & 63, wid = tid >> 6;
    __shared__ float red[4];
    float v = x[(size_t)row * C + tid];
    float s = wave_reduce_sum(v);
    if (lane == 0) red[wid] = s;
    __syncthreads();
    float m = (red[0] + red[1] + red[2] + red[3]) * (1.f / C);
    __syncthreads();
    float d = v - m;
    float s2 = wave_reduce_sum(d * d);
    if (lane == 0) red[wid] = s2;
    __syncthreads();
    float var = (red[0] + red[1] + red[2] + red[3]) * (1.f / C);
    float rs = rsqrtf(var + LN_EPS);
    float o = d * rs * g[tid] + b[tid];
    x[(size_t)row * C + tid] = fmaxf(o, 0.f);
}

// ---- fold attention vectors through W: qs[h*Cin+k] = sum_c W[k, h*Cout+c]*att_s[h,c]
__global__ void fold_att_kernel(const float* __restrict__ W,
                                const float* __restrict__ att_s,
                                const float* __restrict__ att_d,
                                float* __restrict__ qs, float* __restrict__ qd,
                                int Cin, int Cout, int H) {
    int t = blockIdx.x * blockDim.x + threadIdx.x;
    if (t >= H * Cin) return;
    int h = t / Cin, k = t - h * Cin;
    const float* wrow = W + (size_t)k * (H * Cout) + (size_t)h * Cout;
    const float* as = att_s + (size_t)h * Cout;
    const float* ad = att_d + (size_t)h * Cout;
    float ss = 0.f, sd = 0.f;
    for (int c = 0; c < Cout; c++) { float wv = wrow[c]; ss += wv * as[c]; sd += wv * ad[c]; }
    qs[t] = ss;
    qd[t] = sd;
}

// ---- a_s[n,h] = x[n,:] . qs[h,:]   (one wave per (n,h)) ----
__global__ __launch_bounds__(64) void att_scores_kernel(const float* __restrict__ x,
                                                        const float* __restrict__ qs,
                                                        const float* __restrict__ qd,
                                                        float* __restrict__ a_s,
                                                        float* __restrict__ a_d,
                                                        int H, int Cin) {
    int blk = blockIdx.x;
    int n = blk / H, hd = blk - (blk / H) * H;
    int lane = threadIdx.x;
    const float* xp = x + (size_t)n * Cin;
    const float* qsp = qs + (size_t)hd * Cin;
    const float* qdp = qd + (size_t)hd * Cin;
    float ss = 0.f, sd = 0.f;
    for (int k = lane; k < Cin; k += 64) {
        float xv = xp[k];
        ss += xv * qsp[k];
        sd += xv * qdp[k];
    }
    ss = wave_reduce_sum(ss);
    sd = wave_reduce_sum(sd);
    if (lane == 0) {
        a_s[(size_t)n * H + hd] = ss;
        a_d[(size_t)n * H + hd] = sd;
    }
}

// ---------------- order-preserving float<->uint for atomic max ----------------
__device__ __forceinline__ unsigned fenc(float f) {
    unsigned u = __float_as_uint(f);
    return (u & 0x80000000u) ? ~u : (u | 0x80000000u);
}
__device__ __forceinline__ float fdec(unsigned u) {
    return (u & 0x80000000u) ? __uint_as_float(u ^ 0x80000000u) : __uint_as_float(~u);
}

__device__ __forceinline__ void edge_sd(const int* ei, int e, int E, int& s, int& d) {
    if (e < E) { s = ei[e]; d = ei[E + e]; } else { s = d = e - E; }
}

__global__ void edge_max_kernel(const int* __restrict__ ei,
                                const float* __restrict__ a_s,
                                const float* __restrict__ a_d,
                                unsigned* __restrict__ emax,
                                int E, int Et, int H) {
    int t = blockIdx.x * blockDim.x + threadIdx.x;
    if (t >= Et * H) return;
    int e = t / H, hd = t - (t / H) * H;
    int s, d;
    edge_sd(ei, e, E, s, d);
    float v = a_s[(size_t)s * H + hd] + a_d[(size_t)d * H + hd];
    v = v > 0.f ? v : 0.2f * v;   // leaky_relu(0.2)
    atomicMax(&emax[(size_t)d * H + hd], fenc(v));
}

__global__ void edge_exp_kernel(const int* __restrict__ ei,
                                const float* __restrict__ a_s,
                                const float* __restrict__ a_d,
                                const unsigned* __restrict__ emax,
                                float* __restrict__ denom,
                                float* __restrict__ ee,
                                int E, int Et, int H) {
    int t = blockIdx.x * blockDim.x + threadIdx.x;
    if (t >= Et * H) return;
    int e = t / H, hd = t - (t / H) * H;
    int s, d;
    edge_sd(ei, e, E, s, d);
    float v = a_s[(size_t)s * H + hd] + a_d[(size_t)d * H + hd];
    v = v > 0.f ? v : 0.2f * v;
    float ex = __expf(v - fdec(emax[(size_t)d * H + hd]));
    ee[t] = ex;
    atomicAdd(&denom[(size_t)d * H + hd], ex);
}

// ---- block-1 path: aggregate in INPUT space for one head (Cin == 256) ----
__global__ __launch_bounds__(64) void edge_aggr_in_kernel(const int* __restrict__ ei,
                                                          const float* __restrict__ ee,
                                                          const float* __restrict__ denom,
                                                          const float* __restrict__ h1,
                                                          float* __restrict__ acc,
                                                          int E, int H, int hsel) {
    int e = blockIdx.x;
    int s, d;
    edge_sd(ei, e, E, s, d);
    float alpha = ee[(size_t)e * H + hsel] / (denom[(size_t)d * H + hsel] + 1e-16f);
    int lane = threadIdx.x;
    float4 v = *reinterpret_cast<const float4*>(h1 + (size_t)s * 256 + lane * 4);
    float* dst = acc + (size_t)d * 256 + lane * 4;
    atomicAdd(dst + 0, alpha * v.x);
    atomicAdd(dst + 1, alpha * v.y);
    atomicAdd(dst + 2, alpha * v.z);
    atomicAdd(dst + 3, alpha * v.w);
}

// ---- blocks 2/3: aggregate in OUTPUT space (F = H*C <= 256, F%4==0, C%4==0) ----
__global__ __launch_bounds__(64) void edge_aggr_out_kernel(const int* __restrict__ ei,
                                                           const float* __restrict__ ee,
                                                           const float* __restrict__ denom,
                                                           const float* __restrict__ g,
                                                           float* __restrict__ out,
                                                           int E, int H, int C, int F) {
    int e = blockIdx.x;
    int s, d;
    edge_sd(ei, e, E, s, d);
    int lane = threadIdx.x;
    int f = lane * 4;
    if (f >= F) return;
    int hd = f / C;
    float alpha = ee[(size_t)e * H + hd] / (denom[(size_t)d * H + hd] + 1e-16f);
    float4 v = *reinterpret_cast<const float4*>(g + (size_t)s * F + f);
    float* dst = out + (size_t)d * F + f;
    atomicAdd(dst + 0, alpha * v.x);
    atomicAdd(dst + 1, alpha * v.y);
    atomicAdd(dst + 2, alpha * v.z);
    atomicAdd(dst + 3, alpha * v.w);
}

// ---------------- final tiny GEMM: out[M,2] = A[M,64] @ W[64,2] + b ----------------
__global__ __launch_bounds__(256) void mlp2_kernel(const float* __restrict__ A,
                                                   const float* __restrict__ W,
                                                   const float* __restrict__ b,
                                                   float* __restrict__ out, int M) {
    __shared__ float w[128];
    __shared__ float bb[2];
    int tid = threadIdx.x;
    if (tid < 128) w[tid] = W[tid];
    if (tid < 2) bb[tid] = b[tid];
    __syncthreads();
    int row = blockIdx.x * 256 + tid;
    if (row >= M) return;
    float a0 = bb[0], a1 = bb[1];
    const float* ap = A + (size_t)row * 64;
    #pragma unroll 8
    for (int k = 0; k < 64; k++) {
        float av = ap[k];
        a0 += av * w[2 * k];
        a1 += av * w[2 * k + 1];
    }
    out[(size_t)row * 2] = a0;
    out[(size_t)row * 2 + 1] = a1;
}

extern "C" void kernel_launch(void* const* d_in, const int* in_sizes, int n_in,
                              void* d_out, int out_size, void* d_ws, size_t ws_size,
                              hipStream_t stream) {
    const float* x        = (const float*)d_in[0];
    const int*   ei       = (const int*)d_in[1];
    const float* enc_w1   = (const float*)d_in[2];
    const float* enc_b1   = (const float*)d_in[3];
    const float* ln1_g    = (const float*)d_in[4];
    const float* ln1_b    = (const float*)d_in[5];
    const float* enc_w2   = (const float*)d_in[6];
    const float* enc_b2   = (const float*)d_in[7];
    const float* ln2_g    = (const float*)d_in[8];
    const float* ln2_b    = (const float*)d_in[9];
    const float* w1       = (const float*)d_in[10];
    const float* att_src1 = (const float*)d_in[11];
    const float* att_dst1 = (const float*)d_in[12];
    const float* bias1    = (const float*)d_in[13];
    const float* res1_w   = (const float*)d_in[14];
    const float* res1_b   = (const float*)d_in[15];
    const float* w2       = (const float*)d_in[16];
    const float* att_src2 = (const float*)d_in[17];
    const float* att_dst2 = (const float*)d_in[18];
    const float* bias2    = (const float*)d_in[19];
    const float* res2_w   = (const float*)d_in[20];
    const float* res2_b   = (const float*)d_in[21];
    const float* w3       = (const float*)d_in[22];
    const float* att_src3 = (const float*)d_in[23];
    const float* att_dst3 = (const float*)d_in[24];
    const float* bias3    = (const float*)d_in[25];
    const float* res3_w   = (const float*)d_in[26];
    const float* res3_b   = (const float*)d_in[27];
    const float* mlp_w1   = (const float*)d_in[28];
    const float* mlp_b1   = (const float*)d_in[29];
    const float* mlp_w2   = (const float*)d_in[30];
    const float* mlp_b2   = (const float*)d_in[31];

    const int N  = in_sizes[0] / 405;   // 50000
    const int E  = in_sizes[1] / 2;     // 300000
    const int Et = E + N;               // + self loops

    // workspace layout (fp32 elements); peak ~316 MB
    float* A = (float*)d_ws;                       // N*256  (h0 / acc_h / G2 / G3 / M1)
    float* B = A + (size_t)N * 256;                // N*256  (h1 / O2->H3)
    float* C = B + (size_t)N * 256;                // N*1024 (O1->H2 / O3->H4)
    float* a_s = C + (size_t)N * 1024;             // N*4
    float* a_d = a_s + (size_t)N * 4;              // N*4
    float* denom = a_d + (size_t)N * 4;            // N*4
    unsigned* emax = (unsigned*)(denom + (size_t)N * 4); // N*4
    float* ee = (float*)emax + (size_t)N * 4;      // Et*4
    float* qs = ee + (size_t)Et * 4;               // 2048
    float* qd = qs + 2048;                         // 2048

    dim3 gEnc((256 + 127) / 128, (N + 127) / 128);

    // ---- JointEncoder ----
    gemm_kernel<true, false, 0><<<gEnc, 256, 0, stream>>>(x, enc_w1, enc_b1, nullptr, A, N, 256, 405, 405, 256, 256);
    ln_relu_kernel<<<N, 256, 0, stream>>>(A, ln1_g, ln1_b);
    gemm_kernel<true, false, 0><<<gEnc, 256, 0, stream>>>(A, enc_w2, enc_b2, nullptr, B, N, 256, 256, 256, 256, 256);
    ln_relu_kernel<<<N, 256, 0, stream>>>(B, ln2_g, ln2_b);

    // ---- Block 1: GAT 256 -> 4x256 concat (input-space per-head aggregation) ----
    {
        const int H = 4, Cin = 256, Cout = 256;
        fold_att_kernel<<<(H * Cin + 255) / 256, 256, 0, stream>>>(w1, att_src1, att_dst1, qs, qd, Cin, Cout, H);
        att_scores_kernel<<<N * H, 64, 0, stream>>>(B, qs, qd, a_s, a_d, H, Cin);
        hipMemsetAsync(emax, 0, (size_t)N * H * 4, stream);
        hipMemsetAsync(denom, 0, (size_t)N * H * 4, stream);
        int tot = Et * H;
        edge_max_kernel<<<(tot + 255) / 256, 256, 0, stream>>>(ei, a_s, a_d, emax, E, Et, H);
        edge_exp_kernel<<<(tot + 255) / 256, 256, 0, stream>>>(ei, a_s, a_d, emax, denom, ee, E, Et, H);
        for (int h = 0; h < H; h++) {
            hipMemsetAsync(A, 0, (size_t)N * 256 * 4, stream);
            edge_aggr_in_kernel<<<Et, 64, 0, stream>>>(ei, ee, denom, B, A, E, H, h);
            // C[:, h*256:(h+1)*256] = A @ w1[:, h*256:(h+1)*256]
            dim3 gg((256 + 127) / 128, (N + 127) / 128);
            gemm_kernel<false, false, 0><<<gg, 256, 0, stream>>>(A, w1 + (size_t)h * 256, nullptr, nullptr,
                                                                 C + (size_t)h * 256, N, 256, 256, 256, 1024, 1024);
        }
        // C = elu(C + bias1) + B @ res1_w + res1_b   -> H2
        dim3 gg((1024 + 127) / 128, (N + 127) / 128);
        gemm_kernel<true, false, 2><<<gg, 256, 0, stream>>>(B, res1_w, res1_b, bias1, C, N, 1024, 256, 256, 1024, 1024);
    }

    // ---- Block 2: GAT 1024 -> 2x96 concat (output-space aggregation) ----
    {
        const int H = 2, Cin = 1024, Cout = 96, F = H * Cout;
        fold_att_kernel<<<(H * Cin + 255) / 256, 256, 0, stream>>>(w2, att_src2, att_dst2, qs, qd, Cin, Cout, H);
        att_scores_kernel<<<N * H, 64, 0, stream>>>(C, qs, qd, a_s, a_d, H, Cin);
        // G2 = C @ w2 -> A [N,192]
        dim3 gg((F + 127) / 128, (N + 127) / 128);
        gemm_kernel<false, false, 0><<<gg, 256, 0, stream>>>(C, w2, nullptr, nullptr, A, N, F, Cin, Cin, F, F);
        hipMemsetAsync(emax, 0, (size_t)N * H * 4, stream);
        hipMemsetAsync(denom, 0, (size_t)N * H * 4, stream);
        int tot = Et * H;
        edge_max_kernel<<<(tot + 255) / 256, 256, 0, stream>>>(ei, a_s, a_d, emax, E, Et, H);
        edge_exp_kernel<<<(tot + 255) / 256, 256, 0, stream>>>(ei, a_s, a_d, emax, denom, ee, E, Et, H);
        hipMemsetAsync(B, 0, (size_t)N * F * 4, stream);
        edge_aggr_out_kernel<<<Et, 64, 0, stream>>>(ei, ee, denom, A, B, E, H, Cout, F);
        // B = elu(B + bias2) + C @ res2_w + res2_b   -> H3
        gemm_kernel<true, false, 2><<<gg, 256, 0, stream>>>(C, res2_w, res2_b, bias2, B, N, F, Cin, Cin, F, F);
    }

    // ---- Block 3: GAT 192 -> 1x128 (no concat, output-space aggregation) ----
    {
        const int H = 1, Cin = 192, Cout = 128, F = 128;
        fold_att_kernel<<<(H * Cin + 255) / 256, 256, 0, stream>>>(w3, att_src3, att_dst3, qs, qd, Cin, Cout, H);
        att_scores_kernel<<<N * H, 64, 0, stream>>>(B, qs, qd, a_s, a_d, H, Cin);
        // G3 = B @ w3 -> A [N,128]
        dim3 gg((F + 127) / 128, (N + 127) / 128);
        gemm_kernel<false, false, 0><<<gg, 256, 0, stream>>>(B, w3, nullptr, nullptr, A, N, F, Cin, Cin, F, F);
        hipMemsetAsync(emax, 0, (size_t)N * H * 4, stream);
        hipMemsetAsync(denom, 0, (size_t)N * H * 4, stream);
        int tot = Et * H;
        edge_max_kernel<<<(tot + 255) / 256, 256, 0, stream>>>(ei, a_s, a_d, emax, E, Et, H);
        edge_exp_kernel<<<(tot + 255) / 256, 256, 0, stream>>>(ei, a_s, a_d, emax, denom, ee, E, Et, H);
        hipMemsetAsync(C, 0, (size_t)N * F * 4, stream);
        edge_aggr_out_kernel<<<Et, 64, 0, stream>>>(ei, ee, denom, A, C, E, H, Cout, F);
        // C = elu(C + bias3) + B @ res3_w + res3_b   -> H4
        gemm_kernel<true, false, 2><<<gg, 256, 0, stream>>>(B, res3_w, res3_b, bias3, C, N, F, Cin, Cin, F, F);
    }

    // ---- MLP head ----
    {
        dim3 gg((64 + 127) / 128, (N + 127) / 128);
        gemm_kernel<true, true, 0><<<gg, 256, 0, stream>>>(C, mlp_w1, mlp_b1, nullptr, A, N, 64, 128, 128, 64, 64);
    }
    mlp2_kernel<<<(N + 255) / 256, 256, 0, stream>>>(A, mlp_w2, mlp_b2, (float*)d_out, N);
}

// Round 3
// 4055.228 us; speedup vs baseline: 2.4193x; 2.4193x over previous
//
#include <hip/hip_runtime.h>
#include <cstddef>

#define LN_EPS 1e-5f

__device__ __forceinline__ float wave_reduce_sum(float v) {
    #pragma unroll
    for (int off = 32; off > 0; off >>= 1) v += __shfl_down(v, off, 64);
    return v;
}
__device__ __forceinline__ float wave_allreduce_max(float v) {
    #pragma unroll
    for (int off = 32; off > 0; off >>= 1) v = fmaxf(v, __shfl_xor(v, off, 64));
    return v;
}
__device__ __forceinline__ float wave_allreduce_sum(float v) {
    #pragma unroll
    for (int off = 32; off > 0; off >>= 1) v += __shfl_xor(v, off, 64);
    return v;
}

// ---------------- GEMM: C = A[MxK] @ B[KxN] (+bias) (+relu) (+epilogue) ----------
// CMODE: 0 = overwrite, 1 = accumulate (C += gemm), 2 = C = elu(Cold + cbias) + gemm(+bias)
template<bool BIAS, bool RELU, int CMODE>
__global__ __launch_bounds__(256) void gemm_kernel(const float* __restrict__ A,
                                                   const float* __restrict__ B,
                                                   const float* __restrict__ bias,
                                                   const float* __restrict__ cbias,
                                                   float* __restrict__ C,
                                                   int M, int N, int K,
                                                   int lda, int ldb, int ldc) {
    const int BM = 128, BN = 128, BK = 16;
    __shared__ float As[BK][BM + 4];
    __shared__ float Bs[BK][BN];
    int tid = threadIdx.x;
    int tx = tid & 15, ty = tid >> 4;
    int m0 = blockIdx.y * BM, n0 = blockIdx.x * BN;
    float acc[8][8] = {};

    for (int k0 = 0; k0 < K; k0 += BK) {
        #pragma unroll
        for (int i = 0; i < 2; i++) {
            int f = tid + i * 256;
            int row = f >> 2;
            int kc = (f & 3) * 4;
            int gr = m0 + row;
            #pragma unroll
            for (int j = 0; j < 4; j++) {
                int gk = k0 + kc + j;
                float v = (gr < M && gk < K) ? A[(size_t)gr * lda + gk] : 0.f;
                As[kc + j][row] = v;
            }
        }
        #pragma unroll
        for (int i = 0; i < 2; i++) {
            int f = tid + i * 256;
            int kk = f >> 5;
            int nc = (f & 31) * 4;
            int gk = k0 + kk, gn = n0 + nc;
            float4 v = make_float4(0.f, 0.f, 0.f, 0.f);
            if (gk < K && gn < N) v = *reinterpret_cast<const float4*>(&B[(size_t)gk * ldb + gn]);
            *reinterpret_cast<float4*>(&Bs[kk][nc]) = v;
        }
        __syncthreads();
        #pragma unroll
        for (int k = 0; k < BK; k++) {
            float a[8], b[8];
            #pragma unroll
            for (int i = 0; i < 8; i++) a[i] = As[k][ty * 8 + i];
            #pragma unroll
            for (int j = 0; j < 8; j++) b[j] = Bs[k][tx * 8 + j];
            #pragma unroll
            for (int i = 0; i < 8; i++)
                #pragma unroll
                for (int j = 0; j < 8; j++) acc[i][j] += a[i] * b[j];
        }
        __syncthreads();
    }

    #pragma unroll
    for (int i = 0; i < 8; i++) {
        int row = m0 + ty * 8 + i;
        if (row >= M) continue;
        #pragma unroll
        for (int j = 0; j < 8; j++) {
            int col = n0 + tx * 8 + j;
            if (col >= N) continue;
            float v = acc[i][j];
            if (BIAS) v += bias[col];
            if (RELU) v = fmaxf(v, 0.f);
            size_t idx = (size_t)row * ldc + col;
            if (CMODE == 1) v += C[idx];
            if (CMODE == 2) {
                float o = C[idx] + cbias[col];
                o = o > 0.f ? o : (__expf(o) - 1.f);   // elu
                v += o;
            }
            C[idx] = v;
        }
    }
}

// ---------------- LayerNorm(+ReLU) in-place, C == blockDim == 256 ----------------
__global__ __launch_bounds__(256) void ln_relu_kernel(float* __restrict__ x,
                                                      const float* __restrict__ g,
                                                      const float* __restrict__ b) {
    const int C = 256;
    int row = blockIdx.x;
    int tid = threadIdx.x;
    int lane = tid & 63, wid = tid >> 6;
    __shared__ float red[4];
    float v = x[(size_t)row * C + tid];
    float s = wave_reduce_sum(v);
    if (lane == 0) red[wid] = s;
    __syncthreads();
    float m = (red[0] + red[1] + red[2] + red[3]) * (1.f / C);
    __syncthreads();
    float d = v - m;
    float s2 = wave_reduce_sum(d * d);
    if (lane == 0) red[wid] = s2;
    __syncthreads();
    float var = (red[0] + red[1] + red[2] + red[3]) * (1.f / C);
    float rs = rsqrtf(var + LN_EPS);
    float o = d * rs * g[tid] + b[tid];
    x[(size_t)row * C + tid] = fmaxf(o, 0.f);
}

// ---- fold attention vectors through W: qs[h*Cin+k] = sum_c W[k, h*Cout+c]*att_s[h,c]
__global__ void fold_att_kernel(const float* __restrict__ W,
                                const float* __restrict__ att_s,
                                const float* __restrict__ att_d,
                                float* __restrict__ qs, float* __restrict__ qd,
                                int Cin, int Cout, int H) {
    int t = blockIdx.x * blockDim.x + threadIdx.x;
    if (t >= H * Cin) return;
    int h = t / Cin, k = t - h * Cin;
    const float* wrow = W + (size_t)k * (H * Cout) + (size_t)h * Cout;
    const float* as = att_s + (size_t)h * Cout;
    const float* ad = att_d + (size_t)h * Cout;
    float ss = 0.f, sd = 0.f;
    for (int c = 0; c < Cout; c++) { float wv = wrow[c]; ss += wv * as[c]; sd += wv * ad[c]; }
    qs[t] = ss;
    qd[t] = sd;
}

// ---- a_s[n,h] = x[n,:] . qs[h,:]   (one wave per (n,h)) ----
__global__ __launch_bounds__(64) void att_scores_kernel(const float* __restrict__ x,
                                                        const float* __restrict__ qs,
                                                        const float* __restrict__ qd,
                                                        float* __restrict__ a_s,
                                                        float* __restrict__ a_d,
                                                        int H, int Cin) {
    int blk = blockIdx.x;
    int n = blk / H, hd = blk - (blk / H) * H;
    int lane = threadIdx.x;
    const float* xp = x + (size_t)n * Cin;
    const float* qsp = qs + (size_t)hd * Cin;
    const float* qdp = qd + (size_t)hd * Cin;
    float ss = 0.f, sd = 0.f;
    for (int k = lane; k < Cin; k += 64) {
        float xv = xp[k];
        ss += xv * qsp[k];
        sd += xv * qdp[k];
    }
    ss = wave_reduce_sum(ss);
    sd = wave_reduce_sum(sd);
    if (lane == 0) {
        a_s[(size_t)n * H + hd] = ss;
        a_d[(size_t)n * H + hd] = sd;
    }
}

// ================= CSR construction (dst-grouped), built once per launch =========
__device__ __forceinline__ void edge_sd(const int* ei, int e, int E, int& s, int& d) {
    if (e < E) { s = ei[e]; d = ei[E + e]; } else { s = d = e - E; }
}

__global__ void deg_kernel(const int* __restrict__ ei, int* __restrict__ deg, int E, int Et) {
    int e = blockIdx.x * blockDim.x + threadIdx.x;
    if (e >= Et) return;
    int s, d; edge_sd(ei, e, E, s, d);
    atomicAdd(&deg[d], 1);
}

__global__ __launch_bounds__(256) void scan1_kernel(const int* __restrict__ deg,
                                                    int* __restrict__ incl,
                                                    int* __restrict__ part, int N) {
    __shared__ int sd[256];
    int t = threadIdx.x;
    int i = blockIdx.x * 256 + t;
    int v = (i < N) ? deg[i] : 0;
    sd[t] = v; __syncthreads();
    #pragma unroll
    for (int o = 1; o < 256; o <<= 1) {
        int x = (t >= o) ? sd[t - o] : 0;
        __syncthreads();
        sd[t] += x;
        __syncthreads();
    }
    if (i < N) incl[i] = sd[t];
    if (t == 255) part[blockIdx.x] = sd[255];
}

__global__ __launch_bounds__(256) void scan2_kernel(int* __restrict__ part, int nb) {
    __shared__ int sd[256];
    int t = threadIdx.x;
    int v = (t < nb) ? part[t] : 0;
    sd[t] = v; __syncthreads();
    #pragma unroll
    for (int o = 1; o < 256; o <<= 1) {
        int x = (t >= o) ? sd[t - o] : 0;
        __syncthreads();
        sd[t] += x;
        __syncthreads();
    }
    if (t < nb) part[t] = sd[t];
}

__global__ void scan3_kernel(const int* __restrict__ incl, const int* __restrict__ deg,
                             const int* __restrict__ part, int* __restrict__ row_ptr, int N) {
    int i = blockIdx.x * blockDim.x + threadIdx.x;
    if (i >= N) return;
    int off = (blockIdx.x > 0) ? part[blockIdx.x - 1] : 0;
    row_ptr[i] = incl[i] - deg[i] + off;
}

__global__ void fill_kernel(const int* __restrict__ ei, const int* __restrict__ row_ptr,
                            int* __restrict__ cur, int* __restrict__ csr_src, int E, int Et) {
    int e = blockIdx.x * blockDim.x + threadIdx.x;
    if (e >= Et) return;
    int s, d; edge_sd(ei, e, E, s, d);
    int pos = row_ptr[d] + atomicAdd(&cur[d], 1);
    csr_src[pos] = s;
}

// ======= per-dst softmax stats: computes normalized alpha per CSR edge slot ======
template<int H>
__global__ __launch_bounds__(64) void stats_kernel(const int* __restrict__ row_ptr,
                                                   const int* __restrict__ deg,
                                                   const int* __restrict__ csr_src,
                                                   const float* __restrict__ a_s,
                                                   const float* __restrict__ a_d,
                                                   float* __restrict__ alpha) {
    int d = blockIdx.x;
    int lane = threadIdx.x;
    int base = row_ptr[d], dg = deg[d];
    float ad[H];
    #pragma unroll
    for (int h = 0; h < H; h++) ad[h] = a_d[(size_t)d * H + h];

    float mx[H];
    #pragma unroll
    for (int h = 0; h < H; h++) mx[h] = -1e30f;
    for (int j = lane; j < dg; j += 64) {
        int s = csr_src[base + j];
        #pragma unroll
        for (int h = 0; h < H; h++) {
            float sc = a_s[(size_t)s * H + h] + ad[h];
            sc = sc > 0.f ? sc : 0.2f * sc;
            mx[h] = fmaxf(mx[h], sc);
        }
    }
    #pragma unroll
    for (int h = 0; h < H; h++) mx[h] = wave_allreduce_max(mx[h]);

    float sm[H];
    #pragma unroll
    for (int h = 0; h < H; h++) sm[h] = 0.f;
    for (int j = lane; j < dg; j += 64) {
        int s = csr_src[base + j];
        #pragma unroll
        for (int h = 0; h < H; h++) {
            float sc = a_s[(size_t)s * H + h] + ad[h];
            sc = sc > 0.f ? sc : 0.2f * sc;
            sm[h] += __expf(sc - mx[h]);
        }
    }
    float rd[H];
    #pragma unroll
    for (int h = 0; h < H; h++) {
        sm[h] = wave_allreduce_sum(sm[h]);
        rd[h] = 1.f / (sm[h] + 1e-16f);
    }

    for (int j = lane; j < dg; j += 64) {
        int s = csr_src[base + j];
        #pragma unroll
        for (int h = 0; h < H; h++) {
            float sc = a_s[(size_t)s * H + h] + ad[h];
            sc = sc > 0.f ? sc : 0.2f * sc;
            alpha[(size_t)(base + j) * H + h] = __expf(sc - mx[h]) * rd[h];
        }
    }
}

// ==== block-1: gather-aggregate in input space for one head (Cin = 256) ==========
__global__ __launch_bounds__(256) void aggr_b1_kernel(const int* __restrict__ row_ptr,
                                                      const int* __restrict__ deg,
                                                      const int* __restrict__ csr_src,
                                                      const float* __restrict__ alpha,
                                                      const float* __restrict__ h1,
                                                      float* __restrict__ out, int hsel) {
    int d = blockIdx.x;
    int c = threadIdx.x;
    int base = row_ptr[d], dg = deg[d];
    float acc = 0.f;
    for (int j = 0; j < dg; j++) {
        int s = csr_src[base + j];
        float a = alpha[(size_t)(base + j) * 4 + hsel];
        acc += a * h1[(size_t)s * 256 + c];
    }
    out[(size_t)d * 256 + c] = acc;
}

// ==== blocks 2/3: gather-aggregate in output space; block = F threads ============
template<int H, int C, int F>
__global__ void aggr_flat_kernel(const int* __restrict__ row_ptr,
                                 const int* __restrict__ deg,
                                 const int* __restrict__ csr_src,
                                 const float* __restrict__ alpha,
                                 const float* __restrict__ g,
                                 float* __restrict__ out) {
    int d = blockIdx.x;
    int f = threadIdx.x;
    int hd = f / C;
    int base = row_ptr[d], dg = deg[d];
    float acc = 0.f;
    for (int j = 0; j < dg; j++) {
        int s = csr_src[base + j];
        float a = alpha[(size_t)(base + j) * H + hd];
        acc += a * g[(size_t)s * F + f];
    }
    out[(size_t)d * F + f] = acc;
}

// ---------------- final tiny GEMM: out[M,2] = A[M,64] @ W[64,2] + b ----------------
__global__ __launch_bounds__(256) void mlp2_kernel(const float* __restrict__ A,
                                                   const float* __restrict__ W,
                                                   const float* __restrict__ b,
                                                   float* __restrict__ out, int M) {
    __shared__ float w[128];
    __shared__ float bb[2];
    int tid = threadIdx.x;
    if (tid < 128) w[tid] = W[tid];
    if (tid < 2) bb[tid] = b[tid];
    __syncthreads();
    int row = blockIdx.x * 256 + tid;
    if (row >= M) return;
    float a0 = bb[0], a1 = bb[1];
    const float* ap = A + (size_t)row * 64;
    #pragma unroll 8
    for (int k = 0; k < 64; k++) {
        float av = ap[k];
        a0 += av * w[2 * k];
        a1 += av * w[2 * k + 1];
    }
    out[(size_t)row * 2] = a0;
    out[(size_t)row * 2 + 1] = a1;
}

extern "C" void kernel_launch(void* const* d_in, const int* in_sizes, int n_in,
                              void* d_out, int out_size, void* d_ws, size_t ws_size,
                              hipStream_t stream) {
    const float* x        = (const float*)d_in[0];
    const int*   ei       = (const int*)d_in[1];
    const float* enc_w1   = (const float*)d_in[2];
    const float* enc_b1   = (const float*)d_in[3];
    const float* ln1_g    = (const float*)d_in[4];
    const float* ln1_b    = (const float*)d_in[5];
    const float* enc_w2   = (const float*)d_in[6];
    const float* enc_b2   = (const float*)d_in[7];
    const float* ln2_g    = (const float*)d_in[8];
    const float* ln2_b    = (const float*)d_in[9];
    const float* w1       = (const float*)d_in[10];
    const float* att_src1 = (const float*)d_in[11];
    const float* att_dst1 = (const float*)d_in[12];
    const float* bias1    = (const float*)d_in[13];
    const float* res1_w   = (const float*)d_in[14];
    const float* res1_b   = (const float*)d_in[15];
    const float* w2       = (const float*)d_in[16];
    const float* att_src2 = (const float*)d_in[17];
    const float* att_dst2 = (const float*)d_in[18];
    const float* bias2    = (const float*)d_in[19];
    const float* res2_w   = (const float*)d_in[20];
    const float* res2_b   = (const float*)d_in[21];
    const float* w3       = (const float*)d_in[22];
    const float* att_src3 = (const float*)d_in[23];
    const float* att_dst3 = (const float*)d_in[24];
    const float* bias3    = (const float*)d_in[25];
    const float* res3_w   = (const float*)d_in[26];
    const float* res3_b   = (const float*)d_in[27];
    const float* mlp_w1   = (const float*)d_in[28];
    const float* mlp_b1   = (const float*)d_in[29];
    const float* mlp_w2   = (const float*)d_in[30];
    const float* mlp_b2   = (const float*)d_in[31];

    const int N  = in_sizes[0] / 405;   // 50000
    const int E  = in_sizes[1] / 2;     // 300000
    const int Et = E + N;               // + self loops
    const int NB = (N + 255) / 256;     // scan blocks (196 <= 256)

    // workspace layout (fp32 elements); peak ~317 MB
    float* A = (float*)d_ws;                       // N*256
    float* B = A + (size_t)N * 256;                // N*256
    float* C = B + (size_t)N * 256;                // N*1024
    float* a_s = C + (size_t)N * 1024;             // N*4
    float* a_d = a_s + (size_t)N * 4;              // N*4
    float* alpha = a_d + (size_t)N * 4;            // Et*4
    float* qs = alpha + (size_t)Et * 4;            // 2048
    float* qd = qs + 2048;                         // 2048
    int* deg     = (int*)(qd + 2048);              // N
    int* cur     = deg + N;                        // N
    int* row_ptr = cur + N;                        // N
    int* incl    = row_ptr + N;                    // N
    int* part    = incl + N;                       // 256
    int* csr_src = part + 256;                     // Et

    // ---- CSR build (uses only ei; reused by all 3 layers) ----
    hipMemsetAsync(deg, 0, (size_t)N * 8, stream);   // deg + cur
    deg_kernel<<<(Et + 255) / 256, 256, 0, stream>>>(ei, deg, E, Et);
    scan1_kernel<<<NB, 256, 0, stream>>>(deg, incl, part, N);
    scan2_kernel<<<1, 256, 0, stream>>>(part, NB);
    scan3_kernel<<<NB, 256, 0, stream>>>(incl, deg, part, row_ptr, N);
    fill_kernel<<<(Et + 255) / 256, 256, 0, stream>>>(ei, row_ptr, cur, csr_src, E, Et);

    dim3 gEnc((256 + 127) / 128, (N + 127) / 128);

    // ---- JointEncoder ----
    gemm_kernel<true, false, 0><<<gEnc, 256, 0, stream>>>(x, enc_w1, enc_b1, nullptr, A, N, 256, 405, 405, 256, 256);
    ln_relu_kernel<<<N, 256, 0, stream>>>(A, ln1_g, ln1_b);
    gemm_kernel<true, false, 0><<<gEnc, 256, 0, stream>>>(A, enc_w2, enc_b2, nullptr, B, N, 256, 256, 256, 256, 256);
    ln_relu_kernel<<<N, 256, 0, stream>>>(B, ln2_g, ln2_b);

    // ---- Block 1: GAT 256 -> 4x256 concat (input-space per-head aggregation) ----
    {
        const int H = 4, Cin = 256;
        fold_att_kernel<<<(H * Cin + 255) / 256, 256, 0, stream>>>(w1, att_src1, att_dst1, qs, qd, Cin, 256, H);
        att_scores_kernel<<<N * H, 64, 0, stream>>>(B, qs, qd, a_s, a_d, H, Cin);
        stats_kernel<4><<<N, 64, 0, stream>>>(row_ptr, deg, csr_src, a_s, a_d, alpha);
        for (int h = 0; h < H; h++) {
            aggr_b1_kernel<<<N, 256, 0, stream>>>(row_ptr, deg, csr_src, alpha, B, A, h);
            dim3 gg((256 + 127) / 128, (N + 127) / 128);
            gemm_kernel<false, false, 0><<<gg, 256, 0, stream>>>(A, w1 + (size_t)h * 256, nullptr, nullptr,
                                                                 C + (size_t)h * 256, N, 256, 256, 256, 1024, 1024);
        }
        // C = elu(C + bias1) + B @ res1_w + res1_b   -> H2
        dim3 gg((1024 + 127) / 128, (N + 127) / 128);
        gemm_kernel<true, false, 2><<<gg, 256, 0, stream>>>(B, res1_w, res1_b, bias1, C, N, 1024, 256, 256, 1024, 1024);
    }

    // ---- Block 2: GAT 1024 -> 2x96 concat (output-space aggregation) ----
    {
        const int H = 2, Cin = 1024, Cout = 96, F = H * Cout;
        fold_att_kernel<<<(H * Cin + 255) / 256, 256, 0, stream>>>(w2, att_src2, att_dst2, qs, qd, Cin, Cout, H);
        att_scores_kernel<<<N * H, 64, 0, stream>>>(C, qs, qd, a_s, a_d, H, Cin);
        dim3 gg((F + 127) / 128, (N + 127) / 128);
        gemm_kernel<false, false, 0><<<gg, 256, 0, stream>>>(C, w2, nullptr, nullptr, A, N, F, Cin, Cin, F, F);
        stats_kernel<2><<<N, 64, 0, stream>>>(row_ptr, deg, csr_src, a_s, a_d, alpha);
        aggr_flat_kernel<2, 96, 192><<<N, 192, 0, stream>>>(row_ptr, deg, csr_src, alpha, A, B);
        // B = elu(B + bias2) + C @ res2_w + res2_b   -> H3
        gemm_kernel<true, false, 2><<<gg, 256, 0, stream>>>(C, res2_w, res2_b, bias2, B, N, F, Cin, Cin, F, F);
    }

    // ---- Block 3: GAT 192 -> 1x128 (no concat, output-space aggregation) ----
    {
        const int H = 1, Cin = 192, Cout = 128, F = 128;
        fold_att_kernel<<<(H * Cin + 255) / 256, 256, 0, stream>>>(w3, att_src3, att_dst3, qs, qd, Cin, Cout, H);
        att_scores_kernel<<<N * H, 64, 0, stream>>>(B, qs, qd, a_s, a_d, H, Cin);
        dim3 gg((F + 127) / 128, (N + 127) / 128);
        gemm_kernel<false, false, 0><<<gg, 256, 0, stream>>>(B, w3, nullptr, nullptr, A, N, F, Cin, Cin, F, F);
        stats_kernel<1><<<N, 64, 0, stream>>>(row_ptr, deg, csr_src, a_s, a_d, alpha);
        aggr_flat_kernel<1, 128, 128><<<N, 128, 0, stream>>>(row_ptr, deg, csr_src, alpha, A, C);
        // C = elu(C + bias3) + B @ res3_w + res3_b   -> H4
        gemm_kernel<true, false, 2><<<gg, 256, 0, stream>>>(B, res3_w, res3_b, bias3, C, N, F, Cin, Cin, F, F);
    }

    // ---- MLP head ----
    {
        dim3 gg((64 + 127) / 128, (N + 127) / 128);
        gemm_kernel<true, true, 0><<<gg, 256, 0, stream>>>(C, mlp_w1, mlp_b1, nullptr, A, N, 64, 128, 128, 64, 64);
    }
    mlp2_kernel<<<(N + 255) / 256, 256, 0, stream>>>(A, mlp_w2, mlp_b2, (float*)d_out, N);
}

// Round 4
// 1302.693 us; speedup vs baseline: 7.5313x; 3.1130x over previous
//
#include <hip/hip_runtime.h>
#include <cstddef>

#define LN_EPS 1e-5f

typedef __bf16 bf16x8 __attribute__((ext_vector_type(8)));
typedef float  f32x4  __attribute__((ext_vector_type(4)));

__device__ __forceinline__ float b2f(ushort h) {
    return __uint_as_float(((unsigned)h) << 16);
}
__device__ __forceinline__ ushort f2b(float f) {   // RNE
    unsigned u = __float_as_uint(f);
    return (ushort)((u + 0x7fffu + ((u >> 16) & 1u)) >> 16);
}

__device__ __forceinline__ float wave_reduce_sum(float v) {
    #pragma unroll
    for (int off = 32; off > 0; off >>= 1) v += __shfl_down(v, off, 64);
    return v;
}
__device__ __forceinline__ float wave_allreduce_max(float v) {
    #pragma unroll
    for (int off = 32; off > 0; off >>= 1) v = fmaxf(v, __shfl_xor(v, off, 64));
    return v;
}
__device__ __forceinline__ float wave_allreduce_sum(float v) {
    #pragma unroll
    for (int off = 32; off > 0; off >>= 1) v += __shfl_xor(v, off, 64);
    return v;
}

// ============== bf16 MFMA GEMM: C = A[M,K]@B  (B given as BT[Npad,K] bf16) =======
// EPI 0: fp32 out = acc (+bias)          (enc1/enc2/big2/big3)
// EPI 1: bf16 out = acc                  (block1 per-head slices)
// EPI 2: bf16 out = acc + bias + elu(Cold_b + cbias)   (res1 -> H2)
// EPI 3: bf16 out = relu(acc + bias)     (mlp1)
// K must be a multiple of 32; lda/ldbt rows 16B-aligned; BT zero-padded to grid.x*128 rows.
template<int EPI>
__global__ __launch_bounds__(256) void bgemm(const ushort* __restrict__ A,
                                             const ushort* __restrict__ BT,
                                             const float* __restrict__ bias,
                                             const float* __restrict__ cbias,
                                             const ushort* __restrict__ Coldb, int ldco,
                                             void* __restrict__ out, int ldc,
                                             int M, int Ncols, int K, int lda) {
    __shared__ ushort As[128 * 32];
    __shared__ ushort Bs[128 * 32];
    const int tid = threadIdx.x;
    const int m0 = blockIdx.y * 128, n0 = blockIdx.x * 128;
    const int w = tid >> 6, lane = tid & 63;
    const int wr = (w >> 1) * 64, wc = (w & 1) * 64;
    const int quad = lane >> 4, l15 = lane & 15;

    f32x4 acc[4][4] = {};

    for (int k0 = 0; k0 < K; k0 += 32) {
        #pragma unroll
        for (int i = 0; i < 2; i++) {
            int f = tid + i * 256;
            int row = f >> 2, seg = (f & 3) * 8;
            uint4 v = make_uint4(0u, 0u, 0u, 0u);
            int gr = m0 + row;
            if (gr < M) v = *reinterpret_cast<const uint4*>(A + (size_t)gr * lda + k0 + seg);
            *reinterpret_cast<uint4*>(&As[row * 32 + seg]) = v;
        }
        #pragma unroll
        for (int i = 0; i < 2; i++) {
            int f = tid + i * 256;
            int row = f >> 2, seg = (f & 3) * 8;
            uint4 v = *reinterpret_cast<const uint4*>(BT + (size_t)(n0 + row) * K + k0 + seg);
            *reinterpret_cast<uint4*>(&Bs[row * 32 + seg]) = v;
        }
        __syncthreads();
        bf16x8 af[4], bfr[4];
        #pragma unroll
        for (int i = 0; i < 4; i++)
            af[i] = *reinterpret_cast<const bf16x8*>(&As[(wr + i * 16 + l15) * 32 + quad * 8]);
        #pragma unroll
        for (int j = 0; j < 4; j++)
            bfr[j] = *reinterpret_cast<const bf16x8*>(&Bs[(wc + j * 16 + l15) * 32 + quad * 8]);
        #pragma unroll
        for (int i = 0; i < 4; i++)
            #pragma unroll
            for (int j = 0; j < 4; j++)
                acc[i][j] = __builtin_amdgcn_mfma_f32_16x16x32_bf16(af[i], bfr[j], acc[i][j], 0, 0, 0);
        __syncthreads();
    }

    #pragma unroll
    for (int i = 0; i < 4; i++) {
        #pragma unroll
        for (int j = 0; j < 4; j++) {
            int col = n0 + wc + j * 16 + l15;
            if (col >= Ncols) continue;
            #pragma unroll
            for (int r = 0; r < 4; r++) {
                int row = m0 + wr + i * 16 + quad * 4 + r;
                if (row >= M) continue;
                float v = acc[i][j][r];
                size_t idx = (size_t)row * ldc + col;
                if (EPI == 0) {
                    if (bias) v += bias[col];
                    ((float*)out)[idx] = v;
                } else if (EPI == 1) {
                    ((ushort*)out)[idx] = f2b(v);
                } else if (EPI == 2) {
                    float o = b2f(Coldb[(size_t)row * ldco + col]) + cbias[col];
                    o = o > 0.f ? o : (__expf(o) - 1.f);
                    ((ushort*)out)[idx] = f2b(v + bias[col] + o);
                } else {
                    ((ushort*)out)[idx] = f2b(fmaxf(v + bias[col], 0.f));
                }
            }
        }
    }
}

// ---------------- conversions / weight prep ----------------
__global__ void conv_pad_x_kernel(const float* __restrict__ x, ushort* __restrict__ xb, int N) {
    int t = blockIdx.x * 256 + threadIdx.x;
    if (t >= N * 416) return;
    int n = t / 416, k = t - n * 416;
    xb[t] = f2b(k < 405 ? x[(size_t)n * 405 + k] : 0.f);
}

// dst[n][k] (bf16, rows x Kpad) = src[k][n + col_off], zero outside K/Nreal
__global__ void prep_bt_kernel(const float* __restrict__ src, ushort* __restrict__ dst,
                               int K, int Nreal, int Kpad, int rows, int ldsrc, int col_off) {
    int t = blockIdx.x * 256 + threadIdx.x;
    if (t >= rows * Kpad) return;
    int n = t / Kpad, k = t - n * Kpad;
    float v = (k < K && n < Nreal) ? src[(size_t)k * ldsrc + n + col_off] : 0.f;
    dst[t] = f2b(v);
}

__global__ void conv_bf16_kernel(const float* __restrict__ src, ushort* __restrict__ dst, int n) {
    int i = blockIdx.x * 256 + threadIdx.x;
    if (i < n) dst[i] = f2b(src[i]);
}

// fp32 slice [M,F] of src(ld=lds) -> bf16 dst
__global__ void slice_b16_kernel(const float* __restrict__ src, int lds,
                                 ushort* __restrict__ dst, int F, int total) {
    int i = blockIdx.x * 256 + threadIdx.x;
    if (i >= total) return;
    dst[i] = f2b(src[(size_t)(i / F) * lds + (i % F)]);
}

// ---------------- LayerNorm(+ReLU): fp32 in, bf16 out; C == 256 ----------------
__global__ __launch_bounds__(256) void ln_relu_kernel(const float* __restrict__ x,
                                                      const float* __restrict__ g,
                                                      const float* __restrict__ b,
                                                      ushort* __restrict__ out) {
    const int C = 256;
    int row = blockIdx.x;
    int tid = threadIdx.x;
    int lane = tid & 63, wid = tid >> 6;
    __shared__ float red[4];
    float v = x[(size_t)row * C + tid];
    float s = wave_reduce_sum(v);
    if (lane == 0) red[wid] = s;
    __syncthreads();
    float m = (red[0] + red[1] + red[2] + red[3]) * (1.f / C);
    __syncthreads();
    float d = v - m;
    float s2 = wave_reduce_sum(d * d);
    if (lane == 0) red[wid] = s2;
    __syncthreads();
    float var = (red[0] + red[1] + red[2] + red[3]) * (1.f / C);
    float rs = rsqrtf(var + LN_EPS);
    float o = d * rs * g[tid] + b[tid];
    out[(size_t)row * C + tid] = f2b(fmaxf(o, 0.f));
}

// ---- fold attention vectors through W: qs[h*Cin+k] = sum_c W[k, h*Cout+c]*att_s[h,c]
__global__ void fold_att_kernel(const float* __restrict__ W,
                                const float* __restrict__ att_s,
                                const float* __restrict__ att_d,
                                float* __restrict__ qs, float* __restrict__ qd,
                                int Cin, int Cout, int H) {
    int t = blockIdx.x * blockDim.x + threadIdx.x;
    if (t >= H * Cin) return;
    int h = t / Cin, k = t - h * Cin;
    const float* wrow = W + (size_t)k * (H * Cout) + (size_t)h * Cout;
    const float* as = att_s + (size_t)h * Cout;
    const float* ad = att_d + (size_t)h * Cout;
    float ss = 0.f, sd = 0.f;
    for (int c = 0; c < Cout; c++) { float wv = wrow[c]; ss += wv * as[c]; sd += wv * ad[c]; }
    qs[t] = ss;
    qd[t] = sd;
}

// ---- block1 scores: a_s[n,h] = x[n,:] . qs[h,:]  (x bf16) ----
__global__ __launch_bounds__(64) void att_scores_kernel(const ushort* __restrict__ x,
                                                        const float* __restrict__ qs,
                                                        const float* __restrict__ qd,
                                                        float* __restrict__ a_s,
                                                        float* __restrict__ a_d,
                                                        int H, int Cin) {
    int blk = blockIdx.x;
    int n = blk / H, hd = blk - (blk / H) * H;
    int lane = threadIdx.x;
    const ushort* xp = x + (size_t)n * Cin;
    const float* qsp = qs + (size_t)hd * Cin;
    const float* qdp = qd + (size_t)hd * Cin;
    float ss = 0.f, sd = 0.f;
    for (int k = lane; k < Cin; k += 64) {
        float xv = b2f(xp[k]);
        ss += xv * qsp[k];
        sd += xv * qdp[k];
    }
    ss = wave_reduce_sum(ss);
    sd = wave_reduce_sum(sd);
    if (lane == 0) {
        a_s[(size_t)n * H + hd] = ss;
        a_d[(size_t)n * H + hd] = sd;
    }
}

// ================= CSR construction (dst-grouped) =========
__device__ __forceinline__ void edge_sd(const int* ei, int e, int E, int& s, int& d) {
    if (e < E) { s = ei[e]; d = ei[E + e]; } else { s = d = e - E; }
}

__global__ void deg_kernel(const int* __restrict__ ei, int* __restrict__ deg, int E, int Et) {
    int e = blockIdx.x * blockDim.x + threadIdx.x;
    if (e >= Et) return;
    int s, d; edge_sd(ei, e, E, s, d);
    atomicAdd(&deg[d], 1);
}

__global__ __launch_bounds__(256) void scan1_kernel(const int* __restrict__ deg,
                                                    int* __restrict__ incl,
                                                    int* __restrict__ part, int N) {
    __shared__ int sd[256];
    int t = threadIdx.x;
    int i = blockIdx.x * 256 + t;
    int v = (i < N) ? deg[i] : 0;
    sd[t] = v; __syncthreads();
    #pragma unroll
    for (int o = 1; o < 256; o <<= 1) {
        int x = (t >= o) ? sd[t - o] : 0;
        __syncthreads();
        sd[t] += x;
        __syncthreads();
    }
    if (i < N) incl[i] = sd[t];
    if (t == 255) part[blockIdx.x] = sd[255];
}

__global__ __launch_bounds__(256) void scan2_kernel(int* __restrict__ part, int nb) {
    __shared__ int sd[256];
    int t = threadIdx.x;
    int v = (t < nb) ? part[t] : 0;
    sd[t] = v; __syncthreads();
    #pragma unroll
    for (int o = 1; o < 256; o <<= 1) {
        int x = (t >= o) ? sd[t - o] : 0;
        __syncthreads();
        sd[t] += x;
        __syncthreads();
    }
    if (t < nb) part[t] = sd[t];
}

__global__ void scan3_kernel(const int* __restrict__ incl, const int* __restrict__ deg,
                             const int* __restrict__ part, int* __restrict__ row_ptr, int N) {
    int i = blockIdx.x * blockDim.x + threadIdx.x;
    if (i >= N) return;
    int off = (blockIdx.x > 0) ? part[blockIdx.x - 1] : 0;
    row_ptr[i] = incl[i] - deg[i] + off;
}

__global__ void fill_kernel(const int* __restrict__ ei, const int* __restrict__ row_ptr,
                            int* __restrict__ cur, int* __restrict__ csr_src, int E, int Et) {
    int e = blockIdx.x * blockDim.x + threadIdx.x;
    if (e >= Et) return;
    int s, d; edge_sd(ei, e, E, s, d);
    int pos = row_ptr[d] + atomicAdd(&cur[d], 1);
    csr_src[pos] = s;
}

// ======= per-dst softmax stats -> normalized alpha per CSR slot (strided scores) ==
template<int H>
__global__ __launch_bounds__(64) void stats_kernel(const int* __restrict__ row_ptr,
                                                   const int* __restrict__ deg,
                                                   const int* __restrict__ csr_src,
                                                   const float* __restrict__ a_s, int sA,
                                                   const float* __restrict__ a_d, int sD,
                                                   float* __restrict__ alpha) {
    int d = blockIdx.x;
    int lane = threadIdx.x;
    int base = row_ptr[d], dg = deg[d];
    float ad[H];
    #pragma unroll
    for (int h = 0; h < H; h++) ad[h] = a_d[(size_t)d * sD + h];

    float mx[H];
    #pragma unroll
    for (int h = 0; h < H; h++) mx[h] = -1e30f;
    for (int j = lane; j < dg; j += 64) {
        int s = csr_src[base + j];
        #pragma unroll
        for (int h = 0; h < H; h++) {
            float sc = a_s[(size_t)s * sA + h] + ad[h];
            sc = sc > 0.f ? sc : 0.2f * sc;
            mx[h] = fmaxf(mx[h], sc);
        }
    }
    #pragma unroll
    for (int h = 0; h < H; h++) mx[h] = wave_allreduce_max(mx[h]);

    float sm[H];
    #pragma unroll
    for (int h = 0; h < H; h++) sm[h] = 0.f;
    for (int j = lane; j < dg; j += 64) {
        int s = csr_src[base + j];
        #pragma unroll
        for (int h = 0; h < H; h++) {
            float sc = a_s[(size_t)s * sA + h] + ad[h];
            sc = sc > 0.f ? sc : 0.2f * sc;
            sm[h] += __expf(sc - mx[h]);
        }
    }
    float rd[H];
    #pragma unroll
    for (int h = 0; h < H; h++) {
        sm[h] = wave_allreduce_sum(sm[h]);
        rd[h] = 1.f / (sm[h] + 1e-16f);
    }

    for (int j = lane; j < dg; j += 64) {
        int s = csr_src[base + j];
        #pragma unroll
        for (int h = 0; h < H; h++) {
            float sc = a_s[(size_t)s * sA + h] + ad[h];
            sc = sc > 0.f ? sc : 0.2f * sc;
            alpha[(size_t)(base + j) * H + h] = __expf(sc - mx[h]) * rd[h];
        }
    }
}

// ==== block1: gather-aggregate ALL 4 heads at once (Cin=256, bf16 in/out) ========
__global__ __launch_bounds__(256) void aggr_b1_all_kernel(const int* __restrict__ row_ptr,
                                                          const int* __restrict__ deg,
                                                          const int* __restrict__ csr_src,
                                                          const float* __restrict__ alpha,
                                                          const ushort* __restrict__ h1b,
                                                          ushort* __restrict__ accb) {
    int d = blockIdx.x;
    int c = threadIdx.x;
    int base = row_ptr[d], dg = deg[d];
    float a0 = 0.f, a1 = 0.f, a2 = 0.f, a3 = 0.f;
    for (int j = 0; j < dg; j++) {
        int s = csr_src[base + j];
        float4 al = *reinterpret_cast<const float4*>(&alpha[(size_t)(base + j) * 4]);
        float v = b2f(h1b[(size_t)s * 256 + c]);
        a0 += al.x * v; a1 += al.y * v; a2 += al.z * v; a3 += al.w * v;
    }
    size_t o = (size_t)d * 1024 + c;
    accb[o]       = f2b(a0);
    accb[o + 256] = f2b(a1);
    accb[o + 512] = f2b(a2);
    accb[o + 768] = f2b(a3);
}

// ==== blocks 2/3: gather-aggregate output-space (g bf16, out fp32) ===============
template<int H, int C, int F>
__global__ void aggr_flat_kernel(const int* __restrict__ row_ptr,
                                 const int* __restrict__ deg,
                                 const int* __restrict__ csr_src,
                                 const float* __restrict__ alpha,
                                 const ushort* __restrict__ g,
                                 float* __restrict__ out) {
    int d = blockIdx.x;
    int f = threadIdx.x;
    int hd = f / C;
    int base = row_ptr[d], dg = deg[d];
    float acc = 0.f;
    for (int j = 0; j < dg; j++) {
        int s = csr_src[base + j];
        acc += alpha[(size_t)(base + j) * H + hd] * b2f(g[(size_t)s * F + f]);
    }
    out[(size_t)d * F + f] = acc;
}

// ==== elementwise: out_b = elu(O + gb) + R + rb ==================================
__global__ void combine_kernel(const float* __restrict__ O,
                               const float* __restrict__ R, int ldR,
                               const float* __restrict__ gb,
                               const float* __restrict__ rb,
                               ushort* __restrict__ out, int total, int F) {
    int i = blockIdx.x * 256 + threadIdx.x;
    if (i >= total) return;
    int n = i / F, c = i - n * F;
    float o = O[i] + gb[c];
    o = o > 0.f ? o : (__expf(o) - 1.f);
    out[i] = f2b(o + R[(size_t)n * ldR + c] + rb[c]);
}

// ---------------- final tiny GEMM: out[M,2] = A[M,64](bf16) @ W[64,2] + b --------
__global__ __launch_bounds__(256) void mlp2_kernel(const ushort* __restrict__ A,
                                                   const float* __restrict__ W,
                                                   const float* __restrict__ b,
                                                   float* __restrict__ out, int M) {
    __shared__ float w[128];
    __shared__ float bb[2];
    int tid = threadIdx.x;
    if (tid < 128) w[tid] = W[tid];
    if (tid < 2) bb[tid] = b[tid];
    __syncthreads();
    int row = blockIdx.x * 256 + tid;
    if (row >= M) return;
    float a0 = bb[0], a1 = bb[1];
    const ushort* ap = A + (size_t)row * 64;
    #pragma unroll 8
    for (int k = 0; k < 64; k++) {
        float av = b2f(ap[k]);
        a0 += av * w[2 * k];
        a1 += av * w[2 * k + 1];
    }
    out[(size_t)row * 2] = a0;
    out[(size_t)row * 2 + 1] = a1;
}

extern "C" void kernel_launch(void* const* d_in, const int* in_sizes, int n_in,
                              void* d_out, int out_size, void* d_ws, size_t ws_size,
                              hipStream_t stream) {
    const float* x        = (const float*)d_in[0];
    const int*   ei       = (const int*)d_in[1];
    const float* enc_w1   = (const float*)d_in[2];
    const float* enc_b1   = (const float*)d_in[3];
    const float* ln1_g    = (const float*)d_in[4];
    const float* ln1_b    = (const float*)d_in[5];
    const float* enc_w2   = (const float*)d_in[6];
    const float* enc_b2   = (const float*)d_in[7];
    const float* ln2_g    = (const float*)d_in[8];
    const float* ln2_b    = (const float*)d_in[9];
    const float* w1       = (const float*)d_in[10];
    const float* att_src1 = (const float*)d_in[11];
    const float* att_dst1 = (const float*)d_in[12];
    const float* bias1    = (const float*)d_in[13];
    const float* res1_w   = (const float*)d_in[14];
    const float* res1_b   = (const float*)d_in[15];
    const float* w2       = (const float*)d_in[16];
    const float* att_src2 = (const float*)d_in[17];
    const float* att_dst2 = (const float*)d_in[18];
    const float* bias2    = (const float*)d_in[19];
    const float* res2_w   = (const float*)d_in[20];
    const float* res2_b   = (const float*)d_in[21];
    const float* w3       = (const float*)d_in[22];
    const float* att_src3 = (const float*)d_in[23];
    const float* att_dst3 = (const float*)d_in[24];
    const float* bias3    = (const float*)d_in[25];
    const float* res3_w   = (const float*)d_in[26];
    const float* res3_b   = (const float*)d_in[27];
    const float* mlp_w1   = (const float*)d_in[28];
    const float* mlp_b1   = (const float*)d_in[29];
    const float* mlp_w2   = (const float*)d_in[30];
    const float* mlp_b2   = (const float*)d_in[31];

    const int N  = in_sizes[0] / 405;   // 50000
    const int E  = in_sizes[1] / 2;     // 300000
    const int Et = E + N;
    const int NB = (N + 255) / 256;

    // ---------- workspace layout (bytes), peak ~310 MB ----------
    char* p = (char*)d_ws;
    char* R0 = p;                       // N*832 B : xb | O2(f32 192) | O3(f32 128) | M1b
    char* R1 = R0 + (size_t)N * 832;    // N*512 B : h0b | G2b | H3b
    char* R2 = R1 + (size_t)N * 512;    // N*512 B : h1b | G3b , H4b(@+N*256B)
    char* R3 = R2 + (size_t)N * 512;    // N*2048 B: F1(f32 256) | Cbuf_b(b16 1024) | Cbig(f32 512) | Cbig3(f32 384)
    char* R4 = R3 + (size_t)N * 2048;   // N*2048 B: accb(b16 1024) | H2b(b16 1024)
    char* T  = R4 + (size_t)N * 2048;   // tail

    ushort* xb     = (ushort*)R0;
    float*  O2     = (float*)R0;
    float*  O3     = (float*)R0;
    ushort* M1b    = (ushort*)R0;
    ushort* h0b    = (ushort*)R1;
    ushort* G2b    = (ushort*)R1;
    ushort* H3b    = (ushort*)R1;
    ushort* h1b    = (ushort*)R2;
    ushort* G3b    = (ushort*)R2;
    ushort* H4b    = (ushort*)(R2 + (size_t)N * 256);
    float*  F1     = (float*)R3;
    ushort* Cbuf_b = (ushort*)R3;
    float*  Cbig   = (float*)R3;
    ushort* accb   = (ushort*)R4;
    ushort* H2b    = (ushort*)R4;

    float* a_s   = (float*)T;                         T += (size_t)N * 4 * 4;
    float* a_d   = (float*)T;                         T += (size_t)N * 4 * 4;
    float* alpha = (float*)T;                         T += (size_t)Et * 4 * 4;
    float* qs    = (float*)T;                         T += 2048 * 4;
    float* qd    = (float*)T;                         T += 2048 * 4;
    int* deg     = (int*)T;                           T += (size_t)N * 4;
    int* cur     = (int*)T;                           T += (size_t)N * 4;
    int* row_ptr = (int*)T;                           T += (size_t)N * 4;
    int* incl    = (int*)T;                           T += (size_t)N * 4;
    int* part    = (int*)T;                           T += 256 * 4;
    int* csr_src = (int*)T;                           T += (size_t)Et * 4;
    ushort* enc_w1T = (ushort*)T;                     T += (size_t)256 * 416 * 2;
    ushort* enc_w2T = (ushort*)T;                     T += (size_t)256 * 256 * 2;
    ushort* w1T     = (ushort*)T;                     T += (size_t)1024 * 256 * 2;
    ushort* res1T   = (ushort*)T;                     T += (size_t)1024 * 256 * 2;
    ushort* Bcat2T  = (ushort*)T;                     T += (size_t)512 * 1024 * 2;
    ushort* Bcat3T  = (ushort*)T;                     T += (size_t)384 * 192 * 2;
    ushort* mlpw1T  = (ushort*)T;                     T += (size_t)128 * 128 * 2;

    auto cdiv = [](int a, int b) { return (a + b - 1) / b; };
    const int MB = cdiv(N, 128);   // GEMM row blocks

    // ---- CSR build ----
    hipMemsetAsync(deg, 0, (size_t)N * 8, stream);   // deg + cur
    deg_kernel<<<cdiv(Et, 256), 256, 0, stream>>>(ei, deg, E, Et);
    scan1_kernel<<<NB, 256, 0, stream>>>(deg, incl, part, N);
    scan2_kernel<<<1, 256, 0, stream>>>(part, NB);
    scan3_kernel<<<NB, 256, 0, stream>>>(incl, deg, part, row_ptr, N);
    fill_kernel<<<cdiv(Et, 256), 256, 0, stream>>>(ei, row_ptr, cur, csr_src, E, Et);

    // ---- weight prep (bf16, transposed, padded) ----
    prep_bt_kernel<<<cdiv(256 * 416, 256), 256, 0, stream>>>(enc_w1, enc_w1T, 405, 256, 416, 256, 256, 0);
    prep_bt_kernel<<<cdiv(256 * 256, 256), 256, 0, stream>>>(enc_w2, enc_w2T, 256, 256, 256, 256, 256, 0);
    prep_bt_kernel<<<cdiv(1024 * 256, 256), 256, 0, stream>>>(w1, w1T, 256, 1024, 256, 1024, 1024, 0);
    prep_bt_kernel<<<cdiv(1024 * 256, 256), 256, 0, stream>>>(res1_w, res1T, 256, 1024, 256, 1024, 1024, 0);
    prep_bt_kernel<<<cdiv(192 * 1024, 256), 256, 0, stream>>>(w2, Bcat2T, 1024, 192, 1024, 192, 192, 0);
    prep_bt_kernel<<<cdiv(192 * 1024, 256), 256, 0, stream>>>(res2_w, Bcat2T + (size_t)192 * 1024, 1024, 192, 1024, 192, 192, 0);
    prep_bt_kernel<<<cdiv(124 * 1024, 256), 256, 0, stream>>>(w2, Bcat2T + (size_t)388 * 1024, 0, 0, 1024, 124, 192, 0);
    prep_bt_kernel<<<cdiv(128 * 192, 256), 256, 0, stream>>>(w3, Bcat3T, 192, 128, 192, 128, 128, 0);
    prep_bt_kernel<<<cdiv(128 * 192, 256), 256, 0, stream>>>(res3_w, Bcat3T + (size_t)128 * 192, 192, 128, 192, 128, 128, 0);
    prep_bt_kernel<<<cdiv(126 * 192, 256), 256, 0, stream>>>(w3, Bcat3T + (size_t)258 * 192, 0, 0, 192, 126, 128, 0);
    prep_bt_kernel<<<cdiv(128 * 128, 256), 256, 0, stream>>>(mlp_w1, mlpw1T, 128, 64, 128, 128, 64, 0);

    // ---- JointEncoder ----
    conv_pad_x_kernel<<<cdiv(N * 416, 256), 256, 0, stream>>>(x, xb, N);
    bgemm<0><<<dim3(2, MB), 256, 0, stream>>>(xb, enc_w1T, enc_b1, nullptr, nullptr, 0, F1, 256, N, 256, 416, 416);
    ln_relu_kernel<<<N, 256, 0, stream>>>(F1, ln1_g, ln1_b, h0b);
    bgemm<0><<<dim3(2, MB), 256, 0, stream>>>(h0b, enc_w2T, enc_b2, nullptr, nullptr, 0, F1, 256, N, 256, 256, 256);
    ln_relu_kernel<<<N, 256, 0, stream>>>(F1, ln2_g, ln2_b, h1b);

    // ---- Block 1: GAT 256 -> 4x256 concat ----
    {
        fold_att_kernel<<<cdiv(4 * 256, 256), 256, 0, stream>>>(w1, att_src1, att_dst1, qs, qd, 256, 256, 4);
        att_scores_kernel<<<N * 4, 64, 0, stream>>>(h1b, qs, qd, a_s, a_d, 4, 256);
        stats_kernel<4><<<N, 64, 0, stream>>>(row_ptr, deg, csr_src, a_s, 4, a_d, 4, alpha);
        aggr_b1_all_kernel<<<N, 256, 0, stream>>>(row_ptr, deg, csr_src, alpha, h1b, accb);
        for (int h = 0; h < 4; h++) {
            bgemm<1><<<dim3(2, MB), 256, 0, stream>>>(accb + (size_t)h * 256, w1T + (size_t)h * 256 * 256,
                                                      nullptr, nullptr, nullptr, 0,
                                                      Cbuf_b + (size_t)h * 256, 1024, N, 256, 256, 1024);
        }
        // H2b = elu(Cbuf_b + bias1) + h1b @ res1T + res1_b
        bgemm<2><<<dim3(8, MB), 256, 0, stream>>>(h1b, res1T, res1_b, bias1, Cbuf_b, 1024,
                                                  H2b, 1024, N, 1024, 256, 256);
    }

    // ---- Block 2: GAT 1024 -> 2x96 concat (scores+residual folded into one GEMM) --
    {
        fold_att_kernel<<<cdiv(2 * 1024, 256), 256, 0, stream>>>(w2, att_src2, att_dst2, qs, qd, 1024, 96, 2);
        conv_bf16_kernel<<<cdiv(2048, 256), 256, 0, stream>>>(qs, Bcat2T + (size_t)384 * 1024, 2048);
        conv_bf16_kernel<<<cdiv(2048, 256), 256, 0, stream>>>(qd, Bcat2T + (size_t)386 * 1024, 2048);
        // Cbig[N,512] = [G2 | R2 | a_s | a_d | 0]
        bgemm<0><<<dim3(4, MB), 256, 0, stream>>>(H2b, Bcat2T, nullptr, nullptr, nullptr, 0,
                                                  Cbig, 512, N, 512, 1024, 1024);
        slice_b16_kernel<<<cdiv(N * 192, 256), 256, 0, stream>>>(Cbig, 512, G2b, 192, N * 192);
        stats_kernel<2><<<N, 64, 0, stream>>>(row_ptr, deg, csr_src, Cbig + 384, 512, Cbig + 386, 512, alpha);
        aggr_flat_kernel<2, 96, 192><<<N, 192, 0, stream>>>(row_ptr, deg, csr_src, alpha, G2b, O2);
        combine_kernel<<<cdiv(N * 192, 256), 256, 0, stream>>>(O2, Cbig + 192, 512, bias2, res2_b, H3b, N * 192, 192);
    }

    // ---- Block 3: GAT 192 -> 1x128 mean(no concat) ----
    {
        fold_att_kernel<<<cdiv(192, 192), 192, 0, stream>>>(w3, att_src3, att_dst3, qs, qd, 192, 128, 1);
        conv_bf16_kernel<<<1, 256, 0, stream>>>(qs, Bcat3T + (size_t)256 * 192, 192);
        conv_bf16_kernel<<<1, 256, 0, stream>>>(qd, Bcat3T + (size_t)257 * 192, 192);
        // Cbig3[N,384] = [G3 | R3 | a_s | a_d | 0]
        bgemm<0><<<dim3(3, MB), 256, 0, stream>>>(H3b, Bcat3T, nullptr, nullptr, nullptr, 0,
                                                  Cbig, 384, N, 384, 192, 192);
        slice_b16_kernel<<<cdiv(N * 128, 256), 256, 0, stream>>>(Cbig, 384, G3b, 128, N * 128);
        stats_kernel<1><<<N, 64, 0, stream>>>(row_ptr, deg, csr_src, Cbig + 256, 384, Cbig + 257, 384, alpha);
        aggr_flat_kernel<1, 128, 128><<<N, 128, 0, stream>>>(row_ptr, deg, csr_src, alpha, G3b, O3);
        combine_kernel<<<cdiv(N * 128, 256), 256, 0, stream>>>(O3, Cbig + 128, 384, bias3, res3_b, H4b, N * 128, 128);
    }

    // ---- MLP head ----
    bgemm<3><<<dim3(1, MB), 256, 0, stream>>>(H4b, mlpw1T, mlp_b1, nullptr, nullptr, 0,
                                              M1b, 64, N, 64, 128, 128);
    mlp2_kernel<<<cdiv(N, 256), 256, 0, stream>>>(M1b, mlp_w2, mlp_b2, (float*)d_out, N);
}

// Round 5
// 1082.150 us; speedup vs baseline: 9.0661x; 1.2038x over previous
//
#include <hip/hip_runtime.h>
#include <cstddef>

#define LN_EPS 1e-5f

typedef __bf16 bf16x8 __attribute__((ext_vector_type(8)));
typedef float  f32x4  __attribute__((ext_vector_type(4)));

typedef __attribute__((address_space(3))) unsigned int lds_u32;
typedef __attribute__((address_space(1))) unsigned int glb_u32;

__device__ __forceinline__ void gl2lds16(const void* g, void* l) {
    // 16B per lane DMA: LDS dest = wave-uniform base + lane*16
    __builtin_amdgcn_global_load_lds((const glb_u32*)g, (lds_u32*)l, 16, 0, 0);
}

__device__ __forceinline__ float b2f(ushort h) {
    return __uint_as_float(((unsigned)h) << 16);
}
__device__ __forceinline__ ushort f2b(float f) {   // RNE
    unsigned u = __float_as_uint(f);
    return (ushort)((u + 0x7fffu + ((u >> 16) & 1u)) >> 16);
}
__device__ __forceinline__ unsigned pack2(float lo, float hi) {
    return (unsigned)f2b(lo) | ((unsigned)f2b(hi) << 16);
}

__device__ __forceinline__ float wave_reduce_sum(float v) {
    #pragma unroll
    for (int off = 32; off > 0; off >>= 1) v += __shfl_down(v, off, 64);
    return v;
}
__device__ __forceinline__ float wave_allreduce_max(float v) {
    #pragma unroll
    for (int off = 32; off > 0; off >>= 1) v = fmaxf(v, __shfl_xor(v, off, 64));
    return v;
}
__device__ __forceinline__ float wave_allreduce_sum(float v) {
    #pragma unroll
    for (int off = 32; off > 0; off >>= 1) v += __shfl_xor(v, off, 64);
    return v;
}

// ---- shared MFMA K-loop: stages via global_load_lds, accumulates 128x128 tile ----
__device__ __forceinline__ void mfma_loop(const ushort* Ap0, const ushort* Ap1,
                                          const ushort* Bp0, const ushort* Bp1,
                                          ushort* lA0, ushort* lA1,
                                          ushort* lB0, ushort* lB1,
                                          const ushort* As, const ushort* Bs,
                                          int K, int wr, int wc, int quad, int l15,
                                          f32x4 acc[4][4]) {
    for (int k0 = 0; k0 < K; k0 += 32) {
        gl2lds16(Ap0 + k0, lA0);
        gl2lds16(Ap1 + k0, lA1);
        gl2lds16(Bp0 + k0, lB0);
        gl2lds16(Bp1 + k0, lB1);
        __syncthreads();
        bf16x8 af[4], bf[4];
        #pragma unroll
        for (int i = 0; i < 4; i++)
            af[i] = *reinterpret_cast<const bf16x8*>(&As[(wr + i * 16 + l15) * 32 + quad * 8]);
        #pragma unroll
        for (int j = 0; j < 4; j++)
            bf[j] = *reinterpret_cast<const bf16x8*>(&Bs[(wc + j * 16 + l15) * 32 + quad * 8]);
        #pragma unroll
        for (int i = 0; i < 4; i++)
            #pragma unroll
            for (int j = 0; j < 4; j++)
                acc[i][j] = __builtin_amdgcn_mfma_f32_16x16x32_bf16(af[i], bf[j], acc[i][j], 0, 0, 0);
        __syncthreads();
    }
}

// ============== bf16 MFMA GEMM: C = A[M,K]@B  (B given as BT[Npad,K] bf16) =======
// EPI 0: fp32 out = acc (+bias if non-null)
// EPI 3: bf16 out = relu(acc + bias)
// K multiple of 32; A rows 16B-aligned; BT zero-padded to grid.x*128 rows.
template<int EPI>
__global__ __launch_bounds__(256) void bgemm(const ushort* __restrict__ A,
                                             const ushort* __restrict__ BT,
                                             const float* __restrict__ bias,
                                             void* __restrict__ out, int ldc,
                                             int M, int Ncols, int K, int lda) {
    __shared__ ushort As[128 * 32];
    __shared__ ushort Bs[128 * 32];
    const int tid = threadIdx.x;
    const int m0 = blockIdx.y * 128, n0 = blockIdx.x * 128;
    const int w = tid >> 6, lane = tid & 63;
    const int wr = (w >> 1) * 64, wc = (w & 1) * 64;
    const int quad = lane >> 4, l15 = lane & 15;

    const int sl0 = w * 64 + lane, sl1 = sl0 + 256;
    const int r0 = sl0 >> 2, s0 = (sl0 & 3) * 8;
    const int r1 = sl1 >> 2, s1 = (sl1 & 3) * 8;
    int ga0 = m0 + r0; if (ga0 >= M) ga0 = M - 1;
    int ga1 = m0 + r1; if (ga1 >= M) ga1 = M - 1;
    const ushort* Ap0 = A + (size_t)ga0 * lda + s0;
    const ushort* Ap1 = A + (size_t)ga1 * lda + s1;
    const ushort* Bp0 = BT + (size_t)(n0 + r0) * K + s0;
    const ushort* Bp1 = BT + (size_t)(n0 + r1) * K + s1;
    ushort* lA0 = As + (size_t)(w * 64) * 8;
    ushort* lA1 = lA0 + 256 * 8;
    ushort* lB0 = Bs + (size_t)(w * 64) * 8;
    ushort* lB1 = lB0 + 256 * 8;

    f32x4 acc[4][4] = {};
    mfma_loop(Ap0, Ap1, Bp0, Bp1, lA0, lA1, lB0, lB1, As, Bs, K, wr, wc, quad, l15, acc);

    #pragma unroll
    for (int i = 0; i < 4; i++) {
        #pragma unroll
        for (int j = 0; j < 4; j++) {
            int col = n0 + wc + j * 16 + l15;
            if (col >= Ncols) continue;
            #pragma unroll
            for (int r = 0; r < 4; r++) {
                int row = m0 + wr + i * 16 + quad * 4 + r;
                if (row >= M) continue;
                float v = acc[i][j][r];
                size_t idx = (size_t)row * ldc + col;
                if (EPI == 0) {
                    if (bias) v += bias[col];
                    ((float*)out)[idx] = v;
                } else {
                    ((ushort*)out)[idx] = f2b(fmaxf(v + bias[col], 0.f));
                }
            }
        }
    }
}

// ===== fused block-1: H2 = elu(acc_h@W_h + bias1) + h1@res1_w + res1_b (bf16) ====
// grid (8, MB); col block n0 belongs to head h = n0>>8. Both phases K=256.
__global__ __launch_bounds__(256) void bgemm_b1(const ushort* __restrict__ accb,  // N x 1024
                                                const ushort* __restrict__ w1T,   // 1024 x 256
                                                const ushort* __restrict__ h1b,   // N x 256
                                                const ushort* __restrict__ res1T, // 1024 x 256
                                                const float* __restrict__ bias1,
                                                const float* __restrict__ res1b,
                                                ushort* __restrict__ H2b, int M) {
    __shared__ ushort As[128 * 32];
    __shared__ ushort Bs[128 * 32];
    const int tid = threadIdx.x;
    const int m0 = blockIdx.y * 128, n0 = blockIdx.x * 128;
    const int h = n0 >> 8;
    const int w = tid >> 6, lane = tid & 63;
    const int wr = (w >> 1) * 64, wc = (w & 1) * 64;
    const int quad = lane >> 4, l15 = lane & 15;

    const int sl0 = w * 64 + lane, sl1 = sl0 + 256;
    const int r0 = sl0 >> 2, s0 = (sl0 & 3) * 8;
    const int r1 = sl1 >> 2, s1 = (sl1 & 3) * 8;
    int ga0 = m0 + r0; if (ga0 >= M) ga0 = M - 1;
    int ga1 = m0 + r1; if (ga1 >= M) ga1 = M - 1;
    ushort* lA0 = As + (size_t)(w * 64) * 8;
    ushort* lA1 = lA0 + 256 * 8;
    ushort* lB0 = Bs + (size_t)(w * 64) * 8;
    ushort* lB1 = lB0 + 256 * 8;

    f32x4 acc[4][4] = {};

    // phase 1: acc_h @ W_h
    mfma_loop(accb + (size_t)ga0 * 1024 + h * 256 + s0,
              accb + (size_t)ga1 * 1024 + h * 256 + s1,
              w1T + (size_t)(n0 + r0) * 256 + s0,
              w1T + (size_t)(n0 + r1) * 256 + s1,
              lA0, lA1, lB0, lB1, As, Bs, 256, wr, wc, quad, l15, acc);

    // in-register: acc = elu(acc + bias1) + res1_b
    #pragma unroll
    for (int i = 0; i < 4; i++) {
        #pragma unroll
        for (int j = 0; j < 4; j++) {
            int col = n0 + wc + j * 16 + l15;
            float bv = bias1[col], rv = res1b[col];
            #pragma unroll
            for (int r = 0; r < 4; r++) {
                float t = acc[i][j][r] + bv;
                t = t > 0.f ? t : (__expf(t) - 1.f);
                acc[i][j][r] = t + rv;
            }
        }
    }

    // phase 2: += h1 @ res1_w
    mfma_loop(h1b + (size_t)ga0 * 256 + s0,
              h1b + (size_t)ga1 * 256 + s1,
              res1T + (size_t)(n0 + r0) * 256 + s0,
              res1T + (size_t)(n0 + r1) * 256 + s1,
              lA0, lA1, lB0, lB1, As, Bs, 256, wr, wc, quad, l15, acc);

    #pragma unroll
    for (int i = 0; i < 4; i++) {
        #pragma unroll
        for (int j = 0; j < 4; j++) {
            int col = n0 + wc + j * 16 + l15;
            #pragma unroll
            for (int r = 0; r < 4; r++) {
                int row = m0 + wr + i * 16 + quad * 4 + r;
                if (row >= M) continue;
                H2b[(size_t)row * 1024 + col] = f2b(acc[i][j][r]);
            }
        }
    }
}

// ---------------- conversions / weight prep ----------------
__global__ void conv_pad_x_kernel(const float* __restrict__ x, ushort* __restrict__ xb, int N) {
    int t = blockIdx.x * 256 + threadIdx.x;
    if (t >= N * 416) return;
    int n = t / 416, k = t - n * 416;
    xb[t] = f2b(k < 405 ? x[(size_t)n * 405 + k] : 0.f);
}

__global__ void prep_bt_kernel(const float* __restrict__ src, ushort* __restrict__ dst,
                               int K, int Nreal, int Kpad, int rows, int ldsrc, int col_off) {
    int t = blockIdx.x * 256 + threadIdx.x;
    if (t >= rows * Kpad) return;
    int n = t / Kpad, k = t - n * Kpad;
    float v = (k < K && n < Nreal) ? src[(size_t)k * ldsrc + n + col_off] : 0.f;
    dst[t] = f2b(v);
}

__global__ void conv_bf16_kernel(const float* __restrict__ src, ushort* __restrict__ dst, int n) {
    int i = blockIdx.x * 256 + threadIdx.x;
    if (i < n) dst[i] = f2b(src[i]);
}

__global__ void slice_b16_kernel(const float* __restrict__ src, int lds,
                                 ushort* __restrict__ dst, int F, int total) {
    int i = blockIdx.x * 256 + threadIdx.x;
    if (i >= total) return;
    dst[i] = f2b(src[(size_t)(i / F) * lds + (i % F)]);
}

// ---------------- LayerNorm(+ReLU): fp32 in, bf16 out; C == 256 ----------------
__global__ __launch_bounds__(256) void ln_relu_kernel(const float* __restrict__ x,
                                                      const float* __restrict__ g,
                                                      const float* __restrict__ b,
                                                      ushort* __restrict__ out) {
    const int C = 256;
    int row = blockIdx.x;
    int tid = threadIdx.x;
    int lane = tid & 63, wid = tid >> 6;
    __shared__ float red[4];
    float v = x[(size_t)row * C + tid];
    float s = wave_reduce_sum(v);
    if (lane == 0) red[wid] = s;
    __syncthreads();
    float m = (red[0] + red[1] + red[2] + red[3]) * (1.f / C);
    __syncthreads();
    float d = v - m;
    float s2 = wave_reduce_sum(d * d);
    if (lane == 0) red[wid] = s2;
    __syncthreads();
    float var = (red[0] + red[1] + red[2] + red[3]) * (1.f / C);
    float rs = rsqrtf(var + LN_EPS);
    float o = d * rs * g[tid] + b[tid];
    out[(size_t)row * C + tid] = f2b(fmaxf(o, 0.f));
}

// ---- fold attention vectors through W ----
__global__ void fold_att_kernel(const float* __restrict__ W,
                                const float* __restrict__ att_s,
                                const float* __restrict__ att_d,
                                float* __restrict__ qs, float* __restrict__ qd,
                                int Cin, int Cout, int H) {
    int t = blockIdx.x * blockDim.x + threadIdx.x;
    if (t >= H * Cin) return;
    int h = t / Cin, k = t - h * Cin;
    const float* wrow = W + (size_t)k * (H * Cout) + (size_t)h * Cout;
    const float* as = att_s + (size_t)h * Cout;
    const float* ad = att_d + (size_t)h * Cout;
    float ss = 0.f, sd = 0.f;
    for (int c = 0; c < Cout; c++) { float wv = wrow[c]; ss += wv * as[c]; sd += wv * ad[c]; }
    qs[t] = ss;
    qd[t] = sd;
}

// ---- block1 scores: a_s[n,h] = x[n,:] . qs[h,:]  (x bf16) ----
__global__ __launch_bounds__(64) void att_scores_kernel(const ushort* __restrict__ x,
                                                        const float* __restrict__ qs,
                                                        const float* __restrict__ qd,
                                                        float* __restrict__ a_s,
                                                        float* __restrict__ a_d,
                                                        int H, int Cin) {
    int blk = blockIdx.x;
    int n = blk / H, hd = blk - (blk / H) * H;
    int lane = threadIdx.x;
    const ushort* xp = x + (size_t)n * Cin;
    const float* qsp = qs + (size_t)hd * Cin;
    const float* qdp = qd + (size_t)hd * Cin;
    float ss = 0.f, sd = 0.f;
    for (int k = lane; k < Cin; k += 64) {
        float xv = b2f(xp[k]);
        ss += xv * qsp[k];
        sd += xv * qdp[k];
    }
    ss = wave_reduce_sum(ss);
    sd = wave_reduce_sum(sd);
    if (lane == 0) {
        a_s[(size_t)n * H + hd] = ss;
        a_d[(size_t)n * H + hd] = sd;
    }
}

// ================= CSR construction (dst-grouped) =========
__device__ __forceinline__ void edge_sd(const int* ei, int e, int E, int& s, int& d) {
    if (e < E) { s = ei[e]; d = ei[E + e]; } else { s = d = e - E; }
}

__global__ void deg_kernel(const int* __restrict__ ei, int* __restrict__ deg, int E, int Et) {
    int e = blockIdx.x * blockDim.x + threadIdx.x;
    if (e >= Et) return;
    int s, d; edge_sd(ei, e, E, s, d);
    atomicAdd(&deg[d], 1);
}

__global__ __launch_bounds__(256) void scan1_kernel(const int* __restrict__ deg,
                                                    int* __restrict__ incl,
                                                    int* __restrict__ part, int N) {
    __shared__ int sd[256];
    int t = threadIdx.x;
    int i = blockIdx.x * 256 + t;
    int v = (i < N) ? deg[i] : 0;
    sd[t] = v; __syncthreads();
    #pragma unroll
    for (int o = 1; o < 256; o <<= 1) {
        int x = (t >= o) ? sd[t - o] : 0;
        __syncthreads();
        sd[t] += x;
        __syncthreads();
    }
    if (i < N) incl[i] = sd[t];
    if (t == 255) part[blockIdx.x] = sd[255];
}

__global__ __launch_bounds__(256) void scan2_kernel(int* __restrict__ part, int nb) {
    __shared__ int sd[256];
    int t = threadIdx.x;
    int v = (t < nb) ? part[t] : 0;
    sd[t] = v; __syncthreads();
    #pragma unroll
    for (int o = 1; o < 256; o <<= 1) {
        int x = (t >= o) ? sd[t - o] : 0;
        __syncthreads();
        sd[t] += x;
        __syncthreads();
    }
    if (t < nb) part[t] = sd[t];
}

__global__ void scan3_kernel(const int* __restrict__ incl, const int* __restrict__ deg,
                             const int* __restrict__ part, int* __restrict__ row_ptr, int N) {
    int i = blockIdx.x * blockDim.x + threadIdx.x;
    if (i >= N) return;
    int off = (blockIdx.x > 0) ? part[blockIdx.x - 1] : 0;
    row_ptr[i] = incl[i] - deg[i] + off;
}

__global__ void fill_kernel(const int* __restrict__ ei, const int* __restrict__ row_ptr,
                            int* __restrict__ cur, int* __restrict__ csr_src, int E, int Et) {
    int e = blockIdx.x * blockDim.x + threadIdx.x;
    if (e >= Et) return;
    int s, d; edge_sd(ei, e, E, s, d);
    int pos = row_ptr[d] + atomicAdd(&cur[d], 1);
    csr_src[pos] = s;
}

// ======= per-dst softmax stats -> normalized alpha per CSR slot ==
template<int H>
__global__ __launch_bounds__(64) void stats_kernel(const int* __restrict__ row_ptr,
                                                   const int* __restrict__ deg,
                                                   const int* __restrict__ csr_src,
                                                   const float* __restrict__ a_s, int sA,
                                                   const float* __restrict__ a_d, int sD,
                                                   float* __restrict__ alpha) {
    int d = blockIdx.x;
    int lane = threadIdx.x;
    int base = row_ptr[d], dg = deg[d];
    float ad[H];
    #pragma unroll
    for (int h = 0; h < H; h++) ad[h] = a_d[(size_t)d * sD + h];

    float mx[H];
    #pragma unroll
    for (int h = 0; h < H; h++) mx[h] = -1e30f;
    for (int j = lane; j < dg; j += 64) {
        int s = csr_src[base + j];
        #pragma unroll
        for (int h = 0; h < H; h++) {
            float sc = a_s[(size_t)s * sA + h] + ad[h];
            sc = sc > 0.f ? sc : 0.2f * sc;
            mx[h] = fmaxf(mx[h], sc);
        }
    }
    #pragma unroll
    for (int h = 0; h < H; h++) mx[h] = wave_allreduce_max(mx[h]);

    float sm[H];
    #pragma unroll
    for (int h = 0; h < H; h++) sm[h] = 0.f;
    for (int j = lane; j < dg; j += 64) {
        int s = csr_src[base + j];
        #pragma unroll
        for (int h = 0; h < H; h++) {
            float sc = a_s[(size_t)s * sA + h] + ad[h];
            sc = sc > 0.f ? sc : 0.2f * sc;
            sm[h] += __expf(sc - mx[h]);
        }
    }
    float rd[H];
    #pragma unroll
    for (int h = 0; h < H; h++) {
        sm[h] = wave_allreduce_sum(sm[h]);
        rd[h] = 1.f / (sm[h] + 1e-16f);
    }

    for (int j = lane; j < dg; j += 64) {
        int s = csr_src[base + j];
        #pragma unroll
        for (int h = 0; h < H; h++) {
            float sc = a_s[(size_t)s * sA + h] + ad[h];
            sc = sc > 0.f ? sc : 0.2f * sc;
            alpha[(size_t)(base + j) * H + h] = __expf(sc - mx[h]) * rd[h];
        }
    }
}

// ==== block1: gather-aggregate ALL 4 heads (uint-wide, 2 channels/lane) ==========
__global__ __launch_bounds__(128) void aggr_b1_all_kernel(const int* __restrict__ row_ptr,
                                                          const int* __restrict__ deg,
                                                          const int* __restrict__ csr_src,
                                                          const float* __restrict__ alpha,
                                                          const ushort* __restrict__ h1b,
                                                          ushort* __restrict__ accb) {
    int d = blockIdx.x;
    int t = threadIdx.x;   // uint lane: channels 2t, 2t+1
    int base = row_ptr[d], dg = deg[d];
    float a00 = 0, a01 = 0, a10 = 0, a11 = 0, a20 = 0, a21 = 0, a30 = 0, a31 = 0;
    for (int j = 0; j < dg; j++) {
        int s = csr_src[base + j];
        float4 a = *reinterpret_cast<const float4*>(&alpha[(size_t)(base + j) * 4]);
        unsigned v = reinterpret_cast<const unsigned*>(h1b + (size_t)s * 256)[t];
        float lo = b2f((ushort)(v & 0xffff)), hi = b2f((ushort)(v >> 16));
        a00 += a.x * lo; a01 += a.x * hi;
        a10 += a.y * lo; a11 += a.y * hi;
        a20 += a.z * lo; a21 += a.z * hi;
        a30 += a.w * lo; a31 += a.w * hi;
    }
    unsigned* o = reinterpret_cast<unsigned*>(accb + (size_t)d * 1024);
    o[t]       = pack2(a00, a01);
    o[t + 128] = pack2(a10, a11);
    o[t + 256] = pack2(a20, a21);
    o[t + 384] = pack2(a30, a31);
}

// ==== blocks 2/3: gather-aggregate output-space (uint-wide) ======================
template<int H, int C, int F>
__global__ void aggr_flat_kernel(const int* __restrict__ row_ptr,
                                 const int* __restrict__ deg,
                                 const int* __restrict__ csr_src,
                                 const float* __restrict__ alpha,
                                 const ushort* __restrict__ g,
                                 float* __restrict__ out) {
    int d = blockIdx.x;
    int t = threadIdx.x;               // 0..F/2-1
    int hd = (2 * t) / C;
    int base = row_ptr[d], dg = deg[d];
    float lo = 0.f, hi = 0.f;
    for (int j = 0; j < dg; j++) {
        int s = csr_src[base + j];
        float a = alpha[(size_t)(base + j) * H + hd];
        unsigned v = reinterpret_cast<const unsigned*>(g + (size_t)s * F)[t];
        lo += a * b2f((ushort)(v & 0xffff));
        hi += a * b2f((ushort)(v >> 16));
    }
    out[(size_t)d * F + 2 * t]     = lo;
    out[(size_t)d * F + 2 * t + 1] = hi;
}

// ==== elementwise: out_b = elu(O + gb) + R + rb ==================================
__global__ void combine_kernel(const float* __restrict__ O,
                               const float* __restrict__ R, int ldR,
                               const float* __restrict__ gb,
                               const float* __restrict__ rb,
                               ushort* __restrict__ out, int total, int F) {
    int i = blockIdx.x * 256 + threadIdx.x;
    if (i >= total) return;
    int n = i / F, c = i - n * F;
    float o = O[i] + gb[c];
    o = o > 0.f ? o : (__expf(o) - 1.f);
    out[i] = f2b(o + R[(size_t)n * ldR + c] + rb[c]);
}

// ---------------- final tiny GEMM: out[M,2] = A[M,64](bf16) @ W[64,2] + b --------
__global__ __launch_bounds__(256) void mlp2_kernel(const ushort* __restrict__ A,
                                                   const float* __restrict__ W,
                                                   const float* __restrict__ b,
                                                   float* __restrict__ out, int M) {
    __shared__ float w[128];
    __shared__ float bb[2];
    int tid = threadIdx.x;
    if (tid < 128) w[tid] = W[tid];
    if (tid < 2) bb[tid] = b[tid];
    __syncthreads();
    int row = blockIdx.x * 256 + tid;
    if (row >= M) return;
    float a0 = bb[0], a1 = bb[1];
    const ushort* ap = A + (size_t)row * 64;
    #pragma unroll 8
    for (int k = 0; k < 64; k++) {
        float av = b2f(ap[k]);
        a0 += av * w[2 * k];
        a1 += av * w[2 * k + 1];
    }
    out[(size_t)row * 2] = a0;
    out[(size_t)row * 2 + 1] = a1;
}

extern "C" void kernel_launch(void* const* d_in, const int* in_sizes, int n_in,
                              void* d_out, int out_size, void* d_ws, size_t ws_size,
                              hipStream_t stream) {
    const float* x        = (const float*)d_in[0];
    const int*   ei       = (const int*)d_in[1];
    const float* enc_w1   = (const float*)d_in[2];
    const float* enc_b1   = (const float*)d_in[3];
    const float* ln1_g    = (const float*)d_in[4];
    const float* ln1_b    = (const float*)d_in[5];
    const float* enc_w2   = (const float*)d_in[6];
    const float* enc_b2   = (const float*)d_in[7];
    const float* ln2_g    = (const float*)d_in[8];
    const float* ln2_b    = (const float*)d_in[9];
    const float* w1       = (const float*)d_in[10];
    const float* att_src1 = (const float*)d_in[11];
    const float* att_dst1 = (const float*)d_in[12];
    const float* bias1    = (const float*)d_in[13];
    const float* res1_w   = (const float*)d_in[14];
    const float* res1_b   = (const float*)d_in[15];
    const float* w2       = (const float*)d_in[16];
    const float* att_src2 = (const float*)d_in[17];
    const float* att_dst2 = (const float*)d_in[18];
    const float* bias2    = (const float*)d_in[19];
    const float* res2_w   = (const float*)d_in[20];
    const float* res2_b   = (const float*)d_in[21];
    const float* w3       = (const float*)d_in[22];
    const float* att_src3 = (const float*)d_in[23];
    const float* att_dst3 = (const float*)d_in[24];
    const float* bias3    = (const float*)d_in[25];
    const float* res3_w   = (const float*)d_in[26];
    const float* res3_b   = (const float*)d_in[27];
    const float* mlp_w1   = (const float*)d_in[28];
    const float* mlp_b1   = (const float*)d_in[29];
    const float* mlp_w2   = (const float*)d_in[30];
    const float* mlp_b2   = (const float*)d_in[31];

    const int N  = in_sizes[0] / 405;   // 50000
    const int E  = in_sizes[1] / 2;     // 300000
    const int Et = E + N;
    const int NB = (N + 255) / 256;

    // ---------- workspace layout (bytes) ----------
    char* p = (char*)d_ws;
    char* R0 = p;                       // N*832 B : xb | O2(f32 192) | O3(f32 128) | M1b
    char* R1 = R0 + (size_t)N * 832;    // N*512 B : h0b | G2b | H3b
    char* R2 = R1 + (size_t)N * 512;    // N*512 B : h1b | G3b , H4b(@+N*256B)
    char* R3 = R2 + (size_t)N * 512;    // N*2048 B: F1(f32 256) | H2b(b16 1024)
    char* R4 = R3 + (size_t)N * 2048;   // N*2048 B: accb(b16 1024) | Cbig(f32 512/384)
    char* T  = R4 + (size_t)N * 2048;   // tail

    ushort* xb   = (ushort*)R0;
    float*  O2   = (float*)R0;
    float*  O3   = (float*)R0;
    ushort* M1b  = (ushort*)R0;
    ushort* h0b  = (ushort*)R1;
    ushort* G2b  = (ushort*)R1;
    ushort* H3b  = (ushort*)R1;
    ushort* h1b  = (ushort*)R2;
    ushort* G3b  = (ushort*)R2;
    ushort* H4b  = (ushort*)(R2 + (size_t)N * 256);
    float*  F1   = (float*)R3;
    ushort* H2b  = (ushort*)R3;
    ushort* accb = (ushort*)R4;
    float*  Cbig = (float*)R4;

    float* a_s   = (float*)T;                         T += (size_t)N * 4 * 4;
    float* a_d   = (float*)T;                         T += (size_t)N * 4 * 4;
    float* alpha = (float*)T;                         T += (size_t)Et * 4 * 4;
    float* qs    = (float*)T;                         T += 2048 * 4;
    float* qd    = (float*)T;                         T += 2048 * 4;
    int* deg     = (int*)T;                           T += (size_t)N * 4;
    int* cur     = (int*)T;                           T += (size_t)N * 4;
    int* row_ptr = (int*)T;                           T += (size_t)N * 4;
    int* incl    = (int*)T;                           T += (size_t)N * 4;
    int* part    = (int*)T;                           T += 256 * 4;
    int* csr_src = (int*)T;                           T += (size_t)Et * 4;
    ushort* enc_w1T = (ushort*)T;                     T += (size_t)256 * 416 * 2;
    ushort* enc_w2T = (ushort*)T;                     T += (size_t)256 * 256 * 2;
    ushort* w1T     = (ushort*)T;                     T += (size_t)1024 * 256 * 2;
    ushort* res1T   = (ushort*)T;                     T += (size_t)1024 * 256 * 2;
    ushort* Bcat2T  = (ushort*)T;                     T += (size_t)512 * 1024 * 2;
    ushort* Bcat3T  = (ushort*)T;                     T += (size_t)384 * 192 * 2;
    ushort* mlpw1T  = (ushort*)T;                     T += (size_t)128 * 128 * 2;

    auto cdiv = [](int a, int b) { return (a + b - 1) / b; };
    const int MB = cdiv(N, 128);

    // ---- CSR build ----
    hipMemsetAsync(deg, 0, (size_t)N * 8, stream);   // deg + cur
    deg_kernel<<<cdiv(Et, 256), 256, 0, stream>>>(ei, deg, E, Et);
    scan1_kernel<<<NB, 256, 0, stream>>>(deg, incl, part, N);
    scan2_kernel<<<1, 256, 0, stream>>>(part, NB);
    scan3_kernel<<<NB, 256, 0, stream>>>(incl, deg, part, row_ptr, N);
    fill_kernel<<<cdiv(Et, 256), 256, 0, stream>>>(ei, row_ptr, cur, csr_src, E, Et);

    // ---- weight prep (bf16, transposed, padded) ----
    prep_bt_kernel<<<cdiv(256 * 416, 256), 256, 0, stream>>>(enc_w1, enc_w1T, 405, 256, 416, 256, 256, 0);
    prep_bt_kernel<<<cdiv(256 * 256, 256), 256, 0, stream>>>(enc_w2, enc_w2T, 256, 256, 256, 256, 256, 0);
    prep_bt_kernel<<<cdiv(1024 * 256, 256), 256, 0, stream>>>(w1, w1T, 256, 1024, 256, 1024, 1024, 0);
    prep_bt_kernel<<<cdiv(1024 * 256, 256), 256, 0, stream>>>(res1_w, res1T, 256, 1024, 256, 1024, 1024, 0);
    prep_bt_kernel<<<cdiv(192 * 1024, 256), 256, 0, stream>>>(w2, Bcat2T, 1024, 192, 1024, 192, 192, 0);
    prep_bt_kernel<<<cdiv(192 * 1024, 256), 256, 0, stream>>>(res2_w, Bcat2T + (size_t)192 * 1024, 1024, 192, 1024, 192, 192, 0);
    prep_bt_kernel<<<cdiv(124 * 1024, 256), 256, 0, stream>>>(w2, Bcat2T + (size_t)388 * 1024, 0, 0, 1024, 124, 192, 0);
    prep_bt_kernel<<<cdiv(128 * 192, 256), 256, 0, stream>>>(w3, Bcat3T, 192, 128, 192, 128, 128, 0);
    prep_bt_kernel<<<cdiv(128 * 192, 256), 256, 0, stream>>>(res3_w, Bcat3T + (size_t)128 * 192, 192, 128, 192, 128, 128, 0);
    prep_bt_kernel<<<cdiv(126 * 192, 256), 256, 0, stream>>>(w3, Bcat3T + (size_t)258 * 192, 0, 0, 192, 126, 128, 0);
    prep_bt_kernel<<<cdiv(128 * 128, 256), 256, 0, stream>>>(mlp_w1, mlpw1T, 128, 64, 128, 128, 64, 0);

    // ---- JointEncoder ----
    conv_pad_x_kernel<<<cdiv(N * 416, 256), 256, 0, stream>>>(x, xb, N);
    bgemm<0><<<dim3(2, MB), 256, 0, stream>>>(xb, enc_w1T, enc_b1, F1, 256, N, 256, 416, 416);
    ln_relu_kernel<<<N, 256, 0, stream>>>(F1, ln1_g, ln1_b, h0b);
    bgemm<0><<<dim3(2, MB), 256, 0, stream>>>(h0b, enc_w2T, enc_b2, F1, 256, N, 256, 256, 256);
    ln_relu_kernel<<<N, 256, 0, stream>>>(F1, ln2_g, ln2_b, h1b);

    // ---- Block 1: GAT 256 -> 4x256 concat (fused head GEMMs + residual) ----
    {
        fold_att_kernel<<<cdiv(4 * 256, 256), 256, 0, stream>>>(w1, att_src1, att_dst1, qs, qd, 256, 256, 4);
        att_scores_kernel<<<N * 4, 64, 0, stream>>>(h1b, qs, qd, a_s, a_d, 4, 256);
        stats_kernel<4><<<N, 64, 0, stream>>>(row_ptr, deg, csr_src, a_s, 4, a_d, 4, alpha);
        aggr_b1_all_kernel<<<N, 128, 0, stream>>>(row_ptr, deg, csr_src, alpha, h1b, accb);
        bgemm_b1<<<dim3(8, MB), 256, 0, stream>>>(accb, w1T, h1b, res1T, bias1, res1_b, H2b, N);
    }

    // ---- Block 2: GAT 1024 -> 2x96 concat (scores+residual folded into one GEMM) --
    {
        fold_att_kernel<<<cdiv(2 * 1024, 256), 256, 0, stream>>>(w2, att_src2, att_dst2, qs, qd, 1024, 96, 2);
        conv_bf16_kernel<<<cdiv(2048, 256), 256, 0, stream>>>(qs, Bcat2T + (size_t)384 * 1024, 2048);
        conv_bf16_kernel<<<cdiv(2048, 256), 256, 0, stream>>>(qd, Bcat2T + (size_t)386 * 1024, 2048);
        // Cbig[N,512] = [G2 | R2 | a_s | a_d | 0]
        bgemm<0><<<dim3(4, MB), 256, 0, stream>>>(H2b, Bcat2T, nullptr, Cbig, 512, N, 512, 1024, 1024);
        slice_b16_kernel<<<cdiv(N * 192, 256), 256, 0, stream>>>(Cbig, 512, G2b, 192, N * 192);
        stats_kernel<2><<<N, 64, 0, stream>>>(row_ptr, deg, csr_src, Cbig + 384, 512, Cbig + 386, 512, alpha);
        aggr_flat_kernel<2, 96, 192><<<N, 96, 0, stream>>>(row_ptr, deg, csr_src, alpha, G2b, O2);
        combine_kernel<<<cdiv(N * 192, 256), 256, 0, stream>>>(O2, Cbig + 192, 512, bias2, res2_b, H3b, N * 192, 192);
    }

    // ---- Block 3: GAT 192 -> 1x128 (no concat) ----
    {
        fold_att_kernel<<<cdiv(192, 192), 192, 0, stream>>>(w3, att_src3, att_dst3, qs, qd, 192, 128, 1);
        conv_bf16_kernel<<<1, 256, 0, stream>>>(qs, Bcat3T + (size_t)256 * 192, 192);
        conv_bf16_kernel<<<1, 256, 0, stream>>>(qd, Bcat3T + (size_t)257 * 192, 192);
        // Cbig[N,384] = [G3 | R3 | a_s | a_d | 0]
        bgemm<0><<<dim3(3, MB), 256, 0, stream>>>(H3b, Bcat3T, nullptr, Cbig, 384, N, 384, 192, 192);
        slice_b16_kernel<<<cdiv(N * 128, 256), 256, 0, stream>>>(Cbig, 384, G3b, 128, N * 128);
        stats_kernel<1><<<N, 64, 0, stream>>>(row_ptr, deg, csr_src, Cbig + 256, 384, Cbig + 257, 384, alpha);
        aggr_flat_kernel<1, 128, 128><<<N, 64, 0, stream>>>(row_ptr, deg, csr_src, alpha, G3b, O3);
        combine_kernel<<<cdiv(N * 128, 256), 256, 0, stream>>>(O3, Cbig + 128, 384, bias3, res3_b, H4b, N * 128, 128);
    }

    // ---- MLP head ----
    bgemm<3><<<dim3(1, MB), 256, 0, stream>>>(H4b, mlpw1T, mlp_b1, M1b, 64, N, 64, 128, 128);
    mlp2_kernel<<<cdiv(N, 256), 256, 0, stream>>>(M1b, mlp_w2, mlp_b2, (float*)d_out, N);
}

// Round 6
// 1047.629 us; speedup vs baseline: 9.3649x; 1.0330x over previous
//
#include <hip/hip_runtime.h>
#include <cstddef>

#define LN_EPS 1e-5f

typedef __bf16 bf16x8 __attribute__((ext_vector_type(8)));
typedef float  f32x4  __attribute__((ext_vector_type(4)));

typedef __attribute__((address_space(3))) unsigned int lds_u32;
typedef __attribute__((address_space(1))) unsigned int glb_u32;

__device__ __forceinline__ void gl2lds16(const void* g, void* l) {
    // 16B per lane DMA: LDS dest = wave-uniform base + lane*16
    __builtin_amdgcn_global_load_lds((const glb_u32*)g, (lds_u32*)l, 16, 0, 0);
}

__device__ __forceinline__ float b2f(ushort h) {
    return __uint_as_float(((unsigned)h) << 16);
}
__device__ __forceinline__ ushort f2b(float f) {   // RNE
    unsigned u = __float_as_uint(f);
    return (ushort)((u + 0x7fffu + ((u >> 16) & 1u)) >> 16);
}
__device__ __forceinline__ unsigned pack2(float lo, float hi) {
    return (unsigned)f2b(lo) | ((unsigned)f2b(hi) << 16);
}

__device__ __forceinline__ float wave_reduce_sum(float v) {
    #pragma unroll
    for (int off = 32; off > 0; off >>= 1) v += __shfl_down(v, off, 64);
    return v;
}
__device__ __forceinline__ float wave_allreduce_max(float v) {
    #pragma unroll
    for (int off = 32; off > 0; off >>= 1) v = fmaxf(v, __shfl_xor(v, off, 64));
    return v;
}
__device__ __forceinline__ float wave_allreduce_sum(float v) {
    #pragma unroll
    for (int off = 32; off > 0; off >>= 1) v += __shfl_xor(v, off, 64);
    return v;
}

// ---- BK=64 MFMA K-loop with XOR-swizzled LDS (2-way max bank aliasing) ----------
// LDS slot s (16B) holds row = s>>3, global 16B-chunk g = (s&7) ^ (row&7).
// Frag read for chunk kk*4+quad of row r lives at r*64 + ((kk*4+quad)^(r&7))*8 hw.
__device__ __forceinline__ void mfma_loop64(const ushort* ap[4], const ushort* bp[4],
                                            ushort* __restrict__ As, ushort* __restrict__ Bs,
                                            const int lbase[4],
                                            int K, int wr, int wc, int c0, int l15,
                                            f32x4 acc[4][4]) {
    for (int k0 = 0; k0 < K; k0 += 64) {
        #pragma unroll
        for (int i = 0; i < 4; i++) gl2lds16(ap[i] + k0, As + lbase[i]);
        #pragma unroll
        for (int i = 0; i < 4; i++) gl2lds16(bp[i] + k0, Bs + lbase[i]);
        __syncthreads();
        #pragma unroll
        for (int kk = 0; kk < 2; kk++) {
            const int ca = (c0 ^ (kk * 4)) * 8;
            bf16x8 af[4], bf[4];
            #pragma unroll
            for (int i = 0; i < 4; i++)
                af[i] = *reinterpret_cast<const bf16x8*>(&As[(wr + i * 16 + l15) * 64 + ca]);
            #pragma unroll
            for (int j = 0; j < 4; j++)
                bf[j] = *reinterpret_cast<const bf16x8*>(&Bs[(wc + j * 16 + l15) * 64 + ca]);
            #pragma unroll
            for (int i = 0; i < 4; i++)
                #pragma unroll
                for (int j = 0; j < 4; j++)
                    acc[i][j] = __builtin_amdgcn_mfma_f32_16x16x32_bf16(af[i], bf[j], acc[i][j], 0, 0, 0);
        }
        __syncthreads();
    }
}

// ============== bf16 MFMA GEMM: C = A[M,K]@B  (B given as BT[Npad,K] bf16) =======
// EPI 0: fp32 out = acc (+bias if non-null)
// EPI 3: bf16 out = relu(acc + bias)
// EPI 5: split: col<Fs -> bf16 out (ld Fs); col<2Fs -> fp32 Rf (ld Fs);
//        else -> fp32 Sf (ld Ncols-2Fs). Skips cols >= Ncols entirely.
// K multiple of 64; A rows 16B-aligned; BT zero-padded to grid.x*128 rows.
template<int EPI>
__global__ __launch_bounds__(256) void bgemm(const ushort* __restrict__ A,
                                             const ushort* __restrict__ BT,
                                             const float* __restrict__ bias,
                                             void* __restrict__ out, int ldc,
                                             float* __restrict__ Rf,
                                             float* __restrict__ Sf, int Fs,
                                             int M, int Ncols, int K, int lda) {
    __shared__ ushort As[128 * 64];
    __shared__ ushort Bs[128 * 64];
    const int tid = threadIdx.x;
    const int m0 = blockIdx.y * 128, n0 = blockIdx.x * 128;
    const int w = tid >> 6, lane = tid & 63;
    const int wr = (w >> 1) * 64, wc = (w & 1) * 64;
    const int quad = lane >> 4, l15 = lane & 15;
    const int c0 = quad ^ (l15 & 7);

    const ushort* ap[4];
    const ushort* bp[4];
    int lbase[4];
    #pragma unroll
    for (int i = 0; i < 4; i++) {
        int s = i * 256 + tid;
        int r = s >> 3;
        int gseg = ((s & 7) ^ (r & 7)) * 8;
        int ga = m0 + r; if (ga >= M) ga = M - 1;
        ap[i] = A + (size_t)ga * lda + gseg;
        bp[i] = BT + (size_t)(n0 + r) * K + gseg;
        lbase[i] = (i * 256 + w * 64) * 8;
    }

    f32x4 acc[4][4] = {};
    mfma_loop64(ap, bp, As, Bs, lbase, K, wr, wc, c0, l15, acc);

    const int twoH = Ncols - 2 * Fs;
    #pragma unroll
    for (int i = 0; i < 4; i++) {
        #pragma unroll
        for (int j = 0; j < 4; j++) {
            int col = n0 + wc + j * 16 + l15;
            if (col >= Ncols) continue;
            #pragma unroll
            for (int r = 0; r < 4; r++) {
                int row = m0 + wr + i * 16 + quad * 4 + r;
                if (row >= M) continue;
                float v = acc[i][j][r];
                if (EPI == 0) {
                    if (bias) v += bias[col];
                    ((float*)out)[(size_t)row * ldc + col] = v;
                } else if (EPI == 3) {
                    ((ushort*)out)[(size_t)row * ldc + col] = f2b(fmaxf(v + bias[col], 0.f));
                } else {
                    if (col < Fs) ((ushort*)out)[(size_t)row * Fs + col] = f2b(v);
                    else if (col < 2 * Fs) Rf[(size_t)row * Fs + (col - Fs)] = v;
                    else Sf[(size_t)row * twoH + (col - 2 * Fs)] = v;
                }
            }
        }
    }
}

// ===== fused block-1: H2 = elu(acc_h@W_h + bias1) + h1@res1_w + res1_b (bf16) ====
// grid (8, MB); col block n0 belongs to head h = n0>>8. Both phases K=256.
__global__ __launch_bounds__(256) void bgemm_b1(const ushort* __restrict__ accb,  // N x 1024
                                                const ushort* __restrict__ w1T,   // 1024 x 256
                                                const ushort* __restrict__ h1b,   // N x 256
                                                const ushort* __restrict__ res1T, // 1024 x 256
                                                const float* __restrict__ bias1,
                                                const float* __restrict__ res1b,
                                                ushort* __restrict__ H2b, int M) {
    __shared__ ushort As[128 * 64];
    __shared__ ushort Bs[128 * 64];
    const int tid = threadIdx.x;
    const int m0 = blockIdx.y * 128, n0 = blockIdx.x * 128;
    const int h = n0 >> 8;
    const int w = tid >> 6, lane = tid & 63;
    const int wr = (w >> 1) * 64, wc = (w & 1) * 64;
    const int quad = lane >> 4, l15 = lane & 15;
    const int c0 = quad ^ (l15 & 7);

    int rows_[4], gseg[4], lbase[4], garow[4];
    #pragma unroll
    for (int i = 0; i < 4; i++) {
        int s = i * 256 + tid;
        int r = s >> 3;
        rows_[i] = r;
        gseg[i] = ((s & 7) ^ (r & 7)) * 8;
        int ga = m0 + r; if (ga >= M) ga = M - 1;
        garow[i] = ga;
        lbase[i] = (i * 256 + w * 64) * 8;
    }

    f32x4 acc[4][4] = {};
    const ushort* ap[4];
    const ushort* bp[4];

    // phase 1: acc_h @ W_h
    #pragma unroll
    for (int i = 0; i < 4; i++) {
        ap[i] = accb + (size_t)garow[i] * 1024 + h * 256 + gseg[i];
        bp[i] = w1T + (size_t)(n0 + rows_[i]) * 256 + gseg[i];
    }
    mfma_loop64(ap, bp, As, Bs, lbase, 256, wr, wc, c0, l15, acc);

    // in-register: acc = elu(acc + bias1) + res1_b
    #pragma unroll
    for (int i = 0; i < 4; i++) {
        #pragma unroll
        for (int j = 0; j < 4; j++) {
            int col = n0 + wc + j * 16 + l15;
            float bv = bias1[col], rv = res1b[col];
            #pragma unroll
            for (int r = 0; r < 4; r++) {
                float t = acc[i][j][r] + bv;
                t = t > 0.f ? t : (__expf(t) - 1.f);
                acc[i][j][r] = t + rv;
            }
        }
    }

    // phase 2: += h1 @ res1_w
    #pragma unroll
    for (int i = 0; i < 4; i++) {
        ap[i] = h1b + (size_t)garow[i] * 256 + gseg[i];
        bp[i] = res1T + (size_t)(n0 + rows_[i]) * 256 + gseg[i];
    }
    mfma_loop64(ap, bp, As, Bs, lbase, 256, wr, wc, c0, l15, acc);

    #pragma unroll
    for (int i = 0; i < 4; i++) {
        #pragma unroll
        for (int j = 0; j < 4; j++) {
            int col = n0 + wc + j * 16 + l15;
            #pragma unroll
            for (int r = 0; r < 4; r++) {
                int row = m0 + wr + i * 16 + quad * 4 + r;
                if (row >= M) continue;
                H2b[(size_t)row * 1024 + col] = f2b(acc[i][j][r]);
            }
        }
    }
}

// ---------------- conversions / weight prep ----------------
__global__ void conv_pad_x_kernel(const float* __restrict__ x, ushort* __restrict__ xb, int N) {
    int t = blockIdx.x * 256 + threadIdx.x;
    if (t >= N * 448) return;
    int n = t / 448, k = t - n * 448;
    xb[t] = f2b(k < 405 ? x[(size_t)n * 405 + k] : 0.f);
}

__global__ void prep_bt_kernel(const float* __restrict__ src, ushort* __restrict__ dst,
                               int K, int Nreal, int Kpad, int rows, int ldsrc, int col_off) {
    int t = blockIdx.x * 256 + threadIdx.x;
    if (t >= rows * Kpad) return;
    int n = t / Kpad, k = t - n * Kpad;
    float v = (k < K && n < Nreal) ? src[(size_t)k * ldsrc + n + col_off] : 0.f;
    dst[t] = f2b(v);
}

__global__ void conv_bf16_kernel(const float* __restrict__ src, ushort* __restrict__ dst, int n) {
    int i = blockIdx.x * 256 + threadIdx.x;
    if (i < n) dst[i] = f2b(src[i]);
}

// ---------------- LayerNorm(+ReLU): fp32 in, bf16 out; C == 256 ----------------
__global__ __launch_bounds__(256) void ln_relu_kernel(const float* __restrict__ x,
                                                      const float* __restrict__ g,
                                                      const float* __restrict__ b,
                                                      ushort* __restrict__ out) {
    const int C = 256;
    int row = blockIdx.x;
    int tid = threadIdx.x;
    int lane = tid & 63, wid = tid >> 6;
    __shared__ float red[4];
    float v = x[(size_t)row * C + tid];
    float s = wave_reduce_sum(v);
    if (lane == 0) red[wid] = s;
    __syncthreads();
    float m = (red[0] + red[1] + red[2] + red[3]) * (1.f / C);
    __syncthreads();
    float d = v - m;
    float s2 = wave_reduce_sum(d * d);
    if (lane == 0) red[wid] = s2;
    __syncthreads();
    float var = (red[0] + red[1] + red[2] + red[3]) * (1.f / C);
    float rs = rsqrtf(var + LN_EPS);
    float o = d * rs * g[tid] + b[tid];
    out[(size_t)row * C + tid] = f2b(fmaxf(o, 0.f));
}

// ---- fold attention vectors through W ----
__global__ void fold_att_kernel(const float* __restrict__ W,
                                const float* __restrict__ att_s,
                                const float* __restrict__ att_d,
                                float* __restrict__ qs, float* __restrict__ qd,
                                int Cin, int Cout, int H) {
    int t = blockIdx.x * blockDim.x + threadIdx.x;
    if (t >= H * Cin) return;
    int h = t / Cin, k = t - h * Cin;
    const float* wrow = W + (size_t)k * (H * Cout) + (size_t)h * Cout;
    const float* as = att_s + (size_t)h * Cout;
    const float* ad = att_d + (size_t)h * Cout;
    float ss = 0.f, sd = 0.f;
    for (int c = 0; c < Cout; c++) { float wv = wrow[c]; ss += wv * as[c]; sd += wv * ad[c]; }
    qs[t] = ss;
    qd[t] = sd;
}

// ---- block1 scores: a_s[n,h] = x[n,:] . qs[h,:]  (x bf16) ----
__global__ __launch_bounds__(64) void att_scores_kernel(const ushort* __restrict__ x,
                                                        const float* __restrict__ qs,
                                                        const float* __restrict__ qd,
                                                        float* __restrict__ a_s,
                                                        float* __restrict__ a_d,
                                                        int H, int Cin) {
    int blk = blockIdx.x;
    int n = blk / H, hd = blk - (blk / H) * H;
    int lane = threadIdx.x;
    const ushort* xp = x + (size_t)n * Cin;
    const float* qsp = qs + (size_t)hd * Cin;
    const float* qdp = qd + (size_t)hd * Cin;
    float ss = 0.f, sd = 0.f;
    for (int k = lane; k < Cin; k += 64) {
        float xv = b2f(xp[k]);
        ss += xv * qsp[k];
        sd += xv * qdp[k];
    }
    ss = wave_reduce_sum(ss);
    sd = wave_reduce_sum(sd);
    if (lane == 0) {
        a_s[(size_t)n * H + hd] = ss;
        a_d[(size_t)n * H + hd] = sd;
    }
}

// ================= CSR construction (dst-grouped) =========
__device__ __forceinline__ void edge_sd(const int* ei, int e, int E, int& s, int& d) {
    if (e < E) { s = ei[e]; d = ei[E + e]; } else { s = d = e - E; }
}

__global__ void deg_kernel(const int* __restrict__ ei, int* __restrict__ deg, int E, int Et) {
    int e = blockIdx.x * blockDim.x + threadIdx.x;
    if (e >= Et) return;
    int s, d; edge_sd(ei, e, E, s, d);
    atomicAdd(&deg[d], 1);
}

__global__ __launch_bounds__(256) void scan1_kernel(const int* __restrict__ deg,
                                                    int* __restrict__ incl,
                                                    int* __restrict__ part, int N) {
    __shared__ int sd[256];
    int t = threadIdx.x;
    int i = blockIdx.x * 256 + t;
    int v = (i < N) ? deg[i] : 0;
    sd[t] = v; __syncthreads();
    #pragma unroll
    for (int o = 1; o < 256; o <<= 1) {
        int x = (t >= o) ? sd[t - o] : 0;
        __syncthreads();
        sd[t] += x;
        __syncthreads();
    }
    if (i < N) incl[i] = sd[t];
    if (t == 255) part[blockIdx.x] = sd[255];
}

__global__ __launch_bounds__(256) void scan2_kernel(int* __restrict__ part, int nb) {
    __shared__ int sd[256];
    int t = threadIdx.x;
    int v = (t < nb) ? part[t] : 0;
    sd[t] = v; __syncthreads();
    #pragma unroll
    for (int o = 1; o < 256; o <<= 1) {
        int x = (t >= o) ? sd[t - o] : 0;
        __syncthreads();
        sd[t] += x;
        __syncthreads();
    }
    if (t < nb) part[t] = sd[t];
}

__global__ void scan3_kernel(const int* __restrict__ incl, const int* __restrict__ deg,
                             const int* __restrict__ part, int* __restrict__ row_ptr, int N) {
    int i = blockIdx.x * blockDim.x + threadIdx.x;
    if (i >= N) return;
    int off = (blockIdx.x > 0) ? part[blockIdx.x - 1] : 0;
    row_ptr[i] = incl[i] - deg[i] + off;
}

__global__ void fill_kernel(const int* __restrict__ ei, const int* __restrict__ row_ptr,
                            int* __restrict__ cur, int* __restrict__ csr_src, int E, int Et) {
    int e = blockIdx.x * blockDim.x + threadIdx.x;
    if (e >= Et) return;
    int s, d; edge_sd(ei, e, E, s, d);
    int pos = row_ptr[d] + atomicAdd(&cur[d], 1);
    csr_src[pos] = s;
}

// ======= per-dst softmax stats -> normalized alpha per CSR slot ==
template<int H>
__global__ __launch_bounds__(64) void stats_kernel(const int* __restrict__ row_ptr,
                                                   const int* __restrict__ deg,
                                                   const int* __restrict__ csr_src,
                                                   const float* __restrict__ a_s, int sA,
                                                   const float* __restrict__ a_d, int sD,
                                                   float* __restrict__ alpha) {
    int d = blockIdx.x;
    int lane = threadIdx.x;
    int base = row_ptr[d], dg = deg[d];
    float ad[H];
    #pragma unroll
    for (int h = 0; h < H; h++) ad[h] = a_d[(size_t)d * sD + h];

    float mx[H];
    #pragma unroll
    for (int h = 0; h < H; h++) mx[h] = -1e30f;
    for (int j = lane; j < dg; j += 64) {
        int s = csr_src[base + j];
        #pragma unroll
        for (int h = 0; h < H; h++) {
            float sc = a_s[(size_t)s * sA + h] + ad[h];
            sc = sc > 0.f ? sc : 0.2f * sc;
            mx[h] = fmaxf(mx[h], sc);
        }
    }
    #pragma unroll
    for (int h = 0; h < H; h++) mx[h] = wave_allreduce_max(mx[h]);

    float sm[H];
    #pragma unroll
    for (int h = 0; h < H; h++) sm[h] = 0.f;
    for (int j = lane; j < dg; j += 64) {
        int s = csr_src[base + j];
        #pragma unroll
        for (int h = 0; h < H; h++) {
            float sc = a_s[(size_t)s * sA + h] + ad[h];
            sc = sc > 0.f ? sc : 0.2f * sc;
            sm[h] += __expf(sc - mx[h]);
        }
    }
    float rd[H];
    #pragma unroll
    for (int h = 0; h < H; h++) {
        sm[h] = wave_allreduce_sum(sm[h]);
        rd[h] = 1.f / (sm[h] + 1e-16f);
    }

    for (int j = lane; j < dg; j += 64) {
        int s = csr_src[base + j];
        #pragma unroll
        for (int h = 0; h < H; h++) {
            float sc = a_s[(size_t)s * sA + h] + ad[h];
            sc = sc > 0.f ? sc : 0.2f * sc;
            alpha[(size_t)(base + j) * H + h] = __expf(sc - mx[h]) * rd[h];
        }
    }
}

// ==== block1: gather-aggregate ALL 4 heads (uint-wide, 2 channels/lane) ==========
__global__ __launch_bounds__(128) void aggr_b1_all_kernel(const int* __restrict__ row_ptr,
                                                          const int* __restrict__ deg,
                                                          const int* __restrict__ csr_src,
                                                          const float* __restrict__ alpha,
                                                          const ushort* __restrict__ h1b,
                                                          ushort* __restrict__ accb) {
    int d = blockIdx.x;
    int t = threadIdx.x;   // uint lane: channels 2t, 2t+1
    int base = row_ptr[d], dg = deg[d];
    float a00 = 0, a01 = 0, a10 = 0, a11 = 0, a20 = 0, a21 = 0, a30 = 0, a31 = 0;
    for (int j = 0; j < dg; j++) {
        int s = csr_src[base + j];
        float4 a = *reinterpret_cast<const float4*>(&alpha[(size_t)(base + j) * 4]);
        unsigned v = reinterpret_cast<const unsigned*>(h1b + (size_t)s * 256)[t];
        float lo = b2f((ushort)(v & 0xffff)), hi = b2f((ushort)(v >> 16));
        a00 += a.x * lo; a01 += a.x * hi;
        a10 += a.y * lo; a11 += a.y * hi;
        a20 += a.z * lo; a21 += a.z * hi;
        a30 += a.w * lo; a31 += a.w * hi;
    }
    unsigned* o = reinterpret_cast<unsigned*>(accb + (size_t)d * 1024);
    o[t]       = pack2(a00, a01);
    o[t + 128] = pack2(a10, a11);
    o[t + 256] = pack2(a20, a21);
    o[t + 384] = pack2(a30, a31);
}

// ==== blocks 2/3: gather-aggregate output-space (uint-wide) ======================
template<int H, int C, int F>
__global__ void aggr_flat_kernel(const int* __restrict__ row_ptr,
                                 const int* __restrict__ deg,
                                 const int* __restrict__ csr_src,
                                 const float* __restrict__ alpha,
                                 const ushort* __restrict__ g,
                                 float* __restrict__ out) {
    int d = blockIdx.x;
    int t = threadIdx.x;               // 0..F/2-1
    int hd = (2 * t) / C;
    int base = row_ptr[d], dg = deg[d];
    float lo = 0.f, hi = 0.f;
    for (int j = 0; j < dg; j++) {
        int s = csr_src[base + j];
        float a = alpha[(size_t)(base + j) * H + hd];
        unsigned v = reinterpret_cast<const unsigned*>(g + (size_t)s * F)[t];
        lo += a * b2f((ushort)(v & 0xffff));
        hi += a * b2f((ushort)(v >> 16));
    }
    out[(size_t)d * F + 2 * t]     = lo;
    out[(size_t)d * F + 2 * t + 1] = hi;
}

// ==== elementwise: out_b = elu(O + gb) + R + rb ==================================
__global__ void combine_kernel(const float* __restrict__ O,
                               const float* __restrict__ R, int ldR,
                               const float* __restrict__ gb,
                               const float* __restrict__ rb,
                               ushort* __restrict__ out, int total, int F) {
    int i = blockIdx.x * 256 + threadIdx.x;
    if (i >= total) return;
    int n = i / F, c = i - n * F;
    float o = O[i] + gb[c];
    o = o > 0.f ? o : (__expf(o) - 1.f);
    out[i] = f2b(o + R[(size_t)n * ldR + c] + rb[c]);
}

// ---------------- final tiny GEMM: out[M,2] = A[M,64](bf16) @ W[64,2] + b --------
__global__ __launch_bounds__(256) void mlp2_kernel(const ushort* __restrict__ A,
                                                   const float* __restrict__ W,
                                                   const float* __restrict__ b,
                                                   float* __restrict__ out, int M) {
    __shared__ float w[128];
    __shared__ float bb[2];
    int tid = threadIdx.x;
    if (tid < 128) w[tid] = W[tid];
    if (tid < 2) bb[tid] = b[tid];
    __syncthreads();
    int row = blockIdx.x * 256 + tid;
    if (row >= M) return;
    float a0 = bb[0], a1 = bb[1];
    const ushort* ap = A + (size_t)row * 64;
    #pragma unroll 8
    for (int k = 0; k < 64; k++) {
        float av = b2f(ap[k]);
        a0 += av * w[2 * k];
        a1 += av * w[2 * k + 1];
    }
    out[(size_t)row * 2] = a0;
    out[(size_t)row * 2 + 1] = a1;
}

extern "C" void kernel_launch(void* const* d_in, const int* in_sizes, int n_in,
                              void* d_out, int out_size, void* d_ws, size_t ws_size,
                              hipStream_t stream) {
    const float* x        = (const float*)d_in[0];
    const int*   ei       = (const int*)d_in[1];
    const float* enc_w1   = (const float*)d_in[2];
    const float* enc_b1   = (const float*)d_in[3];
    const float* ln1_g    = (const float*)d_in[4];
    const float* ln1_b    = (const float*)d_in[5];
    const float* enc_w2   = (const float*)d_in[6];
    const float* enc_b2   = (const float*)d_in[7];
    const float* ln2_g    = (const float*)d_in[8];
    const float* ln2_b    = (const float*)d_in[9];
    const float* w1       = (const float*)d_in[10];
    const float* att_src1 = (const float*)d_in[11];
    const float* att_dst1 = (const float*)d_in[12];
    const float* bias1    = (const float*)d_in[13];
    const float* res1_w   = (const float*)d_in[14];
    const float* res1_b   = (const float*)d_in[15];
    const float* w2       = (const float*)d_in[16];
    const float* att_src2 = (const float*)d_in[17];
    const float* att_dst2 = (const float*)d_in[18];
    const float* bias2    = (const float*)d_in[19];
    const float* res2_w   = (const float*)d_in[20];
    const float* res2_b   = (const float*)d_in[21];
    const float* w3       = (const float*)d_in[22];
    const float* att_src3 = (const float*)d_in[23];
    const float* att_dst3 = (const float*)d_in[24];
    const float* bias3    = (const float*)d_in[25];
    const float* res3_w   = (const float*)d_in[26];
    const float* res3_b   = (const float*)d_in[27];
    const float* mlp_w1   = (const float*)d_in[28];
    const float* mlp_b1   = (const float*)d_in[29];
    const float* mlp_w2   = (const float*)d_in[30];
    const float* mlp_b2   = (const float*)d_in[31];

    const int N  = in_sizes[0] / 405;   // 50000
    const int E  = in_sizes[1] / 2;     // 300000
    const int Et = E + N;
    const int NB = (N + 255) / 256;

    // ---------- workspace layout (bytes), ~311 MB ----------
    char* p = (char*)d_ws;
    char* R0 = p;                       // N*896 B : xb(448 b16) | O2(f32 192) | O3(f32 128) | M1b
    char* R1 = R0 + (size_t)N * 896;    // N*512 B : h0b | G2b | H3b
    char* R2 = R1 + (size_t)N * 512;    // N*512 B : h1b | G3b , H4b(@+N*256B)
    char* R3 = R2 + (size_t)N * 512;    // N*2048 B: F1(f32 256) | H2b(b16 1024)
    char* R4 = R3 + (size_t)N * 2048;   // N*2048 B: accb(b16 1024) | Rf2(f32 192) | Rf3(f32 128)
    char* T  = R4 + (size_t)N * 2048;   // tail

    ushort* xb   = (ushort*)R0;
    float*  O2   = (float*)R0;
    float*  O3   = (float*)R0;
    ushort* M1b  = (ushort*)R0;
    ushort* h0b  = (ushort*)R1;
    ushort* G2b  = (ushort*)R1;
    ushort* H3b  = (ushort*)R1;
    ushort* h1b  = (ushort*)R2;
    ushort* G3b  = (ushort*)R2;
    ushort* H4b  = (ushort*)(R2 + (size_t)N * 256);
    float*  F1   = (float*)R3;
    ushort* H2b  = (ushort*)R3;
    ushort* accb = (ushort*)R4;
    float*  Rf   = (float*)R4;

    float* a_s   = (float*)T;                         T += (size_t)N * 4 * 4;   // also Sf2/Sf3
    float* a_d   = (float*)T;                         T += (size_t)N * 4 * 4;
    float* alpha = (float*)T;                         T += (size_t)Et * 4 * 4;
    float* qs    = (float*)T;                         T += 2048 * 4;
    float* qd    = (float*)T;                         T += 2048 * 4;
    int* deg     = (int*)T;                           T += (size_t)N * 4;
    int* cur     = (int*)T;                           T += (size_t)N * 4;
    int* row_ptr = (int*)T;                           T += (size_t)N * 4;
    int* incl    = (int*)T;                           T += (size_t)N * 4;
    int* part    = (int*)T;                           T += 256 * 4;
    int* csr_src = (int*)T;                           T += (size_t)Et * 4;
    ushort* enc_w1T = (ushort*)T;                     T += (size_t)256 * 448 * 2;
    ushort* enc_w2T = (ushort*)T;                     T += (size_t)256 * 256 * 2;
    ushort* w1T     = (ushort*)T;                     T += (size_t)1024 * 256 * 2;
    ushort* res1T   = (ushort*)T;                     T += (size_t)1024 * 256 * 2;
    ushort* Bcat2T  = (ushort*)T;                     T += (size_t)512 * 1024 * 2;
    ushort* Bcat3T  = (ushort*)T;                     T += (size_t)384 * 192 * 2;
    ushort* mlpw1T  = (ushort*)T;                     T += (size_t)128 * 128 * 2;

    auto cdiv = [](int a, int b) { return (a + b - 1) / b; };
    const int MB = cdiv(N, 128);

    // ---- CSR build ----
    hipMemsetAsync(deg, 0, (size_t)N * 8, stream);   // deg + cur
    deg_kernel<<<cdiv(Et, 256), 256, 0, stream>>>(ei, deg, E, Et);
    scan1_kernel<<<NB, 256, 0, stream>>>(deg, incl, part, N);
    scan2_kernel<<<1, 256, 0, stream>>>(part, NB);
    scan3_kernel<<<NB, 256, 0, stream>>>(incl, deg, part, row_ptr, N);
    fill_kernel<<<cdiv(Et, 256), 256, 0, stream>>>(ei, row_ptr, cur, csr_src, E, Et);

    // ---- weight prep (bf16, transposed, padded) ----
    prep_bt_kernel<<<cdiv(256 * 448, 256), 256, 0, stream>>>(enc_w1, enc_w1T, 405, 256, 448, 256, 256, 0);
    prep_bt_kernel<<<cdiv(256 * 256, 256), 256, 0, stream>>>(enc_w2, enc_w2T, 256, 256, 256, 256, 256, 0);
    prep_bt_kernel<<<cdiv(1024 * 256, 256), 256, 0, stream>>>(w1, w1T, 256, 1024, 256, 1024, 1024, 0);
    prep_bt_kernel<<<cdiv(1024 * 256, 256), 256, 0, stream>>>(res1_w, res1T, 256, 1024, 256, 1024, 1024, 0);
    prep_bt_kernel<<<cdiv(192 * 1024, 256), 256, 0, stream>>>(w2, Bcat2T, 1024, 192, 1024, 192, 192, 0);
    prep_bt_kernel<<<cdiv(192 * 1024, 256), 256, 0, stream>>>(res2_w, Bcat2T + (size_t)192 * 1024, 1024, 192, 1024, 192, 192, 0);
    prep_bt_kernel<<<cdiv(124 * 1024, 256), 256, 0, stream>>>(w2, Bcat2T + (size_t)388 * 1024, 0, 0, 1024, 124, 192, 0);
    prep_bt_kernel<<<cdiv(128 * 192, 256), 256, 0, stream>>>(w3, Bcat3T, 192, 128, 192, 128, 128, 0);
    prep_bt_kernel<<<cdiv(128 * 192, 256), 256, 0, stream>>>(res3_w, Bcat3T + (size_t)128 * 192, 192, 128, 192, 128, 128, 0);
    prep_bt_kernel<<<cdiv(126 * 192, 256), 256, 0, stream>>>(w3, Bcat3T + (size_t)258 * 192, 0, 0, 192, 126, 128, 0);
    prep_bt_kernel<<<cdiv(128 * 128, 256), 256, 0, stream>>>(mlp_w1, mlpw1T, 128, 64, 128, 128, 64, 0);

    // ---- JointEncoder ----
    conv_pad_x_kernel<<<cdiv(N * 448, 256), 256, 0, stream>>>(x, xb, N);
    bgemm<0><<<dim3(2, MB), 256, 0, stream>>>(xb, enc_w1T, enc_b1, F1, 256, nullptr, nullptr, 0, N, 256, 448, 448);
    ln_relu_kernel<<<N, 256, 0, stream>>>(F1, ln1_g, ln1_b, h0b);
    bgemm<0><<<dim3(2, MB), 256, 0, stream>>>(h0b, enc_w2T, enc_b2, F1, 256, nullptr, nullptr, 0, N, 256, 256, 256);
    ln_relu_kernel<<<N, 256, 0, stream>>>(F1, ln2_g, ln2_b, h1b);

    // ---- Block 1: GAT 256 -> 4x256 concat (fused head GEMMs + residual) ----
    {
        fold_att_kernel<<<cdiv(4 * 256, 256), 256, 0, stream>>>(w1, att_src1, att_dst1, qs, qd, 256, 256, 4);
        att_scores_kernel<<<N * 4, 64, 0, stream>>>(h1b, qs, qd, a_s, a_d, 4, 256);
        stats_kernel<4><<<N, 64, 0, stream>>>(row_ptr, deg, csr_src, a_s, 4, a_d, 4, alpha);
        aggr_b1_all_kernel<<<N, 128, 0, stream>>>(row_ptr, deg, csr_src, alpha, h1b, accb);
        bgemm_b1<<<dim3(8, MB), 256, 0, stream>>>(accb, w1T, h1b, res1T, bias1, res1_b, H2b, N);
    }

    // ---- Block 2: GAT 1024 -> 2x96 concat (G/R/scores in one split-epilogue GEMM) --
    {
        fold_att_kernel<<<cdiv(2 * 1024, 256), 256, 0, stream>>>(w2, att_src2, att_dst2, qs, qd, 1024, 96, 2);
        conv_bf16_kernel<<<cdiv(2048, 256), 256, 0, stream>>>(qs, Bcat2T + (size_t)384 * 1024, 2048);
        conv_bf16_kernel<<<cdiv(2048, 256), 256, 0, stream>>>(qd, Bcat2T + (size_t)386 * 1024, 2048);
        // cols: [0,192)=G2b bf16, [192,384)=Rf fp32, [384,388)=scores -> a_s[N,4]
        bgemm<5><<<dim3(4, MB), 256, 0, stream>>>(H2b, Bcat2T, nullptr, G2b, 0, Rf, a_s, 192, N, 388, 1024, 1024);
        stats_kernel<2><<<N, 64, 0, stream>>>(row_ptr, deg, csr_src, a_s, 4, a_s + 2, 4, alpha);
        aggr_flat_kernel<2, 96, 192><<<N, 96, 0, stream>>>(row_ptr, deg, csr_src, alpha, G2b, O2);
        combine_kernel<<<cdiv(N * 192, 256), 256, 0, stream>>>(O2, Rf, 192, bias2, res2_b, H3b, N * 192, 192);
    }

    // ---- Block 3: GAT 192 -> 1x128 (no concat) ----
    {
        fold_att_kernel<<<cdiv(192, 192), 192, 0, stream>>>(w3, att_src3, att_dst3, qs, qd, 192, 128, 1);
        conv_bf16_kernel<<<1, 256, 0, stream>>>(qs, Bcat3T + (size_t)256 * 192, 192);
        conv_bf16_kernel<<<1, 256, 0, stream>>>(qd, Bcat3T + (size_t)257 * 192, 192);
        // cols: [0,128)=G3b bf16, [128,256)=Rf fp32, [256,258)=scores -> a_s[N,2]
        bgemm<5><<<dim3(3, MB), 256, 0, stream>>>(H3b, Bcat3T, nullptr, G3b, 0, Rf, a_s, 128, N, 258, 192, 192);
        stats_kernel<1><<<N, 64, 0, stream>>>(row_ptr, deg, csr_src, a_s, 2, a_s + 1, 2, alpha);
        aggr_flat_kernel<1, 128, 128><<<N, 64, 0, stream>>>(row_ptr, deg, csr_src, alpha, G3b, O3);
        combine_kernel<<<cdiv(N * 128, 256), 256, 0, stream>>>(O3, Rf, 128, bias3, res3_b, H4b, N * 128, 128);
    }

    // ---- MLP head ----
    bgemm<3><<<dim3(1, MB), 256, 0, stream>>>(H4b, mlpw1T, mlp_b1, M1b, 64, nullptr, nullptr, 0, N, 64, 128, 128);
    mlp2_kernel<<<cdiv(N, 256), 256, 0, stream>>>(M1b, mlp_w2, mlp_b2, (float*)d_out, N);
}

// Round 7
// 1019.238 us; speedup vs baseline: 9.6258x; 1.0279x over previous
//
#include <hip/hip_runtime.h>
#include <cstddef>

#define LN_EPS 1e-5f

typedef __bf16 bf16x8 __attribute__((ext_vector_type(8)));
typedef float  f32x4  __attribute__((ext_vector_type(4)));

typedef __attribute__((address_space(3))) unsigned int lds_u32;
typedef __attribute__((address_space(1))) unsigned int glb_u32;

__device__ __forceinline__ void gl2lds16(const void* g, void* l) {
    // 16B per lane DMA: LDS dest = wave-uniform base + lane*16
    __builtin_amdgcn_global_load_lds((const glb_u32*)g, (lds_u32*)l, 16, 0, 0);
}

__device__ __forceinline__ float b2f(ushort h) {
    return __uint_as_float(((unsigned)h) << 16);
}
__device__ __forceinline__ ushort f2b(float f) {   // RNE
    unsigned u = __float_as_uint(f);
    return (ushort)((u + 0x7fffu + ((u >> 16) & 1u)) >> 16);
}
__device__ __forceinline__ unsigned pack2(float lo, float hi) {
    return (unsigned)f2b(lo) | ((unsigned)f2b(hi) << 16);
}

// XCD-aware remap: all gridDim.x col-blocks of one row-block get linear ids
// congruent mod 8 -> same XCD -> A row-tile fetched into ONE L2, not 8.
// Identity on the tail so the map stays a bijection.
__device__ __forceinline__ void xcd_map(int& bx, int& by) {
    int NX = gridDim.x, MBr = gridDim.y;
    int L = blockIdx.y * NX + blockIdx.x;
    int G = NX * 8;
    int g = L / G;
    if (g * 8 + 8 <= MBr) {
        int r = L - g * G;
        by = g * 8 + (r & 7);
        bx = r >> 3;
    } else {
        by = L / NX;
        bx = L - by * NX;
    }
}

__device__ __forceinline__ float wave_reduce_sum(float v) {
    #pragma unroll
    for (int off = 32; off > 0; off >>= 1) v += __shfl_down(v, off, 64);
    return v;
}
__device__ __forceinline__ float wave_allreduce_max(float v) {
    #pragma unroll
    for (int off = 32; off > 0; off >>= 1) v = fmaxf(v, __shfl_xor(v, off, 64));
    return v;
}
__device__ __forceinline__ float wave_allreduce_sum(float v) {
    #pragma unroll
    for (int off = 32; off > 0; off >>= 1) v += __shfl_xor(v, off, 64);
    return v;
}

// ---- BK=64 MFMA K-loop with XOR-swizzled LDS (2-way max bank aliasing) ----------
__device__ __forceinline__ void mfma_loop64(const ushort* ap[4], const ushort* bp[4],
                                            ushort* __restrict__ As, ushort* __restrict__ Bs,
                                            const int lbase[4],
                                            int K, int wr, int wc, int c0, int l15,
                                            f32x4 acc[4][4]) {
    for (int k0 = 0; k0 < K; k0 += 64) {
        #pragma unroll
        for (int i = 0; i < 4; i++) gl2lds16(ap[i] + k0, As + lbase[i]);
        #pragma unroll
        for (int i = 0; i < 4; i++) gl2lds16(bp[i] + k0, Bs + lbase[i]);
        __syncthreads();
        #pragma unroll
        for (int kk = 0; kk < 2; kk++) {
            const int ca = (c0 ^ (kk * 4)) * 8;
            bf16x8 af[4], bf[4];
            #pragma unroll
            for (int i = 0; i < 4; i++)
                af[i] = *reinterpret_cast<const bf16x8*>(&As[(wr + i * 16 + l15) * 64 + ca]);
            #pragma unroll
            for (int j = 0; j < 4; j++)
                bf[j] = *reinterpret_cast<const bf16x8*>(&Bs[(wc + j * 16 + l15) * 64 + ca]);
            #pragma unroll
            for (int i = 0; i < 4; i++)
                #pragma unroll
                for (int j = 0; j < 4; j++)
                    acc[i][j] = __builtin_amdgcn_mfma_f32_16x16x32_bf16(af[i], bf[j], acc[i][j], 0, 0, 0);
        }
        __syncthreads();
    }
}

// ============== bf16 MFMA GEMM: C = A[M,K]@B  (B given as BT[Npad,K] bf16) =======
// EPI 0: fp32 out = acc (+bias if non-null)
// EPI 3: bf16 out = relu(acc + bias)
// EPI 5: split: col<Fs -> bf16 out; col<2Fs -> fp32 Rf; else fp32 Sf.
template<int EPI>
__global__ __launch_bounds__(256) void bgemm(const ushort* __restrict__ A,
                                             const ushort* __restrict__ BT,
                                             const float* __restrict__ bias,
                                             void* __restrict__ out, int ldc,
                                             float* __restrict__ Rf,
                                             float* __restrict__ Sf, int Fs,
                                             int M, int Ncols, int K, int lda) {
    __shared__ ushort As[128 * 64];
    __shared__ ushort Bs[128 * 64];
    const int tid = threadIdx.x;
    int bx, by; xcd_map(bx, by);
    const int m0 = by * 128, n0 = bx * 128;
    const int w = tid >> 6, lane = tid & 63;
    const int wr = (w >> 1) * 64, wc = (w & 1) * 64;
    const int quad = lane >> 4, l15 = lane & 15;
    const int c0 = quad ^ (l15 & 7);

    const ushort* ap[4];
    const ushort* bp[4];
    int lbase[4];
    #pragma unroll
    for (int i = 0; i < 4; i++) {
        int s = i * 256 + tid;
        int r = s >> 3;
        int gseg = ((s & 7) ^ (r & 7)) * 8;
        int ga = m0 + r; if (ga >= M) ga = M - 1;
        ap[i] = A + (size_t)ga * lda + gseg;
        bp[i] = BT + (size_t)(n0 + r) * K + gseg;
        lbase[i] = (i * 256 + w * 64) * 8;
    }

    f32x4 acc[4][4] = {};
    mfma_loop64(ap, bp, As, Bs, lbase, K, wr, wc, c0, l15, acc);

    const int twoH = Ncols - 2 * Fs;
    #pragma unroll
    for (int i = 0; i < 4; i++) {
        #pragma unroll
        for (int j = 0; j < 4; j++) {
            int col = n0 + wc + j * 16 + l15;
            if (col >= Ncols) continue;
            #pragma unroll
            for (int r = 0; r < 4; r++) {
                int row = m0 + wr + i * 16 + quad * 4 + r;
                if (row >= M) continue;
                float v = acc[i][j][r];
                if (EPI == 0) {
                    if (bias) v += bias[col];
                    ((float*)out)[(size_t)row * ldc + col] = v;
                } else if (EPI == 3) {
                    ((ushort*)out)[(size_t)row * ldc + col] = f2b(fmaxf(v + bias[col], 0.f));
                } else {
                    if (col < Fs) ((ushort*)out)[(size_t)row * Fs + col] = f2b(v);
                    else if (col < 2 * Fs) Rf[(size_t)row * Fs + (col - Fs)] = v;
                    else Sf[(size_t)row * twoH + (col - 2 * Fs)] = v;
                }
            }
        }
    }
}

// ===== fused block-1: H2 = elu(acc_h@W_h + bias1) + h1@res1_w + res1_b (bf16) ====
__global__ __launch_bounds__(256) void bgemm_b1(const ushort* __restrict__ accb,  // N x 1024
                                                const ushort* __restrict__ w1T,   // 1024 x 256
                                                const ushort* __restrict__ h1b,   // N x 256
                                                const ushort* __restrict__ res1T, // 1024 x 256
                                                const float* __restrict__ bias1,
                                                const float* __restrict__ res1b,
                                                ushort* __restrict__ H2b, int M) {
    __shared__ ushort As[128 * 64];
    __shared__ ushort Bs[128 * 64];
    const int tid = threadIdx.x;
    int bx, by; xcd_map(bx, by);
    const int m0 = by * 128, n0 = bx * 128;
    const int h = n0 >> 8;
    const int w = tid >> 6, lane = tid & 63;
    const int wr = (w >> 1) * 64, wc = (w & 1) * 64;
    const int quad = lane >> 4, l15 = lane & 15;
    const int c0 = quad ^ (l15 & 7);

    int rows_[4], gseg[4], lbase[4], garow[4];
    #pragma unroll
    for (int i = 0; i < 4; i++) {
        int s = i * 256 + tid;
        int r = s >> 3;
        rows_[i] = r;
        gseg[i] = ((s & 7) ^ (r & 7)) * 8;
        int ga = m0 + r; if (ga >= M) ga = M - 1;
        garow[i] = ga;
        lbase[i] = (i * 256 + w * 64) * 8;
    }

    f32x4 acc[4][4] = {};
    const ushort* ap[4];
    const ushort* bp[4];

    // phase 1: acc_h @ W_h
    #pragma unroll
    for (int i = 0; i < 4; i++) {
        ap[i] = accb + (size_t)garow[i] * 1024 + h * 256 + gseg[i];
        bp[i] = w1T + (size_t)(n0 + rows_[i]) * 256 + gseg[i];
    }
    mfma_loop64(ap, bp, As, Bs, lbase, 256, wr, wc, c0, l15, acc);

    // in-register: acc = elu(acc + bias1) + res1_b
    #pragma unroll
    for (int i = 0; i < 4; i++) {
        #pragma unroll
        for (int j = 0; j < 4; j++) {
            int col = n0 + wc + j * 16 + l15;
            float bv = bias1[col], rv = res1b[col];
            #pragma unroll
            for (int r = 0; r < 4; r++) {
                float t = acc[i][j][r] + bv;
                t = t > 0.f ? t : (__expf(t) - 1.f);
                acc[i][j][r] = t + rv;
            }
        }
    }

    // phase 2: += h1 @ res1_w
    #pragma unroll
    for (int i = 0; i < 4; i++) {
        ap[i] = h1b + (size_t)garow[i] * 256 + gseg[i];
        bp[i] = res1T + (size_t)(n0 + rows_[i]) * 256 + gseg[i];
    }
    mfma_loop64(ap, bp, As, Bs, lbase, 256, wr, wc, c0, l15, acc);

    #pragma unroll
    for (int i = 0; i < 4; i++) {
        #pragma unroll
        for (int j = 0; j < 4; j++) {
            int col = n0 + wc + j * 16 + l15;
            #pragma unroll
            for (int r = 0; r < 4; r++) {
                int row = m0 + wr + i * 16 + quad * 4 + r;
                if (row >= M) continue;
                H2b[(size_t)row * 1024 + col] = f2b(acc[i][j][r]);
            }
        }
    }
}

// ---------------- conversions / weight prep ----------------
__global__ void conv_pad_x_kernel(const float* __restrict__ x, ushort* __restrict__ xb, int N) {
    int t = blockIdx.x * 256 + threadIdx.x;
    if (t >= N * 448) return;
    int n = t / 448, k = t - n * 448;
    xb[t] = f2b(k < 405 ? x[(size_t)n * 405 + k] : 0.f);
}

__global__ void prep_bt_kernel(const float* __restrict__ src, ushort* __restrict__ dst,
                               int K, int Nreal, int Kpad, int rows, int ldsrc, int col_off) {
    int t = blockIdx.x * 256 + threadIdx.x;
    if (t >= rows * Kpad) return;
    int n = t / Kpad, k = t - n * Kpad;
    float v = (k < K && n < Nreal) ? src[(size_t)k * ldsrc + n + col_off] : 0.f;
    dst[t] = f2b(v);
}

__global__ void conv_bf16_kernel(const float* __restrict__ src, ushort* __restrict__ dst, int n) {
    int i = blockIdx.x * 256 + threadIdx.x;
    if (i < n) dst[i] = f2b(src[i]);
}

// ---------------- LayerNorm(+ReLU): fp32 in, bf16 out; C == 256 ----------------
__global__ __launch_bounds__(256) void ln_relu_kernel(const float* __restrict__ x,
                                                      const float* __restrict__ g,
                                                      const float* __restrict__ b,
                                                      ushort* __restrict__ out) {
    const int C = 256;
    int row = blockIdx.x;
    int tid = threadIdx.x;
    int lane = tid & 63, wid = tid >> 6;
    __shared__ float red[4];
    float v = x[(size_t)row * C + tid];
    float s = wave_reduce_sum(v);
    if (lane == 0) red[wid] = s;
    __syncthreads();
    float m = (red[0] + red[1] + red[2] + red[3]) * (1.f / C);
    __syncthreads();
    float d = v - m;
    float s2 = wave_reduce_sum(d * d);
    if (lane == 0) red[wid] = s2;
    __syncthreads();
    float var = (red[0] + red[1] + red[2] + red[3]) * (1.f / C);
    float rs = rsqrtf(var + LN_EPS);
    float o = d * rs * g[tid] + b[tid];
    out[(size_t)row * C + tid] = f2b(fmaxf(o, 0.f));
}

// ---- fold attention vectors through W ----
__global__ void fold_att_kernel(const float* __restrict__ W,
                                const float* __restrict__ att_s,
                                const float* __restrict__ att_d,
                                float* __restrict__ qs, float* __restrict__ qd,
                                int Cin, int Cout, int H) {
    int t = blockIdx.x * blockDim.x + threadIdx.x;
    if (t >= H * Cin) return;
    int h = t / Cin, k = t - h * Cin;
    const float* wrow = W + (size_t)k * (H * Cout) + (size_t)h * Cout;
    const float* as = att_s + (size_t)h * Cout;
    const float* ad = att_d + (size_t)h * Cout;
    float ss = 0.f, sd = 0.f;
    for (int c = 0; c < Cout; c++) { float wv = wrow[c]; ss += wv * as[c]; sd += wv * ad[c]; }
    qs[t] = ss;
    qd[t] = sd;
}

// ---- block1 scores: a_s[n,h] = x[n,:] . qs[h,:]  (x bf16) ----
__global__ __launch_bounds__(64) void att_scores_kernel(const ushort* __restrict__ x,
                                                        const float* __restrict__ qs,
                                                        const float* __restrict__ qd,
                                                        float* __restrict__ a_s,
                                                        float* __restrict__ a_d,
                                                        int H, int Cin) {
    int blk = blockIdx.x;
    int n = blk / H, hd = blk - (blk / H) * H;
    int lane = threadIdx.x;
    const ushort* xp = x + (size_t)n * Cin;
    const float* qsp = qs + (size_t)hd * Cin;
    const float* qdp = qd + (size_t)hd * Cin;
    float ss = 0.f, sd = 0.f;
    for (int k = lane; k < Cin; k += 64) {
        float xv = b2f(xp[k]);
        ss += xv * qsp[k];
        sd += xv * qdp[k];
    }
    ss = wave_reduce_sum(ss);
    sd = wave_reduce_sum(sd);
    if (lane == 0) {
        a_s[(size_t)n * H + hd] = ss;
        a_d[(size_t)n * H + hd] = sd;
    }
}

// ================= CSR construction (dst-grouped) =========
__device__ __forceinline__ void edge_sd(const int* ei, int e, int E, int& s, int& d) {
    if (e < E) { s = ei[e]; d = ei[E + e]; } else { s = d = e - E; }
}

__global__ void deg_kernel(const int* __restrict__ ei, int* __restrict__ deg, int E, int Et) {
    int e = blockIdx.x * blockDim.x + threadIdx.x;
    if (e >= Et) return;
    int s, d; edge_sd(ei, e, E, s, d);
    atomicAdd(&deg[d], 1);
}

__global__ __launch_bounds__(256) void scan1_kernel(const int* __restrict__ deg,
                                                    int* __restrict__ incl,
                                                    int* __restrict__ part, int N) {
    __shared__ int sd[256];
    int t = threadIdx.x;
    int i = blockIdx.x * 256 + t;
    int v = (i < N) ? deg[i] : 0;
    sd[t] = v; __syncthreads();
    #pragma unroll
    for (int o = 1; o < 256; o <<= 1) {
        int x = (t >= o) ? sd[t - o] : 0;
        __syncthreads();
        sd[t] += x;
        __syncthreads();
    }
    if (i < N) incl[i] = sd[t];
    if (t == 255) part[blockIdx.x] = sd[255];
}

__global__ __launch_bounds__(256) void scan2_kernel(int* __restrict__ part, int nb) {
    __shared__ int sd[256];
    int t = threadIdx.x;
    int v = (t < nb) ? part[t] : 0;
    sd[t] = v; __syncthreads();
    #pragma unroll
    for (int o = 1; o < 256; o <<= 1) {
        int x = (t >= o) ? sd[t - o] : 0;
        __syncthreads();
        sd[t] += x;
        __syncthreads();
    }
    if (t < nb) part[t] = sd[t];
}

__global__ void scan3_kernel(const int* __restrict__ incl, const int* __restrict__ deg,
                             const int* __restrict__ part, int* __restrict__ row_ptr, int N) {
    int i = blockIdx.x * blockDim.x + threadIdx.x;
    if (i >= N) return;
    int off = (blockIdx.x > 0) ? part[blockIdx.x - 1] : 0;
    row_ptr[i] = incl[i] - deg[i] + off;
}

__global__ void fill_kernel(const int* __restrict__ ei, const int* __restrict__ row_ptr,
                            int* __restrict__ cur, int* __restrict__ csr_src, int E, int Et) {
    int e = blockIdx.x * blockDim.x + threadIdx.x;
    if (e >= Et) return;
    int s, d; edge_sd(ei, e, E, s, d);
    int pos = row_ptr[d] + atomicAdd(&cur[d], 1);
    csr_src[pos] = s;
}

// ======= per-dst softmax stats -> normalized alpha per CSR slot ==
template<int H>
__global__ __launch_bounds__(64) void stats_kernel(const int* __restrict__ row_ptr,
                                                   const int* __restrict__ deg,
                                                   const int* __restrict__ csr_src,
                                                   const float* __restrict__ a_s, int sA,
                                                   const float* __restrict__ a_d, int sD,
                                                   float* __restrict__ alpha) {
    int d = blockIdx.x;
    int lane = threadIdx.x;
    int base = row_ptr[d], dg = deg[d];
    float ad[H];
    #pragma unroll
    for (int h = 0; h < H; h++) ad[h] = a_d[(size_t)d * sD + h];

    float mx[H];
    #pragma unroll
    for (int h = 0; h < H; h++) mx[h] = -1e30f;
    for (int j = lane; j < dg; j += 64) {
        int s = csr_src[base + j];
        #pragma unroll
        for (int h = 0; h < H; h++) {
            float sc = a_s[(size_t)s * sA + h] + ad[h];
            sc = sc > 0.f ? sc : 0.2f * sc;
            mx[h] = fmaxf(mx[h], sc);
        }
    }
    #pragma unroll
    for (int h = 0; h < H; h++) mx[h] = wave_allreduce_max(mx[h]);

    float sm[H];
    #pragma unroll
    for (int h = 0; h < H; h++) sm[h] = 0.f;
    for (int j = lane; j < dg; j += 64) {
        int s = csr_src[base + j];
        #pragma unroll
        for (int h = 0; h < H; h++) {
            float sc = a_s[(size_t)s * sA + h] + ad[h];
            sc = sc > 0.f ? sc : 0.2f * sc;
            sm[h] += __expf(sc - mx[h]);
        }
    }
    float rd[H];
    #pragma unroll
    for (int h = 0; h < H; h++) {
        sm[h] = wave_allreduce_sum(sm[h]);
        rd[h] = 1.f / (sm[h] + 1e-16f);
    }

    for (int j = lane; j < dg; j += 64) {
        int s = csr_src[base + j];
        #pragma unroll
        for (int h = 0; h < H; h++) {
            float sc = a_s[(size_t)s * sA + h] + ad[h];
            sc = sc > 0.f ? sc : 0.2f * sc;
            alpha[(size_t)(base + j) * H + h] = __expf(sc - mx[h]) * rd[h];
        }
    }
}

// ==== block1: gather-aggregate ALL 4 heads (uint-wide, 2 channels/lane) ==========
__global__ __launch_bounds__(128) void aggr_b1_all_kernel(const int* __restrict__ row_ptr,
                                                          const int* __restrict__ deg,
                                                          const int* __restrict__ csr_src,
                                                          const float* __restrict__ alpha,
                                                          const ushort* __restrict__ h1b,
                                                          ushort* __restrict__ accb) {
    int d = blockIdx.x;
    int t = threadIdx.x;   // uint lane: channels 2t, 2t+1
    int base = row_ptr[d], dg = deg[d];
    float a00 = 0, a01 = 0, a10 = 0, a11 = 0, a20 = 0, a21 = 0, a30 = 0, a31 = 0;
    for (int j = 0; j < dg; j++) {
        int s = csr_src[base + j];
        float4 a = *reinterpret_cast<const float4*>(&alpha[(size_t)(base + j) * 4]);
        unsigned v = reinterpret_cast<const unsigned*>(h1b + (size_t)s * 256)[t];
        float lo = b2f((ushort)(v & 0xffff)), hi = b2f((ushort)(v >> 16));
        a00 += a.x * lo; a01 += a.x * hi;
        a10 += a.y * lo; a11 += a.y * hi;
        a20 += a.z * lo; a21 += a.z * hi;
        a30 += a.w * lo; a31 += a.w * hi;
    }
    unsigned* o = reinterpret_cast<unsigned*>(accb + (size_t)d * 1024);
    o[t]       = pack2(a00, a01);
    o[t + 128] = pack2(a10, a11);
    o[t + 256] = pack2(a20, a21);
    o[t + 384] = pack2(a30, a31);
}

// ==== blocks 2/3: gather-aggregate output-space (uint-wide) ======================
template<int H, int C, int F>
__global__ void aggr_flat_kernel(const int* __restrict__ row_ptr,
                                 const int* __restrict__ deg,
                                 const int* __restrict__ csr_src,
                                 const float* __restrict__ alpha,
                                 const ushort* __restrict__ g,
                                 float* __restrict__ out) {
    int d = blockIdx.x;
    int t = threadIdx.x;               // 0..F/2-1
    int hd = (2 * t) / C;
    int base = row_ptr[d], dg = deg[d];
    float lo = 0.f, hi = 0.f;
    for (int j = 0; j < dg; j++) {
        int s = csr_src[base + j];
        float a = alpha[(size_t)(base + j) * H + hd];
        unsigned v = reinterpret_cast<const unsigned*>(g + (size_t)s * F)[t];
        lo += a * b2f((ushort)(v & 0xffff));
        hi += a * b2f((ushort)(v >> 16));
    }
    out[(size_t)d * F + 2 * t]     = lo;
    out[(size_t)d * F + 2 * t + 1] = hi;
}

// ==== elementwise: out_b = elu(O + gb) + R + rb ==================================
__global__ void combine_kernel(const float* __restrict__ O,
                               const float* __restrict__ R, int ldR,
                               const float* __restrict__ gb,
                               const float* __restrict__ rb,
                               ushort* __restrict__ out, int total, int F) {
    int i = blockIdx.x * 256 + threadIdx.x;
    if (i >= total) return;
    int n = i / F, c = i - n * F;
    float o = O[i] + gb[c];
    o = o > 0.f ? o : (__expf(o) - 1.f);
    out[i] = f2b(o + R[(size_t)n * ldR + c] + rb[c]);
}

// ---------------- final tiny GEMM: out[M,2] = A[M,64](bf16) @ W[64,2] + b --------
__global__ __launch_bounds__(256) void mlp2_kernel(const ushort* __restrict__ A,
                                                   const float* __restrict__ W,
                                                   const float* __restrict__ b,
                                                   float* __restrict__ out, int M) {
    __shared__ float w[128];
    __shared__ float bb[2];
    int tid = threadIdx.x;
    if (tid < 128) w[tid] = W[tid];
    if (tid < 2) bb[tid] = b[tid];
    __syncthreads();
    int row = blockIdx.x * 256 + tid;
    if (row >= M) return;
    float a0 = bb[0], a1 = bb[1];
    const ushort* ap = A + (size_t)row * 64;
    #pragma unroll 8
    for (int k = 0; k < 64; k++) {
        float av = b2f(ap[k]);
        a0 += av * w[2 * k];
        a1 += av * w[2 * k + 1];
    }
    out[(size_t)row * 2] = a0;
    out[(size_t)row * 2 + 1] = a1;
}

extern "C" void kernel_launch(void* const* d_in, const int* in_sizes, int n_in,
                              void* d_out, int out_size, void* d_ws, size_t ws_size,
                              hipStream_t stream) {
    const float* x        = (const float*)d_in[0];
    const int*   ei       = (const int*)d_in[1];
    const float* enc_w1   = (const float*)d_in[2];
    const float* enc_b1   = (const float*)d_in[3];
    const float* ln1_g    = (const float*)d_in[4];
    const float* ln1_b    = (const float*)d_in[5];
    const float* enc_w2   = (const float*)d_in[6];
    const float* enc_b2   = (const float*)d_in[7];
    const float* ln2_g    = (const float*)d_in[8];
    const float* ln2_b    = (const float*)d_in[9];
    const float* w1       = (const float*)d_in[10];
    const float* att_src1 = (const float*)d_in[11];
    const float* att_dst1 = (const float*)d_in[12];
    const float* bias1    = (const float*)d_in[13];
    const float* res1_w   = (const float*)d_in[14];
    const float* res1_b   = (const float*)d_in[15];
    const float* w2       = (const float*)d_in[16];
    const float* att_src2 = (const float*)d_in[17];
    const float* att_dst2 = (const float*)d_in[18];
    const float* bias2    = (const float*)d_in[19];
    const float* res2_w   = (const float*)d_in[20];
    const float* res2_b   = (const float*)d_in[21];
    const float* w3       = (const float*)d_in[22];
    const float* att_src3 = (const float*)d_in[23];
    const float* att_dst3 = (const float*)d_in[24];
    const float* bias3    = (const float*)d_in[25];
    const float* res3_w   = (const float*)d_in[26];
    const float* res3_b   = (const float*)d_in[27];
    const float* mlp_w1   = (const float*)d_in[28];
    const float* mlp_b1   = (const float*)d_in[29];
    const float* mlp_w2   = (const float*)d_in[30];
    const float* mlp_b2   = (const float*)d_in[31];

    const int N  = in_sizes[0] / 405;   // 50000
    const int E  = in_sizes[1] / 2;     // 300000
    const int Et = E + N;
    const int NB = (N + 255) / 256;

    // ---------- workspace layout (bytes), ~311 MB ----------
    char* p = (char*)d_ws;
    char* R0 = p;                       // N*896 B : xb(448 b16) | O2(f32 192) | O3(f32 128) | M1b
    char* R1 = R0 + (size_t)N * 896;    // N*512 B : h0b | G2b | H3b
    char* R2 = R1 + (size_t)N * 512;    // N*512 B : h1b | G3b , H4b(@+N*256B)
    char* R3 = R2 + (size_t)N * 512;    // N*2048 B: F1(f32 256) | H2b(b16 1024)
    char* R4 = R3 + (size_t)N * 2048;   // N*2048 B: accb(b16 1024) | Rf2(f32 192) | Rf3(f32 128)
    char* T  = R4 + (size_t)N * 2048;   // tail

    ushort* xb   = (ushort*)R0;
    float*  O2   = (float*)R0;
    float*  O3   = (float*)R0;
    ushort* M1b  = (ushort*)R0;
    ushort* h0b  = (ushort*)R1;
    ushort* G2b  = (ushort*)R1;
    ushort* H3b  = (ushort*)R1;
    ushort* h1b  = (ushort*)R2;
    ushort* G3b  = (ushort*)R2;
    ushort* H4b  = (ushort*)(R2 + (size_t)N * 256);
    float*  F1   = (float*)R3;
    ushort* H2b  = (ushort*)R3;
    ushort* accb = (ushort*)R4;
    float*  Rf   = (float*)R4;

    float* a_s   = (float*)T;                         T += (size_t)N * 4 * 4;   // also Sf2/Sf3
    float* a_d   = (float*)T;                         T += (size_t)N * 4 * 4;
    float* alpha = (float*)T;                         T += (size_t)Et * 4 * 4;
    float* qs    = (float*)T;                         T += 2048 * 4;
    float* qd    = (float*)T;                         T += 2048 * 4;
    int* deg     = (int*)T;                           T += (size_t)N * 4;
    int* cur     = (int*)T;                           T += (size_t)N * 4;
    int* row_ptr = (int*)T;                           T += (size_t)N * 4;
    int* incl    = (int*)T;                           T += (size_t)N * 4;
    int* part    = (int*)T;                           T += 256 * 4;
    int* csr_src = (int*)T;                           T += (size_t)Et * 4;
    ushort* enc_w1T = (ushort*)T;                     T += (size_t)256 * 448 * 2;
    ushort* enc_w2T = (ushort*)T;                     T += (size_t)256 * 256 * 2;
    ushort* w1T     = (ushort*)T;                     T += (size_t)1024 * 256 * 2;
    ushort* res1T   = (ushort*)T;                     T += (size_t)1024 * 256 * 2;
    ushort* Bcat2T  = (ushort*)T;                     T += (size_t)512 * 1024 * 2;
    ushort* Bcat3T  = (ushort*)T;                     T += (size_t)384 * 192 * 2;
    ushort* mlpw1T  = (ushort*)T;                     T += (size_t)128 * 128 * 2;

    auto cdiv = [](int a, int b) { return (a + b - 1) / b; };
    const int MB = cdiv(N, 128);

    // ---- CSR build ----
    hipMemsetAsync(deg, 0, (size_t)N * 8, stream);   // deg + cur
    deg_kernel<<<cdiv(Et, 256), 256, 0, stream>>>(ei, deg, E, Et);
    scan1_kernel<<<NB, 256, 0, stream>>>(deg, incl, part, N);
    scan2_kernel<<<1, 256, 0, stream>>>(part, NB);
    scan3_kernel<<<NB, 256, 0, stream>>>(incl, deg, part, row_ptr, N);
    fill_kernel<<<cdiv(Et, 256), 256, 0, stream>>>(ei, row_ptr, cur, csr_src, E, Et);

    // ---- weight prep (bf16, transposed, padded) ----
    prep_bt_kernel<<<cdiv(256 * 448, 256), 256, 0, stream>>>(enc_w1, enc_w1T, 405, 256, 448, 256, 256, 0);
    prep_bt_kernel<<<cdiv(256 * 256, 256), 256, 0, stream>>>(enc_w2, enc_w2T, 256, 256, 256, 256, 256, 0);
    prep_bt_kernel<<<cdiv(1024 * 256, 256), 256, 0, stream>>>(w1, w1T, 256, 1024, 256, 1024, 1024, 0);
    prep_bt_kernel<<<cdiv(1024 * 256, 256), 256, 0, stream>>>(res1_w, res1T, 256, 1024, 256, 1024, 1024, 0);
    prep_bt_kernel<<<cdiv(192 * 1024, 256), 256, 0, stream>>>(w2, Bcat2T, 1024, 192, 1024, 192, 192, 0);
    prep_bt_kernel<<<cdiv(192 * 1024, 256), 256, 0, stream>>>(res2_w, Bcat2T + (size_t)192 * 1024, 1024, 192, 1024, 192, 192, 0);
    prep_bt_kernel<<<cdiv(124 * 1024, 256), 256, 0, stream>>>(w2, Bcat2T + (size_t)388 * 1024, 0, 0, 1024, 124, 192, 0);
    prep_bt_kernel<<<cdiv(128 * 192, 256), 256, 0, stream>>>(w3, Bcat3T, 192, 128, 192, 128, 128, 0);
    prep_bt_kernel<<<cdiv(128 * 192, 256), 256, 0, stream>>>(res3_w, Bcat3T + (size_t)128 * 192, 192, 128, 192, 128, 128, 0);
    prep_bt_kernel<<<cdiv(126 * 192, 256), 256, 0, stream>>>(w3, Bcat3T + (size_t)258 * 192, 0, 0, 192, 126, 128, 0);
    prep_bt_kernel<<<cdiv(128 * 128, 256), 256, 0, stream>>>(mlp_w1, mlpw1T, 128, 64, 128, 128, 64, 0);

    // ---- JointEncoder ----
    conv_pad_x_kernel<<<cdiv(N * 448, 256), 256, 0, stream>>>(x, xb, N);
    bgemm<0><<<dim3(2, MB), 256, 0, stream>>>(xb, enc_w1T, enc_b1, F1, 256, nullptr, nullptr, 0, N, 256, 448, 448);
    ln_relu_kernel<<<N, 256, 0, stream>>>(F1, ln1_g, ln1_b, h0b);
    bgemm<0><<<dim3(2, MB), 256, 0, stream>>>(h0b, enc_w2T, enc_b2, F1, 256, nullptr, nullptr, 0, N, 256, 256, 256);
    ln_relu_kernel<<<N, 256, 0, stream>>>(F1, ln2_g, ln2_b, h1b);

    // ---- Block 1: GAT 256 -> 4x256 concat (fused head GEMMs + residual) ----
    {
        fold_att_kernel<<<cdiv(4 * 256, 256), 256, 0, stream>>>(w1, att_src1, att_dst1, qs, qd, 256, 256, 4);
        att_scores_kernel<<<N * 4, 64, 0, stream>>>(h1b, qs, qd, a_s, a_d, 4, 256);
        stats_kernel<4><<<N, 64, 0, stream>>>(row_ptr, deg, csr_src, a_s, 4, a_d, 4, alpha);
        aggr_b1_all_kernel<<<N, 128, 0, stream>>>(row_ptr, deg, csr_src, alpha, h1b, accb);
        bgemm_b1<<<dim3(8, MB), 256, 0, stream>>>(accb, w1T, h1b, res1T, bias1, res1_b, H2b, N);
    }

    // ---- Block 2: GAT 1024 -> 2x96 concat (G/R/scores in one split-epilogue GEMM) --
    {
        fold_att_kernel<<<cdiv(2 * 1024, 256), 256, 0, stream>>>(w2, att_src2, att_dst2, qs, qd, 1024, 96, 2);
        conv_bf16_kernel<<<cdiv(2048, 256), 256, 0, stream>>>(qs, Bcat2T + (size_t)384 * 1024, 2048);
        conv_bf16_kernel<<<cdiv(2048, 256), 256, 0, stream>>>(qd, Bcat2T + (size_t)386 * 1024, 2048);
        // cols: [0,192)=G2b bf16, [192,384)=Rf fp32, [384,388)=scores -> a_s[N,4]
        bgemm<5><<<dim3(4, MB), 256, 0, stream>>>(H2b, Bcat2T, nullptr, G2b, 0, Rf, a_s, 192, N, 388, 1024, 1024);
        stats_kernel<2><<<N, 64, 0, stream>>>(row_ptr, deg, csr_src, a_s, 4, a_s + 2, 4, alpha);
        aggr_flat_kernel<2, 96, 192><<<N, 96, 0, stream>>>(row_ptr, deg, csr_src, alpha, G2b, O2);
        combine_kernel<<<cdiv(N * 192, 256), 256, 0, stream>>>(O2, Rf, 192, bias2, res2_b, H3b, N * 192, 192);
    }

    // ---- Block 3: GAT 192 -> 1x128 (no concat) ----
    {
        fold_att_kernel<<<cdiv(192, 192), 192, 0, stream>>>(w3, att_src3, att_dst3, qs, qd, 192, 128, 1);
        conv_bf16_kernel<<<1, 256, 0, stream>>>(qs, Bcat3T + (size_t)256 * 192, 192);
        conv_bf16_kernel<<<1, 256, 0, stream>>>(qd, Bcat3T + (size_t)257 * 192, 192);
        // cols: [0,128)=G3b bf16, [128,256)=Rf fp32, [256,258)=scores -> a_s[N,2]
        bgemm<5><<<dim3(3, MB), 256, 0, stream>>>(H3b, Bcat3T, nullptr, G3b, 0, Rf, a_s, 128, N, 258, 192, 192);
        stats_kernel<1><<<N, 64, 0, stream>>>(row_ptr, deg, csr_src, a_s, 2, a_s + 1, 2, alpha);
        aggr_flat_kernel<1, 128, 128><<<N, 64, 0, stream>>>(row_ptr, deg, csr_src, alpha, G3b, O3);
        combine_kernel<<<cdiv(N * 128, 256), 256, 0, stream>>>(O3, Rf, 128, bias3, res3_b, H4b, N * 128, 128);
    }

    // ---- MLP head ----
    bgemm<3><<<dim3(1, MB), 256, 0, stream>>>(H4b, mlpw1T, mlp_b1, M1b, 64, nullptr, nullptr, 0, N, 64, 128, 128);
    mlp2_kernel<<<cdiv(N, 256), 256, 0, stream>>>(M1b, mlp_w2, mlp_b2, (float*)d_out, N);
}

// Round 9
// 951.726 us; speedup vs baseline: 10.3086x; 1.0709x over previous
//
#include <hip/hip_runtime.h>
#include <cstddef>

#define LN_EPS 1e-5f

typedef __bf16 bf16x8 __attribute__((ext_vector_type(8)));
typedef float  f32x4  __attribute__((ext_vector_type(4)));

typedef __attribute__((address_space(3))) unsigned int lds_u32;
typedef __attribute__((address_space(1))) unsigned int glb_u32;

__device__ __forceinline__ void gl2lds16(const void* g, void* l) {
    // 16B per lane DMA: LDS dest = wave-uniform base + lane*16
    __builtin_amdgcn_global_load_lds((const glb_u32*)g, (lds_u32*)l, 16, 0, 0);
}

__device__ __forceinline__ float b2f(ushort h) {
    return __uint_as_float(((unsigned)h) << 16);
}
__device__ __forceinline__ ushort f2b(float f) {   // RNE
    unsigned u = __float_as_uint(f);
    return (ushort)((u + 0x7fffu + ((u >> 16) & 1u)) >> 16);
}
__device__ __forceinline__ unsigned pack2(float lo, float hi) {
    return (unsigned)f2b(lo) | ((unsigned)f2b(hi) << 16);
}

// XCD-aware remap: all gridDim.x col-blocks of one row-block land on one XCD.
__device__ __forceinline__ void xcd_map(int& bx, int& by) {
    int NX = gridDim.x, MBr = gridDim.y;
    int L = blockIdx.y * NX + blockIdx.x;
    int G = NX * 8;
    int g = L / G;
    if (g * 8 + 8 <= MBr) {
        int r = L - g * G;
        by = g * 8 + (r & 7);
        bx = r >> 3;
    } else {
        by = L / NX;
        bx = L - by * NX;
    }
}

__device__ __forceinline__ float wave_reduce_sum(float v) {
    #pragma unroll
    for (int off = 32; off > 0; off >>= 1) v += __shfl_down(v, off, 64);
    return v;
}
__device__ __forceinline__ float wave_allreduce_max(float v) {
    #pragma unroll
    for (int off = 32; off > 0; off >>= 1) v = fmaxf(v, __shfl_xor(v, off, 64));
    return v;
}
__device__ __forceinline__ float wave_allreduce_sum(float v) {
    #pragma unroll
    for (int off = 32; off > 0; off >>= 1) v += __shfl_xor(v, off, 64);
    return v;
}

// ---- BK=32 double-buffered MFMA K-loop, XOR-swizzled (2-way max aliasing) -------
// LDS slot s (16B): row r = s>>2, holds global chunk (s&3) ^ ((r>>1)&3).
// Read row R chunk q at ushort addr R*32 + (q ^ ((R>>1)&3))*8.
__device__ __forceinline__ void stage32(const ushort* a0, const ushort* a1,
                                        const ushort* b0, const ushort* b1,
                                        ushort* __restrict__ As, ushort* __restrict__ Bs,
                                        int lb0, int lb1) {
    gl2lds16(a0, As + lb0);
    gl2lds16(a1, As + lb1);
    gl2lds16(b0, Bs + lb0);
    gl2lds16(b1, Bs + lb1);
}

__device__ __forceinline__ void mfma_loop32(const ushort* aA0, const ushort* aA1,
                                            const ushort* aB0, const ushort* aB1,
                                            ushort* __restrict__ As0, ushort* __restrict__ As1,
                                            ushort* __restrict__ Bs0, ushort* __restrict__ Bs1,
                                            int lb0, int lb1,
                                            int K, int wr, int wc, int cA, int l15,
                                            f32x4 acc[4][4]) {
    stage32(aA0, aA1, aB0, aB1, As0, Bs0, lb0, lb1);   // prime buffer 0
    int p = 0;
    for (int k0 = 0; k0 < K; k0 += 32) {
        __syncthreads();                               // drains current buffer's DMA
        const ushort* Ac = p ? As1 : As0;
        const ushort* Bc = p ? Bs1 : Bs0;
        ushort* Ad = p ? As0 : As1;
        ushort* Bd = p ? Bs0 : Bs1;
        int kn = k0 + 32;
        if (kn < K) stage32(aA0 + kn, aA1 + kn, aB0 + kn, aB1 + kn, Ad, Bd, lb0, lb1);
        bf16x8 af[4], bf[4];
        #pragma unroll
        for (int i = 0; i < 4; i++)
            af[i] = *reinterpret_cast<const bf16x8*>(&Ac[(wr + i * 16 + l15) * 32 + cA]);
        #pragma unroll
        for (int j = 0; j < 4; j++)
            bf[j] = *reinterpret_cast<const bf16x8*>(&Bc[(wc + j * 16 + l15) * 32 + cA]);
        #pragma unroll
        for (int i = 0; i < 4; i++)
            #pragma unroll
            for (int j = 0; j < 4; j++)
                acc[i][j] = __builtin_amdgcn_mfma_f32_16x16x32_bf16(af[i], bf[j], acc[i][j], 0, 0, 0);
        p ^= 1;
    }
    __syncthreads();   // protect LDS reuse (phase 2 / epilogue)
}

// ============== bf16 MFMA GEMM: C = A[M,K]@B  (B given as BT[Npad,K] bf16) =======
// EPI 0: fp32 out = acc (+bias if non-null)
// EPI 3: bf16 out = relu(acc + bias)
// EPI 5: split: col<Fs -> bf16 out; col<2Fs -> fp32 Rf; else fp32 Sf.
template<int EPI>
__global__ __launch_bounds__(256) void bgemm(const ushort* __restrict__ A,
                                             const ushort* __restrict__ BT,
                                             const float* __restrict__ bias,
                                             void* __restrict__ out, int ldc,
                                             float* __restrict__ Rf,
                                             float* __restrict__ Sf, int Fs,
                                             int M, int Ncols, int K, int lda) {
    __shared__ ushort As[2][128 * 32];
    __shared__ ushort Bs[2][128 * 32];
    const int tid = threadIdx.x;
    int bx, by; xcd_map(bx, by);
    const int m0 = by * 128, n0 = bx * 128;
    const int w = tid >> 6, lane = tid & 63;
    const int wr = (w >> 1) * 64, wc = (w & 1) * 64;
    const int quad = lane >> 4, l15 = lane & 15;
    const int cA = (quad ^ ((l15 >> 1) & 3)) * 8;
    const int lb0 = w * 512, lb1 = lb0 + 2048;

    const int s0 = tid, s1 = tid + 256;
    const int r0 = s0 >> 2, g0 = ((s0 & 3) ^ ((s0 >> 3) & 3)) * 8;
    const int r1 = s1 >> 2, g1 = ((s1 & 3) ^ ((s1 >> 3) & 3)) * 8;
    int ga0 = m0 + r0; if (ga0 >= M) ga0 = M - 1;
    int ga1 = m0 + r1; if (ga1 >= M) ga1 = M - 1;
    const ushort* aA0 = A + (size_t)ga0 * lda + g0;
    const ushort* aA1 = A + (size_t)ga1 * lda + g1;
    const ushort* aB0 = BT + (size_t)(n0 + r0) * K + g0;
    const ushort* aB1 = BT + (size_t)(n0 + r1) * K + g1;

    f32x4 acc[4][4] = {};
    mfma_loop32(aA0, aA1, aB0, aB1, As[0], As[1], Bs[0], Bs[1], lb0, lb1,
                K, wr, wc, cA, l15, acc);

    const int twoH = Ncols - 2 * Fs;
    #pragma unroll
    for (int i = 0; i < 4; i++) {
        #pragma unroll
        for (int j = 0; j < 4; j++) {
            int col = n0 + wc + j * 16 + l15;
            if (col >= Ncols) continue;
            #pragma unroll
            for (int r = 0; r < 4; r++) {
                int row = m0 + wr + i * 16 + quad * 4 + r;
                if (row >= M) continue;
                float v = acc[i][j][r];
                if (EPI == 0) {
                    if (bias) v += bias[col];
                    ((float*)out)[(size_t)row * ldc + col] = v;
                } else if (EPI == 3) {
                    ((ushort*)out)[(size_t)row * ldc + col] = f2b(fmaxf(v + bias[col], 0.f));
                } else {
                    if (col < Fs) ((ushort*)out)[(size_t)row * Fs + col] = f2b(v);
                    else if (col < 2 * Fs) Rf[(size_t)row * Fs + (col - Fs)] = v;
                    else Sf[(size_t)row * twoH + (col - 2 * Fs)] = v;
                }
            }
        }
    }
}

// ===== fused block-1: H2 = elu(acc_h@W_h + bias1) + h1@res1_w + res1_b (bf16) ====
__global__ __launch_bounds__(256) void bgemm_b1(const ushort* __restrict__ accb,  // N x 1024
                                                const ushort* __restrict__ w1T,   // 1024 x 256
                                                const ushort* __restrict__ h1b,   // N x 256
                                                const ushort* __restrict__ res1T, // 1024 x 256
                                                const float* __restrict__ bias1,
                                                const float* __restrict__ res1b,
                                                ushort* __restrict__ H2b, int M) {
    __shared__ ushort As[2][128 * 32];
    __shared__ ushort Bs[2][128 * 32];
    const int tid = threadIdx.x;
    int bx, by; xcd_map(bx, by);
    const int m0 = by * 128, n0 = bx * 128;
    const int h = n0 >> 8;
    const int w = tid >> 6, lane = tid & 63;
    const int wr = (w >> 1) * 64, wc = (w & 1) * 64;
    const int quad = lane >> 4, l15 = lane & 15;
    const int cA = (quad ^ ((l15 >> 1) & 3)) * 8;
    const int lb0 = w * 512, lb1 = lb0 + 2048;

    const int s0 = tid, s1 = tid + 256;
    const int r0 = s0 >> 2, g0 = ((s0 & 3) ^ ((s0 >> 3) & 3)) * 8;
    const int r1 = s1 >> 2, g1 = ((s1 & 3) ^ ((s1 >> 3) & 3)) * 8;
    int ga0 = m0 + r0; if (ga0 >= M) ga0 = M - 1;
    int ga1 = m0 + r1; if (ga1 >= M) ga1 = M - 1;

    f32x4 acc[4][4] = {};

    // phase 1: acc_h @ W_h
    mfma_loop32(accb + (size_t)ga0 * 1024 + h * 256 + g0,
                accb + (size_t)ga1 * 1024 + h * 256 + g1,
                w1T + (size_t)(n0 + r0) * 256 + g0,
                w1T + (size_t)(n0 + r1) * 256 + g1,
                As[0], As[1], Bs[0], Bs[1], lb0, lb1, 256, wr, wc, cA, l15, acc);

    // in-register: acc = elu(acc + bias1) + res1_b
    #pragma unroll
    for (int i = 0; i < 4; i++) {
        #pragma unroll
        for (int j = 0; j < 4; j++) {
            int col = n0 + wc + j * 16 + l15;
            float bv = bias1[col], rv = res1b[col];
            #pragma unroll
            for (int r = 0; r < 4; r++) {
                float t = acc[i][j][r] + bv;
                t = t > 0.f ? t : (__expf(t) - 1.f);
                acc[i][j][r] = t + rv;
            }
        }
    }

    // phase 2: += h1 @ res1_w
    mfma_loop32(h1b + (size_t)ga0 * 256 + g0,
                h1b + (size_t)ga1 * 256 + g1,
                res1T + (size_t)(n0 + r0) * 256 + g0,
                res1T + (size_t)(n0 + r1) * 256 + g1,
                As[0], As[1], Bs[0], Bs[1], lb0, lb1, 256, wr, wc, cA, l15, acc);

    #pragma unroll
    for (int i = 0; i < 4; i++) {
        #pragma unroll
        for (int j = 0; j < 4; j++) {
            int col = n0 + wc + j * 16 + l15;
            #pragma unroll
            for (int r = 0; r < 4; r++) {
                int row = m0 + wr + i * 16 + quad * 4 + r;
                if (row >= M) continue;
                H2b[(size_t)row * 1024 + col] = f2b(acc[i][j][r]);
            }
        }
    }
}

// ---------------- conversions / weight prep ----------------
__global__ void conv_pad_x_kernel(const float* __restrict__ x, ushort* __restrict__ xb, int N) {
    int t = blockIdx.x * 256 + threadIdx.x;
    if (t >= N * 448) return;
    int n = t / 448, k = t - n * 448;
    xb[t] = f2b(k < 405 ? x[(size_t)n * 405 + k] : 0.f);
}

__global__ void prep_bt_kernel(const float* __restrict__ src, ushort* __restrict__ dst,
                               int K, int Nreal, int Kpad, int rows, int ldsrc, int col_off) {
    int t = blockIdx.x * 256 + threadIdx.x;
    if (t >= rows * Kpad) return;
    int n = t / Kpad, k = t - n * Kpad;
    float v = (k < K && n < Nreal) ? src[(size_t)k * ldsrc + n + col_off] : 0.f;
    dst[t] = f2b(v);
}

__global__ void conv_bf16_kernel(const float* __restrict__ src, ushort* __restrict__ dst, int n) {
    int i = blockIdx.x * 256 + threadIdx.x;
    if (i < n) dst[i] = f2b(src[i]);
}

// ---------------- LayerNorm(+ReLU): fp32 in, bf16 out; C == 256 ----------------
__global__ __launch_bounds__(256) void ln_relu_kernel(const float* __restrict__ x,
                                                      const float* __restrict__ g,
                                                      const float* __restrict__ b,
                                                      ushort* __restrict__ out) {
    const int C = 256;
    int row = blockIdx.x;
    int tid = threadIdx.x;
    int lane = tid & 63, wid = tid >> 6;
    __shared__ float red[4];
    float v = x[(size_t)row * C + tid];
    float s = wave_reduce_sum(v);
    if (lane == 0) red[wid] = s;
    __syncthreads();
    float m = (red[0] + red[1] + red[2] + red[3]) * (1.f / C);
    __syncthreads();
    float d = v - m;
    float s2 = wave_reduce_sum(d * d);
    if (lane == 0) red[wid] = s2;
    __syncthreads();
    float var = (red[0] + red[1] + red[2] + red[3]) * (1.f / C);
    float rs = rsqrtf(var + LN_EPS);
    float o = d * rs * g[tid] + b[tid];
    out[(size_t)row * C + tid] = f2b(fmaxf(o, 0.f));
}

// ---- fold attention vectors through W ----
__global__ void fold_att_kernel(const float* __restrict__ W,
                                const float* __restrict__ att_s,
                                const float* __restrict__ att_d,
                                float* __restrict__ qs, float* __restrict__ qd,
                                int Cin, int Cout, int H) {
    int t = blockIdx.x * blockDim.x + threadIdx.x;
    if (t >= H * Cin) return;
    int h = t / Cin, k = t - h * Cin;
    const float* wrow = W + (size_t)k * (H * Cout) + (size_t)h * Cout;
    const float* as = att_s + (size_t)h * Cout;
    const float* ad = att_d + (size_t)h * Cout;
    float ss = 0.f, sd = 0.f;
    for (int c = 0; c < Cout; c++) { float wv = wrow[c]; ss += wv * as[c]; sd += wv * ad[c]; }
    qs[t] = ss;
    qd[t] = sd;
}

// ---- block1 scores, ALL 4 heads per wave (reads h1 row once) ----
__global__ __launch_bounds__(64) void att_scores4_kernel(const ushort* __restrict__ x,
                                                         const float* __restrict__ qs,
                                                         const float* __restrict__ qd,
                                                         float* __restrict__ a_s,
                                                         float* __restrict__ a_d) {
    int n = blockIdx.x;
    int lane = threadIdx.x;
    const ushort* xp = x + (size_t)n * 256 + lane * 4;
    uint2 xv = *reinterpret_cast<const uint2*>(xp);
    float v[4] = { b2f((ushort)(xv.x & 0xffff)), b2f((ushort)(xv.x >> 16)),
                   b2f((ushort)(xv.y & 0xffff)), b2f((ushort)(xv.y >> 16)) };
    float rs[4], rd[4];
    #pragma unroll
    for (int h = 0; h < 4; h++) {
        const float* qsp = qs + h * 256 + lane * 4;
        const float* qdp = qd + h * 256 + lane * 4;
        float ss = 0.f, sd = 0.f;
        #pragma unroll
        for (int k = 0; k < 4; k++) { ss += v[k] * qsp[k]; sd += v[k] * qdp[k]; }
        rs[h] = wave_reduce_sum(ss);
        rd[h] = wave_reduce_sum(sd);
    }
    if (lane == 0) {
        *reinterpret_cast<float4*>(&a_s[(size_t)n * 4]) = make_float4(rs[0], rs[1], rs[2], rs[3]);
        *reinterpret_cast<float4*>(&a_d[(size_t)n * 4]) = make_float4(rd[0], rd[1], rd[2], rd[3]);
    }
}

// ================= CSR construction (dst-grouped) =========
__device__ __forceinline__ void edge_sd(const int* ei, int e, int E, int& s, int& d) {
    if (e < E) { s = ei[e]; d = ei[E + e]; } else { s = d = e - E; }
}

__global__ void deg_kernel(const int* __restrict__ ei, int* __restrict__ deg, int E, int Et) {
    int e = blockIdx.x * blockDim.x + threadIdx.x;
    if (e >= Et) return;
    int s, d; edge_sd(ei, e, E, s, d);
    atomicAdd(&deg[d], 1);
}

__global__ __launch_bounds__(256) void scan1_kernel(const int* __restrict__ deg,
                                                    int* __restrict__ incl,
                                                    int* __restrict__ part, int N) {
    __shared__ int sd[256];
    int t = threadIdx.x;
    int i = blockIdx.x * 256 + t;
    int v = (i < N) ? deg[i] : 0;
    sd[t] = v; __syncthreads();
    #pragma unroll
    for (int o = 1; o < 256; o <<= 1) {
        int x = (t >= o) ? sd[t - o] : 0;
        __syncthreads();
        sd[t] += x;
        __syncthreads();
    }
    if (i < N) incl[i] = sd[t];
    if (t == 255) part[blockIdx.x] = sd[255];
}

__global__ __launch_bounds__(256) void scan2_kernel(int* __restrict__ part, int nb) {
    __shared__ int sd[256];
    int t = threadIdx.x;
    int v = (t < nb) ? part[t] : 0;
    sd[t] = v; __syncthreads();
    #pragma unroll
    for (int o = 1; o < 256; o <<= 1) {
        int x = (t >= o) ? sd[t - o] : 0;
        __syncthreads();
        sd[t] += x;
        __syncthreads();
    }
    if (t < nb) part[t] = sd[t];
}

__global__ void scan3_kernel(const int* __restrict__ incl, const int* __restrict__ deg,
                             const int* __restrict__ part, int* __restrict__ row_ptr, int N) {
    int i = blockIdx.x * blockDim.x + threadIdx.x;
    if (i >= N) return;
    int off = (blockIdx.x > 0) ? part[blockIdx.x - 1] : 0;
    row_ptr[i] = incl[i] - deg[i] + off;
}

__global__ void fill_kernel(const int* __restrict__ ei, const int* __restrict__ row_ptr,
                            int* __restrict__ cur, int* __restrict__ csr_src, int E, int Et) {
    int e = blockIdx.x * blockDim.x + threadIdx.x;
    if (e >= Et) return;
    int s, d; edge_sd(ei, e, E, s, d);
    int pos = row_ptr[d] + atomicAdd(&cur[d], 1);
    csr_src[pos] = s;
}

// ======= per-dst softmax stats -> normalized alpha per CSR slot ==
template<int H>
__global__ __launch_bounds__(64) void stats_kernel(const int* __restrict__ row_ptr,
                                                   const int* __restrict__ deg,
                                                   const int* __restrict__ csr_src,
                                                   const float* __restrict__ a_s, int sA,
                                                   const float* __restrict__ a_d, int sD,
                                                   float* __restrict__ alpha) {
    int d = blockIdx.x;
    int lane = threadIdx.x;
    int base = row_ptr[d], dg = deg[d];
    float ad[H];
    #pragma unroll
    for (int h = 0; h < H; h++) ad[h] = a_d[(size_t)d * sD + h];

    float mx[H];
    #pragma unroll
    for (int h = 0; h < H; h++) mx[h] = -1e30f;
    for (int j = lane; j < dg; j += 64) {
        int s = csr_src[base + j];
        #pragma unroll
        for (int h = 0; h < H; h++) {
            float sc = a_s[(size_t)s * sA + h] + ad[h];
            sc = sc > 0.f ? sc : 0.2f * sc;
            mx[h] = fmaxf(mx[h], sc);
        }
    }
    #pragma unroll
    for (int h = 0; h < H; h++) mx[h] = wave_allreduce_max(mx[h]);

    float sm[H];
    #pragma unroll
    for (int h = 0; h < H; h++) sm[h] = 0.f;
    for (int j = lane; j < dg; j += 64) {
        int s = csr_src[base + j];
        #pragma unroll
        for (int h = 0; h < H; h++) {
            float sc = a_s[(size_t)s * sA + h] + ad[h];
            sc = sc > 0.f ? sc : 0.2f * sc;
            sm[h] += __expf(sc - mx[h]);
        }
    }
    float rd[H];
    #pragma unroll
    for (int h = 0; h < H; h++) {
        sm[h] = wave_allreduce_sum(sm[h]);
        rd[h] = 1.f / (sm[h] + 1e-16f);
    }

    for (int j = lane; j < dg; j += 64) {
        int s = csr_src[base + j];
        #pragma unroll
        for (int h = 0; h < H; h++) {
            float sc = a_s[(size_t)s * sA + h] + ad[h];
            sc = sc > 0.f ? sc : 0.2f * sc;
            alpha[(size_t)(base + j) * H + h] = __expf(sc - mx[h]) * rd[h];
        }
    }
}

// ==== block1: gather-aggregate ALL 4 heads (uint-wide, 2 channels/lane) ==========
__global__ __launch_bounds__(128) void aggr_b1_all_kernel(const int* __restrict__ row_ptr,
                                                          const int* __restrict__ deg,
                                                          const int* __restrict__ csr_src,
                                                          const float* __restrict__ alpha,
                                                          const ushort* __restrict__ h1b,
                                                          ushort* __restrict__ accb) {
    int d = blockIdx.x;
    int t = threadIdx.x;   // uint lane: channels 2t, 2t+1
    int base = row_ptr[d], dg = deg[d];
    float a00 = 0, a01 = 0, a10 = 0, a11 = 0, a20 = 0, a21 = 0, a30 = 0, a31 = 0;
    for (int j = 0; j < dg; j++) {
        int s = csr_src[base + j];
        float4 a = *reinterpret_cast<const float4*>(&alpha[(size_t)(base + j) * 4]);
        unsigned v = reinterpret_cast<const unsigned*>(h1b + (size_t)s * 256)[t];
        float lo = b2f((ushort)(v & 0xffff)), hi = b2f((ushort)(v >> 16));
        a00 += a.x * lo; a01 += a.x * hi;
        a10 += a.y * lo; a11 += a.y * hi;
        a20 += a.z * lo; a21 += a.z * hi;
        a30 += a.w * lo; a31 += a.w * hi;
    }
    unsigned* o = reinterpret_cast<unsigned*>(accb + (size_t)d * 1024);
    o[t]       = pack2(a00, a01);
    o[t + 128] = pack2(a10, a11);
    o[t + 256] = pack2(a20, a21);
    o[t + 384] = pack2(a30, a31);
}

// ==== blocks 2/3: gather-aggregate + fused elu/residual epilogue ================
// NOTE: outb must NOT alias g (gather source) — blocks read arbitrary g rows.
template<int H, int C, int F>
__global__ void aggr_comb_kernel(const int* __restrict__ row_ptr,
                                 const int* __restrict__ deg,
                                 const int* __restrict__ csr_src,
                                 const float* __restrict__ alpha,
                                 const ushort* __restrict__ g,
                                 const float* __restrict__ Rf,
                                 const float* __restrict__ gb,
                                 const float* __restrict__ rb,
                                 ushort* __restrict__ outb) {
    int d = blockIdx.x;
    int t = threadIdx.x;               // 0..F/2-1
    int hd = (2 * t) / C;
    int base = row_ptr[d], dg = deg[d];
    float lo = 0.f, hi = 0.f;
    for (int j = 0; j < dg; j++) {
        int s = csr_src[base + j];
        float a = alpha[(size_t)(base + j) * H + hd];
        unsigned v = reinterpret_cast<const unsigned*>(g + (size_t)s * F)[t];
        lo += a * b2f((ushort)(v & 0xffff));
        hi += a * b2f((ushort)(v >> 16));
    }
    int c0 = 2 * t, c1 = 2 * t + 1;
    float o0 = lo + gb[c0]; o0 = o0 > 0.f ? o0 : (__expf(o0) - 1.f);
    float o1 = hi + gb[c1]; o1 = o1 > 0.f ? o1 : (__expf(o1) - 1.f);
    o0 += Rf[(size_t)d * F + c0] + rb[c0];
    o1 += Rf[(size_t)d * F + c1] + rb[c1];
    reinterpret_cast<unsigned*>(outb)[(size_t)d * (F / 2) + t] = pack2(o0, o1);
}

// ---------------- final tiny GEMM: out[M,2] = A[M,64](bf16) @ W[64,2] + b --------
__global__ __launch_bounds__(256) void mlp2_kernel(const ushort* __restrict__ A,
                                                   const float* __restrict__ W,
                                                   const float* __restrict__ b,
                                                   float* __restrict__ out, int M) {
    __shared__ float w[128];
    __shared__ float bb[2];
    int tid = threadIdx.x;
    if (tid < 128) w[tid] = W[tid];
    if (tid < 2) bb[tid] = b[tid];
    __syncthreads();
    int row = blockIdx.x * 256 + tid;
    if (row >= M) return;
    float a0 = bb[0], a1 = bb[1];
    const ushort* ap = A + (size_t)row * 64;
    #pragma unroll 8
    for (int k = 0; k < 64; k++) {
        float av = b2f(ap[k]);
        a0 += av * w[2 * k];
        a1 += av * w[2 * k + 1];
    }
    out[(size_t)row * 2] = a0;
    out[(size_t)row * 2 + 1] = a1;
}

extern "C" void kernel_launch(void* const* d_in, const int* in_sizes, int n_in,
                              void* d_out, int out_size, void* d_ws, size_t ws_size,
                              hipStream_t stream) {
    const float* x        = (const float*)d_in[0];
    const int*   ei       = (const int*)d_in[1];
    const float* enc_w1   = (const float*)d_in[2];
    const float* enc_b1   = (const float*)d_in[3];
    const float* ln1_g    = (const float*)d_in[4];
    const float* ln1_b    = (const float*)d_in[5];
    const float* enc_w2   = (const float*)d_in[6];
    const float* enc_b2   = (const float*)d_in[7];
    const float* ln2_g    = (const float*)d_in[8];
    const float* ln2_b    = (const float*)d_in[9];
    const float* w1       = (const float*)d_in[10];
    const float* att_src1 = (const float*)d_in[11];
    const float* att_dst1 = (const float*)d_in[12];
    const float* bias1    = (const float*)d_in[13];
    const float* res1_w   = (const float*)d_in[14];
    const float* res1_b   = (const float*)d_in[15];
    const float* w2       = (const float*)d_in[16];
    const float* att_src2 = (const float*)d_in[17];
    const float* att_dst2 = (const float*)d_in[18];
    const float* bias2    = (const float*)d_in[19];
    const float* res2_w   = (const float*)d_in[20];
    const float* res2_b   = (const float*)d_in[21];
    const float* w3       = (const float*)d_in[22];
    const float* att_src3 = (const float*)d_in[23];
    const float* att_dst3 = (const float*)d_in[24];
    const float* bias3    = (const float*)d_in[25];
    const float* res3_w   = (const float*)d_in[26];
    const float* res3_b   = (const float*)d_in[27];
    const float* mlp_w1   = (const float*)d_in[28];
    const float* mlp_b1   = (const float*)d_in[29];
    const float* mlp_w2   = (const float*)d_in[30];
    const float* mlp_b2   = (const float*)d_in[31];

    const int N  = in_sizes[0] / 405;   // 50000
    const int E  = in_sizes[1] / 2;     // 300000
    const int Et = E + N;
    const int NB = (N + 255) / 256;

    // ---------- workspace layout (bytes) ----------
    char* p = (char*)d_ws;
    char* R0 = p;                       // N*896 B : xb(448 b16) | H3b(b16 192) | M1b
    char* R1 = R0 + (size_t)N * 896;    // N*512 B : h0b | G2b
    char* R2 = R1 + (size_t)N * 512;    // N*512 B : h1b | G3b , H4b(@+N*256B)
    char* R3 = R2 + (size_t)N * 512;    // N*2048 B: F1(f32 256) | H2b(b16 1024)
    char* R4 = R3 + (size_t)N * 2048;   // N*2048 B: accb(b16 1024) | Rf(f32 192/128)
    char* T  = R4 + (size_t)N * 2048;   // tail

    ushort* xb   = (ushort*)R0;
    ushort* H3b  = (ushort*)R0;          // lives after xb is dead (enc1 done)
    ushort* M1b  = (ushort*)R0;          // lives after H3b is dead (block-3 GEMM done)
    ushort* h0b  = (ushort*)R1;
    ushort* G2b  = (ushort*)R1;
    ushort* h1b  = (ushort*)R2;
    ushort* G3b  = (ushort*)R2;
    ushort* H4b  = (ushort*)(R2 + (size_t)N * 256);
    float*  F1   = (float*)R3;
    ushort* H2b  = (ushort*)R3;
    ushort* accb = (ushort*)R4;
    float*  Rf   = (float*)R4;

    float* a_s   = (float*)T;                         T += (size_t)N * 4 * 4;   // also Sf2/Sf3
    float* a_d   = (float*)T;                         T += (size_t)N * 4 * 4;
    float* alpha = (float*)T;                         T += (size_t)Et * 4 * 4;
    float* qs    = (float*)T;                         T += 2048 * 4;
    float* qd    = (float*)T;                         T += 2048 * 4;
    int* deg     = (int*)T;                           T += (size_t)N * 4;
    int* cur     = (int*)T;                           T += (size_t)N * 4;
    int* row_ptr = (int*)T;                           T += (size_t)N * 4;
    int* incl    = (int*)T;                           T += (size_t)N * 4;
    int* part    = (int*)T;                           T += 256 * 4;
    int* csr_src = (int*)T;                           T += (size_t)Et * 4;
    ushort* enc_w1T = (ushort*)T;                     T += (size_t)256 * 448 * 2;
    ushort* enc_w2T = (ushort*)T;                     T += (size_t)256 * 256 * 2;
    ushort* w1T     = (ushort*)T;                     T += (size_t)1024 * 256 * 2;
    ushort* res1T   = (ushort*)T;                     T += (size_t)1024 * 256 * 2;
    ushort* Bcat2T  = (ushort*)T;                     T += (size_t)512 * 1024 * 2;
    ushort* Bcat3T  = (ushort*)T;                     T += (size_t)384 * 192 * 2;
    ushort* mlpw1T  = (ushort*)T;                     T += (size_t)128 * 128 * 2;

    auto cdiv = [](int a, int b) { return (a + b - 1) / b; };
    const int MB = cdiv(N, 128);

    // ---- CSR build ----
    hipMemsetAsync(deg, 0, (size_t)N * 8, stream);   // deg + cur
    deg_kernel<<<cdiv(Et, 256), 256, 0, stream>>>(ei, deg, E, Et);
    scan1_kernel<<<NB, 256, 0, stream>>>(deg, incl, part, N);
    scan2_kernel<<<1, 256, 0, stream>>>(part, NB);
    scan3_kernel<<<NB, 256, 0, stream>>>(incl, deg, part, row_ptr, N);
    fill_kernel<<<cdiv(Et, 256), 256, 0, stream>>>(ei, row_ptr, cur, csr_src, E, Et);

    // ---- weight prep (bf16, transposed, padded) ----
    prep_bt_kernel<<<cdiv(256 * 448, 256), 256, 0, stream>>>(enc_w1, enc_w1T, 405, 256, 448, 256, 256, 0);
    prep_bt_kernel<<<cdiv(256 * 256, 256), 256, 0, stream>>>(enc_w2, enc_w2T, 256, 256, 256, 256, 256, 0);
    prep_bt_kernel<<<cdiv(1024 * 256, 256), 256, 0, stream>>>(w1, w1T, 256, 1024, 256, 1024, 1024, 0);
    prep_bt_kernel<<<cdiv(1024 * 256, 256), 256, 0, stream>>>(res1_w, res1T, 256, 1024, 256, 1024, 1024, 0);
    prep_bt_kernel<<<cdiv(192 * 1024, 256), 256, 0, stream>>>(w2, Bcat2T, 1024, 192, 1024, 192, 192, 0);
    prep_bt_kernel<<<cdiv(192 * 1024, 256), 256, 0, stream>>>(res2_w, Bcat2T + (size_t)192 * 1024, 1024, 192, 1024, 192, 192, 0);
    prep_bt_kernel<<<cdiv(124 * 1024, 256), 256, 0, stream>>>(w2, Bcat2T + (size_t)388 * 1024, 0, 0, 1024, 124, 192, 0);
    prep_bt_kernel<<<cdiv(128 * 192, 256), 256, 0, stream>>>(w3, Bcat3T, 192, 128, 192, 128, 128, 0);
    prep_bt_kernel<<<cdiv(128 * 192, 256), 256, 0, stream>>>(res3_w, Bcat3T + (size_t)128 * 192, 192, 128, 192, 128, 128, 0);
    prep_bt_kernel<<<cdiv(126 * 192, 256), 256, 0, stream>>>(w3, Bcat3T + (size_t)258 * 192, 0, 0, 192, 126, 128, 0);
    prep_bt_kernel<<<cdiv(128 * 128, 256), 256, 0, stream>>>(mlp_w1, mlpw1T, 128, 64, 128, 128, 64, 0);

    // ---- JointEncoder ----
    conv_pad_x_kernel<<<cdiv(N * 448, 256), 256, 0, stream>>>(x, xb, N);
    bgemm<0><<<dim3(2, MB), 256, 0, stream>>>(xb, enc_w1T, enc_b1, F1, 256, nullptr, nullptr, 0, N, 256, 448, 448);
    ln_relu_kernel<<<N, 256, 0, stream>>>(F1, ln1_g, ln1_b, h0b);
    bgemm<0><<<dim3(2, MB), 256, 0, stream>>>(h0b, enc_w2T, enc_b2, F1, 256, nullptr, nullptr, 0, N, 256, 256, 256);
    ln_relu_kernel<<<N, 256, 0, stream>>>(F1, ln2_g, ln2_b, h1b);

    // ---- Block 1: GAT 256 -> 4x256 concat (fused head GEMMs + residual) ----
    {
        fold_att_kernel<<<cdiv(4 * 256, 256), 256, 0, stream>>>(w1, att_src1, att_dst1, qs, qd, 256, 256, 4);
        att_scores4_kernel<<<N, 64, 0, stream>>>(h1b, qs, qd, a_s, a_d);
        stats_kernel<4><<<N, 64, 0, stream>>>(row_ptr, deg, csr_src, a_s, 4, a_d, 4, alpha);
        aggr_b1_all_kernel<<<N, 128, 0, stream>>>(row_ptr, deg, csr_src, alpha, h1b, accb);
        bgemm_b1<<<dim3(8, MB), 256, 0, stream>>>(accb, w1T, h1b, res1T, bias1, res1_b, H2b, N);
    }

    // ---- Block 2: GAT 1024 -> 2x96 concat (G/R/scores in one split-epilogue GEMM) --
    {
        fold_att_kernel<<<cdiv(2 * 1024, 256), 256, 0, stream>>>(w2, att_src2, att_dst2, qs, qd, 1024, 96, 2);
        conv_bf16_kernel<<<cdiv(2048, 256), 256, 0, stream>>>(qs, Bcat2T + (size_t)384 * 1024, 2048);
        conv_bf16_kernel<<<cdiv(2048, 256), 256, 0, stream>>>(qd, Bcat2T + (size_t)386 * 1024, 2048);
        // cols: [0,192)=G2b bf16, [192,384)=Rf fp32, [384,388)=scores -> a_s[N,4]
        bgemm<5><<<dim3(4, MB), 256, 0, stream>>>(H2b, Bcat2T, nullptr, G2b, 0, Rf, a_s, 192, N, 388, 1024, 1024);
        stats_kernel<2><<<N, 64, 0, stream>>>(row_ptr, deg, csr_src, a_s, 4, a_s + 2, 4, alpha);
        // H3b (R0) does NOT alias G2b (R1) -> fused gather+epilogue is safe
        aggr_comb_kernel<2, 96, 192><<<N, 96, 0, stream>>>(row_ptr, deg, csr_src, alpha, G2b,
                                                           Rf, bias2, res2_b, H3b);
    }

    // ---- Block 3: GAT 192 -> 1x128 (no concat) ----
    {
        fold_att_kernel<<<cdiv(192, 192), 192, 0, stream>>>(w3, att_src3, att_dst3, qs, qd, 192, 128, 1);
        conv_bf16_kernel<<<1, 256, 0, stream>>>(qs, Bcat3T + (size_t)256 * 192, 192);
        conv_bf16_kernel<<<1, 256, 0, stream>>>(qd, Bcat3T + (size_t)257 * 192, 192);
        // cols: [0,128)=G3b bf16, [128,256)=Rf fp32, [256,258)=scores -> a_s[N,2]
        bgemm<5><<<dim3(3, MB), 256, 0, stream>>>(H3b, Bcat3T, nullptr, G3b, 0, Rf, a_s, 128, N, 258, 192, 192);
        stats_kernel<1><<<N, 64, 0, stream>>>(row_ptr, deg, csr_src, a_s, 2, a_s + 1, 2, alpha);
        // H4b (R2 + N*256B) does NOT alias G3b (R2, N*256B) -> safe
        aggr_comb_kernel<1, 128, 128><<<N, 64, 0, stream>>>(row_ptr, deg, csr_src, alpha, G3b,
                                                            Rf, bias3, res3_b, H4b);
    }

    // ---- MLP head ----
    bgemm<3><<<dim3(1, MB), 256, 0, stream>>>(H4b, mlpw1T, mlp_b1, M1b, 64, nullptr, nullptr, 0, N, 64, 128, 128);
    mlp2_kernel<<<cdiv(N, 256), 256, 0, stream>>>(M1b, mlp_w2, mlp_b2, (float*)d_out, N);
}

// Round 10
// 894.847 us; speedup vs baseline: 10.9638x; 1.0636x over previous
//
#include <hip/hip_runtime.h>
#include <cstddef>

#define LN_EPS 1e-5f

typedef __bf16 bf16x8 __attribute__((ext_vector_type(8)));
typedef float  f32x4  __attribute__((ext_vector_type(4)));

typedef __attribute__((address_space(3))) unsigned int lds_u32;
typedef __attribute__((address_space(1))) unsigned int glb_u32;

__device__ __forceinline__ void gl2lds16(const void* g, void* l) {
    // 16B per lane DMA: LDS dest = wave-uniform base + lane*16
    __builtin_amdgcn_global_load_lds((const glb_u32*)g, (lds_u32*)l, 16, 0, 0);
}

__device__ __forceinline__ float b2f(ushort h) {
    return __uint_as_float(((unsigned)h) << 16);
}
__device__ __forceinline__ ushort f2b(float f) {   // RNE
    unsigned u = __float_as_uint(f);
    return (ushort)((u + 0x7fffu + ((u >> 16) & 1u)) >> 16);
}
__device__ __forceinline__ unsigned pack2(float lo, float hi) {
    return (unsigned)f2b(lo) | ((unsigned)f2b(hi) << 16);
}
__device__ __forceinline__ uint2 pack4(const f32x4 v) {
    return make_uint2(pack2(v[0], v[1]), pack2(v[2], v[3]));
}

// XCD-aware remap: all gridDim.x col-blocks of one row-block land on one XCD.
__device__ __forceinline__ void xcd_map(int& bx, int& by) {
    int NX = gridDim.x, MBr = gridDim.y;
    int L = blockIdx.y * NX + blockIdx.x;
    int G = NX * 8;
    int g = L / G;
    if (g * 8 + 8 <= MBr) {
        int r = L - g * G;
        by = g * 8 + (r & 7);
        bx = r >> 3;
    } else {
        by = L / NX;
        bx = L - by * NX;
    }
}

__device__ __forceinline__ float wave_reduce_sum(float v) {
    #pragma unroll
    for (int off = 32; off > 0; off >>= 1) v += __shfl_down(v, off, 64);
    return v;
}
__device__ __forceinline__ float wave_allreduce_max(float v) {
    #pragma unroll
    for (int off = 32; off > 0; off >>= 1) v = fmaxf(v, __shfl_xor(v, off, 64));
    return v;
}
__device__ __forceinline__ float wave_allreduce_sum(float v) {
    #pragma unroll
    for (int off = 32; off > 0; off >>= 1) v += __shfl_xor(v, off, 64);
    return v;
}

// ---- BK=32 double-buffered MFMA K-loop, XOR-swizzled (2-way max aliasing) -------
// SWAPPED operands: acc[i][j] = mfma(bf[j], af[i], acc) so that
//   C row = m0+wr+i*16+l15 ; C col = n0+wc+j*16+quad*4+reg  (4 consecutive cols/reg)
__device__ __forceinline__ void stage32(const ushort* a0, const ushort* a1,
                                        const ushort* b0, const ushort* b1,
                                        ushort* __restrict__ As, ushort* __restrict__ Bs,
                                        int lb0, int lb1) {
    gl2lds16(a0, As + lb0);
    gl2lds16(a1, As + lb1);
    gl2lds16(b0, Bs + lb0);
    gl2lds16(b1, Bs + lb1);
}

__device__ __forceinline__ void mfma_loop32(const ushort* aA0, const ushort* aA1,
                                            const ushort* aB0, const ushort* aB1,
                                            ushort* __restrict__ As0, ushort* __restrict__ As1,
                                            ushort* __restrict__ Bs0, ushort* __restrict__ Bs1,
                                            int lb0, int lb1,
                                            int K, int wr, int wc, int cA, int l15,
                                            f32x4 acc[4][4]) {
    stage32(aA0, aA1, aB0, aB1, As0, Bs0, lb0, lb1);   // prime buffer 0
    int p = 0;
    for (int k0 = 0; k0 < K; k0 += 32) {
        __syncthreads();                               // drains current buffer's DMA
        const ushort* Ac = p ? As1 : As0;
        const ushort* Bc = p ? Bs1 : Bs0;
        ushort* Ad = p ? As0 : As1;
        ushort* Bd = p ? Bs0 : Bs1;
        int kn = k0 + 32;
        if (kn < K) stage32(aA0 + kn, aA1 + kn, aB0 + kn, aB1 + kn, Ad, Bd, lb0, lb1);
        bf16x8 af[4], bf[4];
        #pragma unroll
        for (int i = 0; i < 4; i++)
            af[i] = *reinterpret_cast<const bf16x8*>(&Ac[(wr + i * 16 + l15) * 32 + cA]);
        #pragma unroll
        for (int j = 0; j < 4; j++)
            bf[j] = *reinterpret_cast<const bf16x8*>(&Bc[(wc + j * 16 + l15) * 32 + cA]);
        #pragma unroll
        for (int i = 0; i < 4; i++)
            #pragma unroll
            for (int j = 0; j < 4; j++)
                acc[i][j] = __builtin_amdgcn_mfma_f32_16x16x32_bf16(bf[j], af[i], acc[i][j], 0, 0, 0);
        p ^= 1;
    }
    __syncthreads();   // protect LDS reuse (phase 2 / epilogue)
}

// ============== bf16 MFMA GEMM: C = A[M,K]@B  (B given as BT[Npad,K] bf16) =======
// EPI 0: fp32 out = acc (+bias if non-null)        (full-col grids only)
// EPI 3: bf16 out = relu(acc + bias)               (col-group bounds vs Ncols)
// EPI 5: split: col<Fs -> bf16 out; col<2Fs -> fp32 Rf; else fp32 Sf (elem guard).
template<int EPI>
__global__ __launch_bounds__(256) void bgemm(const ushort* __restrict__ A,
                                             const ushort* __restrict__ BT,
                                             const float* __restrict__ bias,
                                             void* __restrict__ out, int ldc,
                                             float* __restrict__ Rf,
                                             float* __restrict__ Sf, int Fs,
                                             int M, int Ncols, int K, int lda) {
    __shared__ ushort As[2][128 * 32];
    __shared__ ushort Bs[2][128 * 32];
    const int tid = threadIdx.x;
    int bx, by; xcd_map(bx, by);
    const int m0 = by * 128, n0 = bx * 128;
    const int w = tid >> 6, lane = tid & 63;
    const int wr = (w >> 1) * 64, wc = (w & 1) * 64;
    const int quad = lane >> 4, l15 = lane & 15;
    const int cA = (quad ^ ((l15 >> 1) & 3)) * 8;
    const int lb0 = w * 512, lb1 = lb0 + 2048;

    const int s0 = tid, s1 = tid + 256;
    const int r0 = s0 >> 2, g0 = ((s0 & 3) ^ ((s0 >> 3) & 3)) * 8;
    const int r1 = s1 >> 2, g1 = ((s1 & 3) ^ ((s1 >> 3) & 3)) * 8;
    int ga0 = m0 + r0; if (ga0 >= M) ga0 = M - 1;
    int ga1 = m0 + r1; if (ga1 >= M) ga1 = M - 1;
    const ushort* aA0 = A + (size_t)ga0 * lda + g0;
    const ushort* aA1 = A + (size_t)ga1 * lda + g1;
    const ushort* aB0 = BT + (size_t)(n0 + r0) * K + g0;
    const ushort* aB1 = BT + (size_t)(n0 + r1) * K + g1;

    f32x4 acc[4][4] = {};
    mfma_loop32(aA0, aA1, aB0, aB1, As[0], As[1], Bs[0], Bs[1], lb0, lb1,
                K, wr, wc, cA, l15, acc);

    const int twoH = Ncols - 2 * Fs;
    #pragma unroll
    for (int i = 0; i < 4; i++) {
        int row = m0 + wr + i * 16 + l15;
        if (row >= M) continue;
        #pragma unroll
        for (int j = 0; j < 4; j++) {
            int colbase = n0 + wc + j * 16 + quad * 4;
            if (EPI == 0) {
                f32x4 v = acc[i][j];
                if (bias) {
                    float4 bv = *reinterpret_cast<const float4*>(&bias[colbase]);
                    v[0] += bv.x; v[1] += bv.y; v[2] += bv.z; v[3] += bv.w;
                }
                *reinterpret_cast<f32x4*>(&((float*)out)[(size_t)row * ldc + colbase]) = v;
            } else if (EPI == 3) {
                if (colbase >= Ncols) continue;
                float4 bv = *reinterpret_cast<const float4*>(&bias[colbase]);
                f32x4 v = acc[i][j];
                v[0] = fmaxf(v[0] + bv.x, 0.f); v[1] = fmaxf(v[1] + bv.y, 0.f);
                v[2] = fmaxf(v[2] + bv.z, 0.f); v[3] = fmaxf(v[3] + bv.w, 0.f);
                *reinterpret_cast<uint2*>(&((ushort*)out)[(size_t)row * ldc + colbase]) = pack4(v);
            } else {
                if (colbase + 3 < Fs) {
                    *reinterpret_cast<uint2*>(&((ushort*)out)[(size_t)row * Fs + colbase]) = pack4(acc[i][j]);
                } else if (colbase >= Fs && colbase + 3 < 2 * Fs) {
                    *reinterpret_cast<f32x4*>(&Rf[(size_t)row * Fs + (colbase - Fs)]) = acc[i][j];
                } else {
                    #pragma unroll
                    for (int r = 0; r < 4; r++) {
                        int col = colbase + r;
                        if (col < 2 * Fs || col >= Ncols) continue;
                        Sf[(size_t)row * twoH + (col - 2 * Fs)] = acc[i][j][r];
                    }
                }
            }
        }
    }
}

// ===== fused block-1: H2 = elu(acc_h@W_h + bias1) + h1@res1_w + res1_b (bf16) ====
__global__ __launch_bounds__(256) void bgemm_b1(const ushort* __restrict__ accb,  // N x 1024
                                                const ushort* __restrict__ w1T,   // 1024 x 256
                                                const ushort* __restrict__ h1b,   // N x 256
                                                const ushort* __restrict__ res1T, // 1024 x 256
                                                const float* __restrict__ bias1,
                                                const float* __restrict__ res1b,
                                                ushort* __restrict__ H2b, int M) {
    __shared__ ushort As[2][128 * 32];
    __shared__ ushort Bs[2][128 * 32];
    const int tid = threadIdx.x;
    int bx, by; xcd_map(bx, by);
    const int m0 = by * 128, n0 = bx * 128;
    const int h = n0 >> 8;
    const int w = tid >> 6, lane = tid & 63;
    const int wr = (w >> 1) * 64, wc = (w & 1) * 64;
    const int quad = lane >> 4, l15 = lane & 15;
    const int cA = (quad ^ ((l15 >> 1) & 3)) * 8;
    const int lb0 = w * 512, lb1 = lb0 + 2048;

    const int s0 = tid, s1 = tid + 256;
    const int r0 = s0 >> 2, g0 = ((s0 & 3) ^ ((s0 >> 3) & 3)) * 8;
    const int r1 = s1 >> 2, g1 = ((s1 & 3) ^ ((s1 >> 3) & 3)) * 8;
    int ga0 = m0 + r0; if (ga0 >= M) ga0 = M - 1;
    int ga1 = m0 + r1; if (ga1 >= M) ga1 = M - 1;

    f32x4 acc[4][4] = {};

    // phase 1: acc_h @ W_h
    mfma_loop32(accb + (size_t)ga0 * 1024 + h * 256 + g0,
                accb + (size_t)ga1 * 1024 + h * 256 + g1,
                w1T + (size_t)(n0 + r0) * 256 + g0,
                w1T + (size_t)(n0 + r1) * 256 + g1,
                As[0], As[1], Bs[0], Bs[1], lb0, lb1, 256, wr, wc, cA, l15, acc);

    // in-register: acc = elu(acc + bias1) + res1_b
    #pragma unroll
    for (int i = 0; i < 4; i++) {
        #pragma unroll
        for (int j = 0; j < 4; j++) {
            int colbase = n0 + wc + j * 16 + quad * 4;
            float4 bv = *reinterpret_cast<const float4*>(&bias1[colbase]);
            float4 rv = *reinterpret_cast<const float4*>(&res1b[colbase]);
            float bb[4] = { bv.x, bv.y, bv.z, bv.w };
            float rr[4] = { rv.x, rv.y, rv.z, rv.w };
            #pragma unroll
            for (int r = 0; r < 4; r++) {
                float t = acc[i][j][r] + bb[r];
                t = t > 0.f ? t : (__expf(t) - 1.f);
                acc[i][j][r] = t + rr[r];
            }
        }
    }

    // phase 2: += h1 @ res1_w
    mfma_loop32(h1b + (size_t)ga0 * 256 + g0,
                h1b + (size_t)ga1 * 256 + g1,
                res1T + (size_t)(n0 + r0) * 256 + g0,
                res1T + (size_t)(n0 + r1) * 256 + g1,
                As[0], As[1], Bs[0], Bs[1], lb0, lb1, 256, wr, wc, cA, l15, acc);

    #pragma unroll
    for (int i = 0; i < 4; i++) {
        int row = m0 + wr + i * 16 + l15;
        if (row >= M) continue;
        #pragma unroll
        for (int j = 0; j < 4; j++) {
            int colbase = n0 + wc + j * 16 + quad * 4;
            *reinterpret_cast<uint2*>(&H2b[(size_t)row * 1024 + colbase]) = pack4(acc[i][j]);
        }
    }
}

// ---------------- conversions / weight prep ----------------
__global__ void conv_pad_x_kernel(const float* __restrict__ x, ushort* __restrict__ xb, int N) {
    int t = blockIdx.x * 256 + threadIdx.x;
    if (t >= N * 448) return;
    int n = t / 448, k = t - n * 448;
    xb[t] = f2b(k < 405 ? x[(size_t)n * 405 + k] : 0.f);
}

// ---- ALL weight preps in ONE launch (bf16 transpose+pad, segment table) ----
__device__ __forceinline__ void prep_seg(int t, const float* src, ushort* dst,
                                         int K, int Nreal, int Kpad, int ldsrc) {
    int n = t / Kpad, k = t - n * Kpad;
    float v = (k < K && n < Nreal) ? src[(size_t)k * ldsrc + n] : 0.f;
    dst[t] = f2b(v);
}

__global__ void prep_all_kernel(const float* __restrict__ enc_w1, const float* __restrict__ enc_w2,
                                const float* __restrict__ w1, const float* __restrict__ res1_w,
                                const float* __restrict__ w2, const float* __restrict__ res2_w,
                                const float* __restrict__ w3, const float* __restrict__ res3_w,
                                const float* __restrict__ mlp_w1,
                                ushort* __restrict__ enc_w1T, ushort* __restrict__ enc_w2T,
                                ushort* __restrict__ w1T, ushort* __restrict__ res1T,
                                ushort* __restrict__ Bcat2T, ushort* __restrict__ Bcat3T,
                                ushort* __restrict__ mlpw1T) {
    int t = blockIdx.x * 256 + threadIdx.x;
    // cumulative boundaries
    const int c0 = 114688;            // enc_w1T 256x448
    const int c1 = c0 + 65536;        // enc_w2T 256x256
    const int c2 = c1 + 262144;       // w1T 1024x256
    const int c3 = c2 + 262144;       // res1T 1024x256
    const int c4 = c3 + 196608;       // Bcat2T rows 0-191 (w2)
    const int c5 = c4 + 196608;       // Bcat2T rows 192-383 (res2)
    const int c6 = c5 + 126976;       // Bcat2T rows 388-511 zero
    const int c7 = c6 + 24576;        // Bcat3T rows 0-127 (w3)
    const int c8 = c7 + 24576;        // Bcat3T rows 128-255 (res3)
    const int c9 = c8 + 24192;        // Bcat3T rows 258-383 zero
    const int c10 = c9 + 16384;       // mlpw1T 128x128
    if (t < c0)      prep_seg(t,        enc_w1, enc_w1T, 405, 256, 448, 256);
    else if (t < c1) prep_seg(t - c0,   enc_w2, enc_w2T, 256, 256, 256, 256);
    else if (t < c2) prep_seg(t - c1,   w1,     w1T,     256, 1024, 256, 1024);
    else if (t < c3) prep_seg(t - c2,   res1_w, res1T,   256, 1024, 256, 1024);
    else if (t < c4) prep_seg(t - c3,   w2,     Bcat2T,  1024, 192, 1024, 192);
    else if (t < c5) prep_seg(t - c4,   res2_w, Bcat2T + (size_t)192 * 1024, 1024, 192, 1024, 192);
    else if (t < c6) Bcat2T[(size_t)388 * 1024 + (t - c5)] = 0;
    else if (t < c7) prep_seg(t - c6,   w3,     Bcat3T,  192, 128, 192, 128);
    else if (t < c8) prep_seg(t - c7,   res3_w, Bcat3T + (size_t)128 * 192, 192, 128, 192, 128);
    else if (t < c9) Bcat3T[(size_t)258 * 192 + (t - c8)] = 0;
    else if (t < c10) prep_seg(t - c9,  mlp_w1, mlpw1T,  128, 64, 128, 64);
}

// ---------------- LayerNorm(+ReLU): fp32 in, bf16 out; C == 256 ----------------
__global__ __launch_bounds__(256) void ln_relu_kernel(const float* __restrict__ x,
                                                      const float* __restrict__ g,
                                                      const float* __restrict__ b,
                                                      ushort* __restrict__ out) {
    const int C = 256;
    int row = blockIdx.x;
    int tid = threadIdx.x;
    int lane = tid & 63, wid = tid >> 6;
    __shared__ float red[4];
    float v = x[(size_t)row * C + tid];
    float s = wave_reduce_sum(v);
    if (lane == 0) red[wid] = s;
    __syncthreads();
    float m = (red[0] + red[1] + red[2] + red[3]) * (1.f / C);
    __syncthreads();
    float d = v - m;
    float s2 = wave_reduce_sum(d * d);
    if (lane == 0) red[wid] = s2;
    __syncthreads();
    float var = (red[0] + red[1] + red[2] + red[3]) * (1.f / C);
    float rs = rsqrtf(var + LN_EPS);
    float o = d * rs * g[tid] + b[tid];
    out[(size_t)row * C + tid] = f2b(fmaxf(o, 0.f));
}

// ---- fold attention vectors through W (fp32 out, block1) ----
__global__ void fold_att_kernel(const float* __restrict__ W,
                                const float* __restrict__ att_s,
                                const float* __restrict__ att_d,
                                float* __restrict__ qs, float* __restrict__ qd,
                                int Cin, int Cout, int H) {
    int t = blockIdx.x * blockDim.x + threadIdx.x;
    if (t >= H * Cin) return;
    int h = t / Cin, k = t - h * Cin;
    const float* wrow = W + (size_t)k * (H * Cout) + (size_t)h * Cout;
    const float* as = att_s + (size_t)h * Cout;
    const float* ad = att_d + (size_t)h * Cout;
    float ss = 0.f, sd = 0.f;
    for (int c = 0; c < Cout; c++) { float wv = wrow[c]; ss += wv * as[c]; sd += wv * ad[c]; }
    qs[t] = ss;
    qd[t] = sd;
}

// ---- fold attention vectors through W, bf16 out (blocks 2/3 -> Bcat rows) ----
__global__ void fold_att_b16_kernel(const float* __restrict__ W,
                                    const float* __restrict__ att_s,
                                    const float* __restrict__ att_d,
                                    ushort* __restrict__ qs_b, ushort* __restrict__ qd_b,
                                    int Cin, int Cout, int H) {
    int t = blockIdx.x * blockDim.x + threadIdx.x;
    if (t >= H * Cin) return;
    int h = t / Cin, k = t - h * Cin;
    const float* wrow = W + (size_t)k * (H * Cout) + (size_t)h * Cout;
    const float* as = att_s + (size_t)h * Cout;
    const float* ad = att_d + (size_t)h * Cout;
    float ss = 0.f, sd = 0.f;
    for (int c = 0; c < Cout; c++) { float wv = wrow[c]; ss += wv * as[c]; sd += wv * ad[c]; }
    qs_b[t] = f2b(ss);
    qd_b[t] = f2b(sd);
}

// ---- block1 scores, ALL 4 heads per wave (reads h1 row once) ----
__global__ __launch_bounds__(64) void att_scores4_kernel(const ushort* __restrict__ x,
                                                         const float* __restrict__ qs,
                                                         const float* __restrict__ qd,
                                                         float* __restrict__ a_s,
                                                         float* __restrict__ a_d) {
    int n = blockIdx.x;
    int lane = threadIdx.x;
    const ushort* xp = x + (size_t)n * 256 + lane * 4;
    uint2 xv = *reinterpret_cast<const uint2*>(xp);
    float v[4] = { b2f((ushort)(xv.x & 0xffff)), b2f((ushort)(xv.x >> 16)),
                   b2f((ushort)(xv.y & 0xffff)), b2f((ushort)(xv.y >> 16)) };
    float rs[4], rd[4];
    #pragma unroll
    for (int h = 0; h < 4; h++) {
        const float* qsp = qs + h * 256 + lane * 4;
        const float* qdp = qd + h * 256 + lane * 4;
        float ss = 0.f, sd = 0.f;
        #pragma unroll
        for (int k = 0; k < 4; k++) { ss += v[k] * qsp[k]; sd += v[k] * qdp[k]; }
        rs[h] = wave_reduce_sum(ss);
        rd[h] = wave_reduce_sum(sd);
    }
    if (lane == 0) {
        *reinterpret_cast<float4*>(&a_s[(size_t)n * 4]) = make_float4(rs[0], rs[1], rs[2], rs[3]);
        *reinterpret_cast<float4*>(&a_d[(size_t)n * 4]) = make_float4(rd[0], rd[1], rd[2], rd[3]);
    }
}

// ================= CSR construction (dst-grouped) =========
__device__ __forceinline__ void edge_sd(const int* ei, int e, int E, int& s, int& d) {
    if (e < E) { s = ei[e]; d = ei[E + e]; } else { s = d = e - E; }
}

__global__ void deg_kernel(const int* __restrict__ ei, int* __restrict__ deg, int E, int Et) {
    int e = blockIdx.x * blockDim.x + threadIdx.x;
    if (e >= Et) return;
    int s, d; edge_sd(ei, e, E, s, d);
    atomicAdd(&deg[d], 1);
}

__global__ __launch_bounds__(256) void scan1_kernel(const int* __restrict__ deg,
                                                    int* __restrict__ incl,
                                                    int* __restrict__ part, int N) {
    __shared__ int sd[256];
    int t = threadIdx.x;
    int i = blockIdx.x * 256 + t;
    int v = (i < N) ? deg[i] : 0;
    sd[t] = v; __syncthreads();
    #pragma unroll
    for (int o = 1; o < 256; o <<= 1) {
        int x = (t >= o) ? sd[t - o] : 0;
        __syncthreads();
        sd[t] += x;
        __syncthreads();
    }
    if (i < N) incl[i] = sd[t];
    if (t == 255) part[blockIdx.x] = sd[255];
}

__global__ __launch_bounds__(256) void scan2_kernel(int* __restrict__ part, int nb) {
    __shared__ int sd[256];
    int t = threadIdx.x;
    int v = (t < nb) ? part[t] : 0;
    sd[t] = v; __syncthreads();
    #pragma unroll
    for (int o = 1; o < 256; o <<= 1) {
        int x = (t >= o) ? sd[t - o] : 0;
        __syncthreads();
        sd[t] += x;
        __syncthreads();
    }
    if (t < nb) part[t] = sd[t];
}

__global__ void scan3_kernel(const int* __restrict__ incl, const int* __restrict__ deg,
                             const int* __restrict__ part, int* __restrict__ row_ptr, int N) {
    int i = blockIdx.x * blockDim.x + threadIdx.x;
    if (i >= N) return;
    int off = (blockIdx.x > 0) ? part[blockIdx.x - 1] : 0;
    row_ptr[i] = incl[i] - deg[i] + off;
}

__global__ void fill_kernel(const int* __restrict__ ei, const int* __restrict__ row_ptr,
                            int* __restrict__ cur, int* __restrict__ csr_src, int E, int Et) {
    int e = blockIdx.x * blockDim.x + threadIdx.x;
    if (e >= Et) return;
    int s, d; edge_sd(ei, e, E, s, d);
    int pos = row_ptr[d] + atomicAdd(&cur[d], 1);
    csr_src[pos] = s;
}

// ======= per-dst softmax stats -> normalized alpha per CSR slot ==
template<int H>
__global__ __launch_bounds__(64) void stats_kernel(const int* __restrict__ row_ptr,
                                                   const int* __restrict__ deg,
                                                   const int* __restrict__ csr_src,
                                                   const float* __restrict__ a_s, int sA,
                                                   const float* __restrict__ a_d, int sD,
                                                   float* __restrict__ alpha) {
    int d = blockIdx.x;
    int lane = threadIdx.x;
    int base = row_ptr[d], dg = deg[d];
    float ad[H];
    #pragma unroll
    for (int h = 0; h < H; h++) ad[h] = a_d[(size_t)d * sD + h];

    float mx[H];
    #pragma unroll
    for (int h = 0; h < H; h++) mx[h] = -1e30f;
    for (int j = lane; j < dg; j += 64) {
        int s = csr_src[base + j];
        #pragma unroll
        for (int h = 0; h < H; h++) {
            float sc = a_s[(size_t)s * sA + h] + ad[h];
            sc = sc > 0.f ? sc : 0.2f * sc;
            mx[h] = fmaxf(mx[h], sc);
        }
    }
    #pragma unroll
    for (int h = 0; h < H; h++) mx[h] = wave_allreduce_max(mx[h]);

    float sm[H];
    #pragma unroll
    for (int h = 0; h < H; h++) sm[h] = 0.f;
    for (int j = lane; j < dg; j += 64) {
        int s = csr_src[base + j];
        #pragma unroll
        for (int h = 0; h < H; h++) {
            float sc = a_s[(size_t)s * sA + h] + ad[h];
            sc = sc > 0.f ? sc : 0.2f * sc;
            sm[h] += __expf(sc - mx[h]);
        }
    }
    float rd[H];
    #pragma unroll
    for (int h = 0; h < H; h++) {
        sm[h] = wave_allreduce_sum(sm[h]);
        rd[h] = 1.f / (sm[h] + 1e-16f);
    }

    for (int j = lane; j < dg; j += 64) {
        int s = csr_src[base + j];
        #pragma unroll
        for (int h = 0; h < H; h++) {
            float sc = a_s[(size_t)s * sA + h] + ad[h];
            sc = sc > 0.f ? sc : 0.2f * sc;
            alpha[(size_t)(base + j) * H + h] = __expf(sc - mx[h]) * rd[h];
        }
    }
}

// ==== block1: gather-aggregate ALL 4 heads (uint-wide, 2 channels/lane) ==========
__global__ __launch_bounds__(128) void aggr_b1_all_kernel(const int* __restrict__ row_ptr,
                                                          const int* __restrict__ deg,
                                                          const int* __restrict__ csr_src,
                                                          const float* __restrict__ alpha,
                                                          const ushort* __restrict__ h1b,
                                                          ushort* __restrict__ accb) {
    int d = blockIdx.x;
    int t = threadIdx.x;   // uint lane: channels 2t, 2t+1
    int base = row_ptr[d], dg = deg[d];
    float a00 = 0, a01 = 0, a10 = 0, a11 = 0, a20 = 0, a21 = 0, a30 = 0, a31 = 0;
    for (int j = 0; j < dg; j++) {
        int s = csr_src[base + j];
        float4 a = *reinterpret_cast<const float4*>(&alpha[(size_t)(base + j) * 4]);
        unsigned v = reinterpret_cast<const unsigned*>(h1b + (size_t)s * 256)[t];
        float lo = b2f((ushort)(v & 0xffff)), hi = b2f((ushort)(v >> 16));
        a00 += a.x * lo; a01 += a.x * hi;
        a10 += a.y * lo; a11 += a.y * hi;
        a20 += a.z * lo; a21 += a.z * hi;
        a30 += a.w * lo; a31 += a.w * hi;
    }
    unsigned* o = reinterpret_cast<unsigned*>(accb + (size_t)d * 1024);
    o[t]       = pack2(a00, a01);
    o[t + 128] = pack2(a10, a11);
    o[t + 256] = pack2(a20, a21);
    o[t + 384] = pack2(a30, a31);
}

// ==== blocks 2/3: gather-aggregate + fused elu/residual epilogue ================
// NOTE: outb must NOT alias g (gather source) — blocks read arbitrary g rows.
template<int H, int C, int F>
__global__ void aggr_comb_kernel(const int* __restrict__ row_ptr,
                                 const int* __restrict__ deg,
                                 const int* __restrict__ csr_src,
                                 const float* __restrict__ alpha,
                                 const ushort* __restrict__ g,
                                 const float* __restrict__ Rf,
                                 const float* __restrict__ gb,
                                 const float* __restrict__ rb,
                                 ushort* __restrict__ outb) {
    int d = blockIdx.x;
    int t = threadIdx.x;               // 0..F/2-1
    int hd = (2 * t) / C;
    int base = row_ptr[d], dg = deg[d];
    float lo = 0.f, hi = 0.f;
    for (int j = 0; j < dg; j++) {
        int s = csr_src[base + j];
        float a = alpha[(size_t)(base + j) * H + hd];
        unsigned v = reinterpret_cast<const unsigned*>(g + (size_t)s * F)[t];
        lo += a * b2f((ushort)(v & 0xffff));
        hi += a * b2f((ushort)(v >> 16));
    }
    int c0 = 2 * t, c1 = 2 * t + 1;
    float o0 = lo + gb[c0]; o0 = o0 > 0.f ? o0 : (__expf(o0) - 1.f);
    float o1 = hi + gb[c1]; o1 = o1 > 0.f ? o1 : (__expf(o1) - 1.f);
    o0 += Rf[(size_t)d * F + c0] + rb[c0];
    o1 += Rf[(size_t)d * F + c1] + rb[c1];
    reinterpret_cast<unsigned*>(outb)[(size_t)d * (F / 2) + t] = pack2(o0, o1);
}

// ---------------- final tiny GEMM: out[M,2] = A[M,64](bf16) @ W[64,2] + b --------
__global__ __launch_bounds__(256) void mlp2_kernel(const ushort* __restrict__ A,
                                                   const float* __restrict__ W,
                                                   const float* __restrict__ b,
                                                   float* __restrict__ out, int M) {
    __shared__ float w[128];
    __shared__ float bb[2];
    int tid = threadIdx.x;
    if (tid < 128) w[tid] = W[tid];
    if (tid < 2) bb[tid] = b[tid];
    __syncthreads();
    int row = blockIdx.x * 256 + tid;
    if (row >= M) return;
    float a0 = bb[0], a1 = bb[1];
    const ushort* ap = A + (size_t)row * 64;
    #pragma unroll 8
    for (int k = 0; k < 64; k++) {
        float av = b2f(ap[k]);
        a0 += av * w[2 * k];
        a1 += av * w[2 * k + 1];
    }
    out[(size_t)row * 2] = a0;
    out[(size_t)row * 2 + 1] = a1;
}

extern "C" void kernel_launch(void* const* d_in, const int* in_sizes, int n_in,
                              void* d_out, int out_size, void* d_ws, size_t ws_size,
                              hipStream_t stream) {
    const float* x        = (const float*)d_in[0];
    const int*   ei       = (const int*)d_in[1];
    const float* enc_w1   = (const float*)d_in[2];
    const float* enc_b1   = (const float*)d_in[3];
    const float* ln1_g    = (const float*)d_in[4];
    const float* ln1_b    = (const float*)d_in[5];
    const float* enc_w2   = (const float*)d_in[6];
    const float* enc_b2   = (const float*)d_in[7];
    const float* ln2_g    = (const float*)d_in[8];
    const float* ln2_b    = (const float*)d_in[9];
    const float* w1       = (const float*)d_in[10];
    const float* att_src1 = (const float*)d_in[11];
    const float* att_dst1 = (const float*)d_in[12];
    const float* bias1    = (const float*)d_in[13];
    const float* res1_w   = (const float*)d_in[14];
    const float* res1_b   = (const float*)d_in[15];
    const float* w2       = (const float*)d_in[16];
    const float* att_src2 = (const float*)d_in[17];
    const float* att_dst2 = (const float*)d_in[18];
    const float* bias2    = (const float*)d_in[19];
    const float* res2_w   = (const float*)d_in[20];
    const float* res2_b   = (const float*)d_in[21];
    const float* w3       = (const float*)d_in[22];
    const float* att_src3 = (const float*)d_in[23];
    const float* att_dst3 = (const float*)d_in[24];
    const float* bias3    = (const float*)d_in[25];
    const float* res3_w   = (const float*)d_in[26];
    const float* res3_b   = (const float*)d_in[27];
    const float* mlp_w1   = (const float*)d_in[28];
    const float* mlp_b1   = (const float*)d_in[29];
    const float* mlp_w2   = (const float*)d_in[30];
    const float* mlp_b2   = (const float*)d_in[31];

    const int N  = in_sizes[0] / 405;   // 50000
    const int E  = in_sizes[1] / 2;     // 300000
    const int Et = E + N;
    const int NB = (N + 255) / 256;

    // ---------- workspace layout (bytes) ----------
    char* p = (char*)d_ws;
    char* R0 = p;                       // N*896 B : xb(448 b16) | H3b(b16 192) | M1b
    char* R1 = R0 + (size_t)N * 896;    // N*512 B : h0b | G2b
    char* R2 = R1 + (size_t)N * 512;    // N*512 B : h1b | G3b , H4b(@+N*256B)
    char* R3 = R2 + (size_t)N * 512;    // N*2048 B: F1(f32 256) | H2b(b16 1024)
    char* R4 = R3 + (size_t)N * 2048;   // N*2048 B: accb(b16 1024) | Rf(f32 192/128)
    char* T  = R4 + (size_t)N * 2048;   // tail

    ushort* xb   = (ushort*)R0;
    ushort* H3b  = (ushort*)R0;          // lives after xb is dead (enc1 done)
    ushort* M1b  = (ushort*)R0;          // lives after H3b is dead (block-3 GEMM done)
    ushort* h0b  = (ushort*)R1;
    ushort* G2b  = (ushort*)R1;
    ushort* h1b  = (ushort*)R2;
    ushort* G3b  = (ushort*)R2;
    ushort* H4b  = (ushort*)(R2 + (size_t)N * 256);
    float*  F1   = (float*)R3;
    ushort* H2b  = (ushort*)R3;
    ushort* accb = (ushort*)R4;
    float*  Rf   = (float*)R4;

    float* a_s   = (float*)T;                         T += (size_t)N * 4 * 4;   // also Sf2/Sf3
    float* a_d   = (float*)T;                         T += (size_t)N * 4 * 4;
    float* alpha = (float*)T;                         T += (size_t)Et * 4 * 4;
    float* qs    = (float*)T;                         T += 2048 * 4;
    float* qd    = (float*)T;                         T += 2048 * 4;
    int* deg     = (int*)T;                           T += (size_t)N * 4;
    int* cur     = (int*)T;                           T += (size_t)N * 4;
    int* row_ptr = (int*)T;                           T += (size_t)N * 4;
    int* incl    = (int*)T;                           T += (size_t)N * 4;
    int* part    = (int*)T;                           T += 256 * 4;
    int* csr_src = (int*)T;                           T += (size_t)Et * 4;
    ushort* enc_w1T = (ushort*)T;                     T += (size_t)256 * 448 * 2;
    ushort* enc_w2T = (ushort*)T;                     T += (size_t)256 * 256 * 2;
    ushort* w1T     = (ushort*)T;                     T += (size_t)1024 * 256 * 2;
    ushort* res1T   = (ushort*)T;                     T += (size_t)1024 * 256 * 2;
    ushort* Bcat2T  = (ushort*)T;                     T += (size_t)512 * 1024 * 2;
    ushort* Bcat3T  = (ushort*)T;                     T += (size_t)384 * 192 * 2;
    ushort* mlpw1T  = (ushort*)T;                     T += (size_t)128 * 128 * 2;

    auto cdiv = [](int a, int b) { return (a + b - 1) / b; };
    const int MB = cdiv(N, 128);

    // ---- CSR build ----
    hipMemsetAsync(deg, 0, (size_t)N * 8, stream);   // deg + cur
    deg_kernel<<<cdiv(Et, 256), 256, 0, stream>>>(ei, deg, E, Et);
    scan1_kernel<<<NB, 256, 0, stream>>>(deg, incl, part, N);
    scan2_kernel<<<1, 256, 0, stream>>>(part, NB);
    scan3_kernel<<<NB, 256, 0, stream>>>(incl, deg, part, row_ptr, N);
    fill_kernel<<<cdiv(Et, 256), 256, 0, stream>>>(ei, row_ptr, cur, csr_src, E, Et);

    // ---- weight prep: ONE launch ----
    prep_all_kernel<<<cdiv(1314432, 256), 256, 0, stream>>>(
        enc_w1, enc_w2, w1, res1_w, w2, res2_w, w3, res3_w, mlp_w1,
        enc_w1T, enc_w2T, w1T, res1T, Bcat2T, Bcat3T, mlpw1T);

    // ---- JointEncoder ----
    conv_pad_x_kernel<<<cdiv(N * 448, 256), 256, 0, stream>>>(x, xb, N);
    bgemm<0><<<dim3(2, MB), 256, 0, stream>>>(xb, enc_w1T, enc_b1, F1, 256, nullptr, nullptr, 0, N, 256, 448, 448);
    ln_relu_kernel<<<N, 256, 0, stream>>>(F1, ln1_g, ln1_b, h0b);
    bgemm<0><<<dim3(2, MB), 256, 0, stream>>>(h0b, enc_w2T, enc_b2, F1, 256, nullptr, nullptr, 0, N, 256, 256, 256);
    ln_relu_kernel<<<N, 256, 0, stream>>>(F1, ln2_g, ln2_b, h1b);

    // ---- Block 1: GAT 256 -> 4x256 concat (fused head GEMMs + residual) ----
    {
        fold_att_kernel<<<cdiv(4 * 256, 256), 256, 0, stream>>>(w1, att_src1, att_dst1, qs, qd, 256, 256, 4);
        att_scores4_kernel<<<N, 64, 0, stream>>>(h1b, qs, qd, a_s, a_d);
        stats_kernel<4><<<N, 64, 0, stream>>>(row_ptr, deg, csr_src, a_s, 4, a_d, 4, alpha);
        aggr_b1_all_kernel<<<N, 128, 0, stream>>>(row_ptr, deg, csr_src, alpha, h1b, accb);
        bgemm_b1<<<dim3(8, MB), 256, 0, stream>>>(accb, w1T, h1b, res1T, bias1, res1_b, H2b, N);
    }

    // ---- Block 2: GAT 1024 -> 2x96 concat (G/R/scores in one split-epilogue GEMM) --
    {
        fold_att_b16_kernel<<<cdiv(2 * 1024, 256), 256, 0, stream>>>(w2, att_src2, att_dst2,
            Bcat2T + (size_t)384 * 1024, Bcat2T + (size_t)386 * 1024, 1024, 96, 2);
        // cols: [0,192)=G2b bf16, [192,384)=Rf fp32, [384,388)=scores -> a_s[N,4]
        bgemm<5><<<dim3(4, MB), 256, 0, stream>>>(H2b, Bcat2T, nullptr, G2b, 0, Rf, a_s, 192, N, 388, 1024, 1024);
        stats_kernel<2><<<N, 64, 0, stream>>>(row_ptr, deg, csr_src, a_s, 4, a_s + 2, 4, alpha);
        // H3b (R0) does NOT alias G2b (R1) -> fused gather+epilogue is safe
        aggr_comb_kernel<2, 96, 192><<<N, 96, 0, stream>>>(row_ptr, deg, csr_src, alpha, G2b,
                                                           Rf, bias2, res2_b, H3b);
    }

    // ---- Block 3: GAT 192 -> 1x128 (no concat) ----
    {
        fold_att_b16_kernel<<<1, 256, 0, stream>>>(w3, att_src3, att_dst3,
            Bcat3T + (size_t)256 * 192, Bcat3T + (size_t)257 * 192, 192, 128, 1);
        // cols: [0,128)=G3b bf16, [128,256)=Rf fp32, [256,258)=scores -> a_s[N,2]
        bgemm<5><<<dim3(3, MB), 256, 0, stream>>>(H3b, Bcat3T, nullptr, G3b, 0, Rf, a_s, 128, N, 258, 192, 192);
        stats_kernel<1><<<N, 64, 0, stream>>>(row_ptr, deg, csr_src, a_s, 2, a_s + 1, 2, alpha);
        // H4b (R2 + N*256B) does NOT alias G3b (R2, N*256B) -> safe
        aggr_comb_kernel<1, 128, 128><<<N, 64, 0, stream>>>(row_ptr, deg, csr_src, alpha, G3b,
                                                            Rf, bias3, res3_b, H4b);
    }

    // ---- MLP head ----
    bgemm<3><<<dim3(1, MB), 256, 0, stream>>>(H4b, mlpw1T, mlp_b1, M1b, 64, nullptr, nullptr, 0, N, 64, 128, 128);
    mlp2_kernel<<<cdiv(N, 256), 256, 0, stream>>>(M1b, mlp_w2, mlp_b2, (float*)d_out, N);
}